// Round 7
// baseline (1577.323 us; speedup 1.0000x reference)
//
#include <hip/hip_runtime.h>
#include <hip/hip_bf16.h>
#include <cstdint>

// ---------------------------------------------------------------------------
// B=2 S=2048 D=512 H=8 HD=64, FFH=1024. Encoder: 4 layers, G=2, Sg=2048
// (block-causal-64 AND doc mask). Router: 2 layers, G=64, Sg=72, full attn.
// Round 16: register-staged A, B-only LDS GEMMs.
//  Cross-round law: MfmaUtil ~ 10% x blocks/CU; LDS is the occupancy limiter;
//  A-tile needn't be in LDS (per-lane frag = direct short8 global load,
//  verified equal to the old LDS+swizzle address algebra). A is L2-resident.
//  - gemm3r<BN>: A frags double-buffered in regs (aNext loaded iter-early),
//    B in 2-set gload_lds+XOR LDS. LDS 32KB(BN=128)/16KB(BN=64) -> 4 blk/CU.
//  - gemm_up_silu: BN=64 + reg-A, grid (16,T/64)=1024 -> 4/CU (was 2).
//  - o/dn: BN=64 -> grid 512 (was 256 = 1/CU).
// ---------------------------------------------------------------------------

typedef __attribute__((ext_vector_type(8))) short short8;   // 8 bf16 = 4 VGPR
typedef __attribute__((ext_vector_type(4))) float f32x4;
typedef unsigned short ushort_t;

__device__ __forceinline__ float bf2f(unsigned short u) {
    return __uint_as_float(((unsigned)u) << 16);
}
__device__ __forceinline__ unsigned short f2bf(float f) {
    unsigned u = __float_as_uint(f);
    unsigned r = 0x7FFFu + ((u >> 16) & 1u);
    return (unsigned short)((u + r) >> 16);
}
__device__ __forceinline__ float wave_sum64(float v) {
#pragma unroll
    for (int o = 32; o; o >>= 1) v += __shfl_xor(v, o);
    return v;
}
__device__ __forceinline__ void load_lds16(const ushort_t* g, ushort_t* l) {
    __builtin_amdgcn_global_load_lds(
        (const __attribute__((address_space(1))) unsigned int*)g,
        (__attribute__((address_space(3))) unsigned int*)l, 16, 0, 0);
}

#define MFMA16(a, b, c) __builtin_amdgcn_mfma_f32_16x16x32_bf16(a, b, c, 0, 0, 0)
#define BARRIER_RAW() do { asm volatile("" ::: "memory"); \
    __builtin_amdgcn_s_barrier(); asm volatile("" ::: "memory"); } while (0)
#define VMCNT0() asm volatile("s_waitcnt vmcnt(0)" ::: "memory")

// ---- f32 copy (input x -> mutable X) --------------------------------------
__global__ void copy_in_kernel(const float* __restrict__ src,
                               float* __restrict__ dst, int n) {
    int i = blockIdx.x * 256 + threadIdx.x;
    if (i < n) dst[i] = src[i];
}

// ---- weight transpose + hi/lo bf16 split: W[K,N] -> WT_hi/lo[N,K] ---------
__global__ __launch_bounds__(256) void wsplit_kernel(const float* __restrict__ W,
        unsigned short* __restrict__ WH, unsigned short* __restrict__ WL,
        int K, int N) {
    __shared__ float tile[32][33];
    int bn = blockIdx.x * 32, bk = blockIdx.y * 32;
    int tx = threadIdx.x & 31, ty = threadIdx.x >> 5;
#pragma unroll
    for (int i = 0; i < 4; ++i)
        tile[ty + 8 * i][tx] = W[(size_t)(bk + ty + 8 * i) * N + bn + tx];
    __syncthreads();
#pragma unroll
    for (int i = 0; i < 4; ++i) {
        int n = bn + ty + 8 * i, k = bk + tx;
        float x = tile[tx][ty + 8 * i];
        unsigned short h = f2bf(x);
        unsigned short lo = f2bf(x - bf2f(h));
        WH[(size_t)n * K + k] = h;
        WL[(size_t)n * K + k] = lo;
    }
}

// ---- RMSNorm over D=512, emits bf16 hi/lo ---------------------------------
__global__ __launch_bounds__(256) void rmsnorm_kernel(const float* __restrict__ X,
        const float* __restrict__ W, ushort_t* __restrict__ XNH,
        ushort_t* __restrict__ XNL) {
    int t = blockIdx.x, tid = threadIdx.x;
    const float* xr = X + (size_t)t * 512;
    float v0 = xr[tid], v1 = xr[tid + 256];
    float ss = wave_sum64(v0 * v0 + v1 * v1);
    __shared__ float red[4];
    if ((tid & 63) == 0) red[tid >> 6] = ss;
    __syncthreads();
    float tot = red[0] + red[1] + red[2] + red[3];
    float scale = rsqrtf(tot * (1.0f / 512.0f) + 1e-6f);
    float a0 = v0 * scale * W[tid];
    float a1 = v1 * scale * W[tid + 256];
    unsigned short h0 = f2bf(a0), h1 = f2bf(a1);
    size_t base = (size_t)t * 512;
    XNH[base + tid]       = h0;
    XNL[base + tid]       = f2bf(a0 - bf2f(h0));
    XNH[base + tid + 256] = h1;
    XNL[base + tid + 256] = f2bf(a1 - bf2f(h1));
}

// ---- bf16x3 MFMA GEMM: reg-staged A, B-only 2-set LDS ---------------------
// C[M,N] = A @ B^T (+Res). Tile 64 x BN, BK=32, 256 thr = 4 waves,
// wave 32 x BN/2. A frags double-buffered in regs (aNext loaded iter-early,
// direct short8 global loads — address equals old LDS+swizzle algebra).
// B set rows: [0,BN)=Bh, [BN,2BN)=Bl, gload_lds + XOR swizzle as before.
template <int BN>
__global__ __launch_bounds__(256) void gemm3r(
        const ushort_t* __restrict__ AH, const ushort_t* __restrict__ AL,
        const ushort_t* __restrict__ BH, const ushort_t* __restrict__ BL,
        const float* __restrict__ Res, float* __restrict__ C,
        int M, int N, int K) {
    constexpr int NI   = BN / 32;        // B frags per wave
    constexpr int ROWS = 2 * BN;         // Bh|Bl rows per set
    constexpr int LPW  = ROWS / 64;      // gload_lds per wave per stage
    constexpr int SS   = ROWS * 32;      // ushorts per set
    __shared__ __align__(16) ushort_t S[2][ROWS][32];
    int tid = threadIdx.x;
    int n0 = blockIdx.x * BN, m0 = blockIdx.y * 64;
    int wid = tid >> 6, lane = tid & 63;
    int wm = (wid >> 1) * 32, wn = (wid & 1) * (BN / 2);
    int col = lane & 15, quad = lane >> 4;

    // B staging sources (pre-swizzled chunk)
    const ushort_t* gsrc[LPW];
    int ldof[LPW];
#pragma unroll
    for (int j = 0; j < LPW; ++j) {
        int e = wid * LPW + j;
        int srow = e * 16 + (lane >> 2);
        const ushort_t* gp; int rin;
        if (srow < BN) { gp = BH; rin = n0 + srow; }
        else           { gp = BL; rin = n0 + srow - BN; }
        gsrc[j] = gp + (size_t)rin * K + ((lane & 3) ^ ((lane >> 3) & 3)) * 8;
        ldof[j] = e * 512;
    }
    // A direct per-lane fragment pointers
    const ushort_t* apH[2];
    const ushort_t* apL[2];
#pragma unroll
    for (int mi = 0; mi < 2; ++mi) {
        int arow = m0 + wm + mi * 16 + col;
        apH[mi] = AH + (size_t)arow * K + quad * 8;
        apL[mi] = AL + (size_t)arow * K + quad * 8;
    }
    ushort_t* sbase = &S[0][0][0];
    auto STAGE = [&](int set, int kc) {
        ushort_t* sb = sbase + set * SS;
#pragma unroll
        for (int j = 0; j < LPW; ++j)
            load_lds16(gsrc[j] + kc * 32, sb + ldof[j]);
    };

    int chrd = (quad ^ ((col >> 1) & 3)) * 8;   // read-side swizzled chunk
    f32x4 acc[2][NI] = {};
    int nk = K >> 5;
    short8 aCH[2], aCL[2], aNH[2], aNL[2];
#pragma unroll
    for (int mi = 0; mi < 2; ++mi) {
        aCH[mi] = *(const short8*)(apH[mi]);
        aCL[mi] = *(const short8*)(apL[mi]);
    }
    STAGE(0, 0);
    VMCNT0();
    BARRIER_RAW();
    int cur = 0;
#pragma unroll 1
    for (int kc = 0; kc < nk; ++kc) {
        if (kc + 1 < nk) {
            STAGE(cur ^ 1, kc + 1);            // B in flight during compute
#pragma unroll
            for (int mi = 0; mi < 2; ++mi) {   // A(kc+1) in flight too
                aNH[mi] = *(const short8*)(apH[mi] + (kc + 1) * 32);
                aNL[mi] = *(const short8*)(apL[mi] + (kc + 1) * 32);
            }
        }
        const ushort_t* sb = sbase + cur * SS;
        short8 bfh[NI], bfl[NI];
#pragma unroll
        for (int i = 0; i < NI; ++i) {
            bfh[i] = *(const short8*)(sb + (size_t)(wn + i * 16 + col) * 32 + chrd);
            bfl[i] = *(const short8*)(sb + (size_t)(BN + wn + i * 16 + col) * 32 + chrd);
        }
#pragma unroll
        for (int mi = 0; mi < 2; ++mi)
#pragma unroll
            for (int ni = 0; ni < NI; ++ni) {
                f32x4 c = acc[mi][ni];
                c = MFMA16(aCH[mi], bfh[ni], c);
                c = MFMA16(aCH[mi], bfl[ni], c);
                c = MFMA16(aCL[mi], bfh[ni], c);
                acc[mi][ni] = c;
            }
        if (kc + 1 < nk) {
            VMCNT0();           // next set's B landed (A reg loads too)
            BARRIER_RAW();      // all waves done reading cur
            cur ^= 1;
#pragma unroll
            for (int mi = 0; mi < 2; ++mi) { aCH[mi] = aNH[mi]; aCL[mi] = aNL[mi]; }
        }
    }
#pragma unroll
    for (int mi = 0; mi < 2; ++mi)
#pragma unroll
        for (int ni = 0; ni < NI; ++ni)
#pragma unroll
            for (int r = 0; r < 4; ++r) {
                int row = m0 + wm + mi * 16 + quad * 4 + r;
                int ccol = n0 + wn + ni * 16 + col;
                size_t o = (size_t)row * N + ccol;
                float v = acc[mi][ni][r];
                if (Res) v += Res[o];
                C[o] = v;
            }
}

// ---- fused up-proj + silu: MID = silu(A@W1^T) * (A@W2^T), bf16 hi/lo ------
// BN=64 h-cols per block; W rows [n0,n0+64)=h1, [1024+n0,1024+n0+64)=h2.
// Reg-staged A; B set rows: [0,64)B1h [64,128)B1l [128,192)B2h [192,256)B2l.
// 2 sets = 32KB. Grid (16, T/64). Wave 32x32 against both panels.
__global__ __launch_bounds__(256) void gemm_up_silu(
        const ushort_t* __restrict__ AH, const ushort_t* __restrict__ AL,
        const ushort_t* __restrict__ BH, const ushort_t* __restrict__ BL,
        ushort_t* __restrict__ MIDH, ushort_t* __restrict__ MIDL, int K) {
    constexpr int ROWS = 256;
    constexpr int LPW  = 4;
    constexpr int SS   = ROWS * 32;
    __shared__ __align__(16) ushort_t S[2][ROWS][32];
    int tid = threadIdx.x;
    int n0 = blockIdx.x * 64, m0 = blockIdx.y * 64;
    int wid = tid >> 6, lane = tid & 63;
    int wm = (wid >> 1) * 32, wn = (wid & 1) * 32;
    int col = lane & 15, quad = lane >> 4;

    const ushort_t* gsrc[LPW];
    int ldof[LPW];
#pragma unroll
    for (int j = 0; j < LPW; ++j) {
        int e = wid * LPW + j;
        int srow = e * 16 + (lane >> 2);
        const ushort_t* gp; int rin;
        if (srow < 64)       { gp = BH; rin = n0 + srow; }
        else if (srow < 128) { gp = BL; rin = n0 + srow - 64; }
        else if (srow < 192) { gp = BH; rin = 1024 + n0 + srow - 128; }
        else                 { gp = BL; rin = 1024 + n0 + srow - 192; }
        gsrc[j] = gp + (size_t)rin * K + ((lane & 3) ^ ((lane >> 3) & 3)) * 8;
        ldof[j] = e * 512;
    }
    const ushort_t* apH[2];
    const ushort_t* apL[2];
#pragma unroll
    for (int mi = 0; mi < 2; ++mi) {
        int arow = m0 + wm + mi * 16 + col;
        apH[mi] = AH + (size_t)arow * K + quad * 8;
        apL[mi] = AL + (size_t)arow * K + quad * 8;
    }
    ushort_t* sbase = &S[0][0][0];
    auto STAGE = [&](int set, int kc) {
        ushort_t* sb = sbase + set * SS;
#pragma unroll
        for (int j = 0; j < LPW; ++j)
            load_lds16(gsrc[j] + kc * 32, sb + ldof[j]);
    };

    int chrd = (quad ^ ((col >> 1) & 3)) * 8;
    f32x4 a1[2][2] = {}, a2[2][2] = {};
    int nk = K >> 5;
    short8 aCH[2], aCL[2], aNH[2], aNL[2];
#pragma unroll
    for (int mi = 0; mi < 2; ++mi) {
        aCH[mi] = *(const short8*)(apH[mi]);
        aCL[mi] = *(const short8*)(apL[mi]);
    }
    STAGE(0, 0);
    VMCNT0();
    BARRIER_RAW();
    int cur = 0;
#pragma unroll 1
    for (int kc = 0; kc < nk; ++kc) {
        if (kc + 1 < nk) {
            STAGE(cur ^ 1, kc + 1);
#pragma unroll
            for (int mi = 0; mi < 2; ++mi) {
                aNH[mi] = *(const short8*)(apH[mi] + (kc + 1) * 32);
                aNL[mi] = *(const short8*)(apL[mi] + (kc + 1) * 32);
            }
        }
        const ushort_t* sb = sbase + cur * SS;
        short8 b1h[2], b1l[2], b2h[2], b2l[2];
#pragma unroll
        for (int i = 0; i < 2; ++i) {
            b1h[i] = *(const short8*)(sb + (size_t)(wn + i * 16 + col) * 32 + chrd);
            b1l[i] = *(const short8*)(sb + (size_t)(64 + wn + i * 16 + col) * 32 + chrd);
            b2h[i] = *(const short8*)(sb + (size_t)(128 + wn + i * 16 + col) * 32 + chrd);
            b2l[i] = *(const short8*)(sb + (size_t)(192 + wn + i * 16 + col) * 32 + chrd);
        }
#pragma unroll
        for (int mi = 0; mi < 2; ++mi)
#pragma unroll
            for (int ni = 0; ni < 2; ++ni) {
                f32x4 c = a1[mi][ni];
                c = MFMA16(aCH[mi], b1h[ni], c);
                c = MFMA16(aCH[mi], b1l[ni], c);
                c = MFMA16(aCL[mi], b1h[ni], c);
                a1[mi][ni] = c;
                f32x4 d = a2[mi][ni];
                d = MFMA16(aCH[mi], b2h[ni], d);
                d = MFMA16(aCH[mi], b2l[ni], d);
                d = MFMA16(aCL[mi], b2h[ni], d);
                a2[mi][ni] = d;
            }
        if (kc + 1 < nk) {
            VMCNT0();
            BARRIER_RAW();
            cur ^= 1;
#pragma unroll
            for (int mi = 0; mi < 2; ++mi) { aCH[mi] = aNH[mi]; aCL[mi] = aNL[mi]; }
        }
    }
#pragma unroll
    for (int mi = 0; mi < 2; ++mi)
#pragma unroll
        for (int ni = 0; ni < 2; ++ni)
#pragma unroll
            for (int r = 0; r < 4; ++r) {
                int row = m0 + wm + mi * 16 + quad * 4 + r;
                int ccol = n0 + wn + ni * 16 + col;
                float v1 = a1[mi][ni][r], v2 = a2[mi][ni][r];
                float rr = (v1 / (1.0f + __expf(-v1))) * v2;
                unsigned short h = f2bf(rr);
                size_t o = (size_t)row * 1024 + ccol;
                MIDH[o] = h;
                MIDL[o] = f2bf(rr - bf2f(h));
            }
}

// ---- split qkv + RoPE; Q f32 (g,h,s,hd); K bf16 hi/lo [gh][Sg][64] --------
__global__ void rope_pack_kernel(const float* __restrict__ QKV,
        float* __restrict__ Q, ushort_t* __restrict__ KH,
        ushort_t* __restrict__ KL, int Sg, int total) {
    int idx = blockIdx.x * 256 + threadIdx.x;
    if (idx >= total) return;
    int i = idx & 31;
    int h = (idx >> 5) & 7;
    int t = idx >> 8;
    int g = t / Sg; int s = t - g * Sg;
    const float* row = QKV + (size_t)t * 1536;
    float inv = powf(10000.0f, -(float)(2 * i) / 64.0f);
    float sn, cs;
    sincosf((float)s * inv, &sn, &cs);
    size_t ob = ((size_t)(g * 8 + h) * Sg + s) * 64 + i;
    int c = h * 64 + i;
    float q1 = row[c], q2 = row[c + 32];
    Q[ob]      = q1 * cs + q2 * sn;
    Q[ob + 32] = q2 * cs - q1 * sn;
    float k1 = row[512 + c], k2 = row[512 + c + 32];
    float ka = k1 * cs + k2 * sn;
    float kb = k2 * cs - k1 * sn;
    unsigned short ha = f2bf(ka), hb = f2bf(kb);
    KH[ob]      = ha;  KL[ob]      = f2bf(ka - bf2f(ha));
    KH[ob + 32] = hb;  KL[ob + 32] = f2bf(kb - bf2f(hb));
}

// ---- V^T split: QKV f32 [T][1536] -> VT hi/lo [gh][64 d][Sg s] ------------
__global__ __launch_bounds__(256) void vtrans_kernel(const float* __restrict__ QKV,
        ushort_t* __restrict__ VTH, ushort_t* __restrict__ VTL, int Sg) {
    __shared__ float tile[64][65];
    int chunk = blockIdx.x, gh = blockIdx.y;
    int g = gh >> 3, h = gh & 7;
    int tid = threadIdx.x;
    int sr = tid >> 2, dc = (tid & 3) * 16;
    int s = chunk * 64 + sr;
    if (s < Sg) {
        const float* src = QKV + ((size_t)g * Sg + s) * 1536 + 1024 + h * 64 + dc;
#pragma unroll
        for (int j = 0; j < 4; ++j) {
            float4 v = *(const float4*)(src + 4 * j);
            tile[sr][dc + 4 * j]     = v.x;
            tile[sr][dc + 4 * j + 1] = v.y;
            tile[sr][dc + 4 * j + 2] = v.z;
            tile[sr][dc + 4 * j + 3] = v.w;
        }
    } else {
#pragma unroll
        for (int j = 0; j < 16; ++j) tile[sr][dc + j] = 0.f;
    }
    __syncthreads();
    int dr = tid >> 2, sc = (tid & 3) * 16;
    short8 hv[2], lv[2];
#pragma unroll
    for (int half = 0; half < 2; ++half)
#pragma unroll
        for (int j = 0; j < 8; ++j) {
            float v = tile[sc + half * 8 + j][dr];
            unsigned short hb = f2bf(v);
            hv[half][j] = (short)hb;
            lv[half][j] = (short)f2bf(v - bf2f(hb));
        }
    int scol = chunk * 64 + sc;
    size_t ob = ((size_t)gh * 64 + dr) * Sg + scol;
    if (scol + 16 <= Sg) {
        *(short8*)(VTH + ob)     = hv[0];
        *(short8*)(VTH + ob + 8) = hv[1];
        *(short8*)(VTL + ob)     = lv[0];
        *(short8*)(VTL + ob + 8) = lv[1];
    } else {
#pragma unroll
        for (int j = 0; j < 16; ++j)
            if (scol + j < Sg) {
                VTH[ob + j] = (ushort_t)((j < 8) ? hv[0][j] : hv[1][j - 8]);
                VTL[ob + j] = (ushort_t)((j < 8) ? lv[0][j] : lv[1][j - 8]);
            }
    }
}

// ---- MFMA flash attention (bf16x3), K/V pre-split, gload_lds + XOR swz ----
template <bool MASKED>
__global__ __launch_bounds__(256, 3) void attn3_kernel(const float* __restrict__ Q,
        const ushort_t* __restrict__ KHg, const ushort_t* __restrict__ KLg,
        const ushort_t* __restrict__ VTHg, const ushort_t* __restrict__ VTLg,
        const int* __restrict__ doc, ushort_t* __restrict__ AOH,
        ushort_t* __restrict__ AOL, int Sg) {
    __shared__ __align__(16) ushort_t Khs[64][64], Kls[64][64];  // swizzled
    __shared__ __align__(16) ushort_t Vts[64][64], Vtl[64][64];  // swizzled
    __shared__ __align__(16) ushort_t Ph[4][16][72], Pl[4][16][72];
    __shared__ int dock[64];
    int qb = (int)(gridDim.x - 1 - blockIdx.x);   // big qb first (load balance)
    int gh = blockIdx.y, g = gh >> 3;
    int tid = threadIdx.x, wid = tid >> 6, lane = tid & 63;
    int col = lane & 15, quad = lane >> 4;

    int rL = lane >> 3, cSw = (lane & 7) ^ rL;
    const ushort_t* kb;      // K waves: row base (chunk folded in)
    const ushort_t* vb;      // V waves: d-row base
    ushort_t* lb;
    if (wid == 0)      { kb = KHg + (size_t)gh * Sg * 64 + cSw * 8;  vb = nullptr; lb = &Khs[0][0]; }
    else if (wid == 1) { kb = KLg + (size_t)gh * Sg * 64 + cSw * 8;  vb = nullptr; lb = &Kls[0][0]; }
    else if (wid == 2) { vb = VTHg + ((size_t)gh * 64 + rL) * Sg;    kb = nullptr; lb = &Vts[0][0]; }
    else               { vb = VTLg + ((size_t)gh * 64 + rL) * Sg;    kb = nullptr; lb = &Vtl[0][0]; }
    int sw0 = ((0 + quad) ^ (col & 7)) * 8;
    int sw1 = ((4 + quad) ^ (col & 7)) * 8;

    short8 qa[2][2];  // [kk][0=hi,1=lo]
    {
        int qrow = qb * 64 + wid * 16 + col;
        if (qrow >= Sg) qrow = Sg - 1;
        const float* Qg = Q + ((size_t)gh * Sg + qrow) * 64 + quad * 8;
#pragma unroll
        for (int kk = 0; kk < 2; ++kk) {
            float4 v0 = *(const float4*)(Qg + kk * 32);
            float4 v1 = *(const float4*)(Qg + kk * 32 + 4);
            float vv[8] = {v0.x, v0.y, v0.z, v0.w, v1.x, v1.y, v1.z, v1.w};
            short8 h, l;
#pragma unroll
            for (int e = 0; e < 8; ++e) {
                float x = vv[e] * 0.125f;
                unsigned short hb = f2bf(x);
                h[e] = (short)hb;
                l[e] = (short)f2bf(x - bf2f(hb));
            }
            qa[kk][0] = h; qa[kk][1] = l;
        }
    }
    int dqr[4]; int wq0 = 0, wq1 = 0, bq0 = 0, bq1 = 0;
    if (MASKED) {
        const int* db = doc + (size_t)g * Sg + qb * 64;
#pragma unroll
        for (int r = 0; r < 4; ++r) dqr[r] = db[wid * 16 + quad * 4 + r];
        wq0 = db[wid * 16]; wq1 = db[wid * 16 + 15];
        bq0 = db[0];        bq1 = db[63];
    }
    float m[4], l[4];
    f32x4 accO[4];
#pragma unroll
    for (int r = 0; r < 4; ++r) { m[r] = -1e30f; l[r] = 0.f; }
#pragma unroll
    for (int nd = 0; nd < 4; ++nd) accO[nd] = (f32x4){0.f, 0.f, 0.f, 0.f};

    int nkt = MASKED ? (qb + 1) : ((Sg + 63) >> 6);
    for (int kt = 0; kt < nkt; ++kt) {
        int kval = Sg - kt * 64; if (kval > 64) kval = 64;
        __syncthreads();
        if (MASKED) {
            if (tid < 64) dock[tid] = doc[(size_t)g * Sg + kt * 64 + tid];
            __syncthreads();
        }
        bool bskip = false;
        if (MASKED) bskip = (dock[63] < bq0) || (dock[0] > bq1);
        if (!bskip) {
            if (wid < 2) {
#pragma unroll
                for (int p = 0; p < 8; ++p) {
                    int sr2 = kt * 64 + p * 8 + rL;
                    if (sr2 > Sg - 1) sr2 = Sg - 1;
                    load_lds16(kb + (size_t)sr2 * 64, lb + p * 512);
                }
            } else {
                int vc = kt * 64 + cSw * 8;
                if (vc > Sg - 8) vc = Sg - 8;
#pragma unroll
                for (int p = 0; p < 8; ++p)
                    load_lds16(vb + (size_t)(p * 8) * Sg + vc, lb + p * 512);
            }
            __syncthreads();
            bool wskip = false;
            if (MASKED) wskip = (dock[kval - 1] < wq0) || (dock[0] > wq1);
            if (!wskip) {
                int dk[4];
                if (MASKED) {
#pragma unroll
                    for (int ni = 0; ni < 4; ++ni) dk[ni] = dock[ni * 16 + col];
                }
                f32x4 sc[4];
#pragma unroll
                for (int ni = 0; ni < 4; ++ni) {
                    int rb = (ni * 16 + col) * 64;
                    short8 bh0 = *(const short8*)(&Khs[0][0] + rb + sw0);
                    short8 bl0 = *(const short8*)(&Kls[0][0] + rb + sw0);
                    short8 bh1 = *(const short8*)(&Khs[0][0] + rb + sw1);
                    short8 bl1 = *(const short8*)(&Kls[0][0] + rb + sw1);
                    f32x4 c = (f32x4){0.f, 0.f, 0.f, 0.f};
                    c = MFMA16(qa[0][0], bh0, c);
                    c = MFMA16(qa[0][0], bl0, c);
                    c = MFMA16(qa[0][1], bh0, c);
                    c = MFMA16(qa[1][0], bh1, c);
                    c = MFMA16(qa[1][0], bl1, c);
                    c = MFMA16(qa[1][1], bh1, c);
                    sc[ni] = c;
                }
                float mnew[4];
#pragma unroll
                for (int r = 0; r < 4; ++r) mnew[r] = -1e30f;
#pragma unroll
                for (int ni = 0; ni < 4; ++ni)
#pragma unroll
                    for (int r = 0; r < 4; ++r) {
                        bool ok = MASKED ? (dk[ni] == dqr[r]) : (ni * 16 + col < kval);
                        float s = ok ? sc[ni][r] : -1e30f;
                        sc[ni][r] = s;
                        mnew[r] = fmaxf(mnew[r], s);
                    }
#pragma unroll
                for (int r = 0; r < 4; ++r)
#pragma unroll
                    for (int o = 1; o < 16; o <<= 1)
                        mnew[r] = fmaxf(mnew[r], __shfl_xor(mnew[r], o));
                float alpha[4], lsum[4];
#pragma unroll
                for (int r = 0; r < 4; ++r) {
                    float M = fmaxf(m[r], mnew[r]);
                    alpha[r] = __expf(m[r] - M);
                    m[r] = M;
                    lsum[r] = 0.f;
                }
#pragma unroll
                for (int ni = 0; ni < 4; ++ni)
#pragma unroll
                    for (int r = 0; r < 4; ++r) {
                        bool ok = MASKED ? (dk[ni] == dqr[r]) : (ni * 16 + col < kval);
                        float p = ok ? __expf(sc[ni][r] - m[r]) : 0.f;
                        lsum[r] += p;
                        unsigned short h = f2bf(p);
                        Ph[wid][quad * 4 + r][ni * 16 + col] = h;
                        Pl[wid][quad * 4 + r][ni * 16 + col] = f2bf(p - bf2f(h));
                    }
#pragma unroll
                for (int r = 0; r < 4; ++r) {
#pragma unroll
                    for (int o = 1; o < 16; o <<= 1)
                        lsum[r] += __shfl_xor(lsum[r], o);
                    l[r] = l[r] * alpha[r] + lsum[r];
                }
#pragma unroll
                for (int nd = 0; nd < 4; ++nd)
#pragma unroll
                    for (int r = 0; r < 4; ++r) accO[nd][r] *= alpha[r];
#pragma unroll
                for (int kk = 0; kk < 2; ++kk) {
                    short8 pah = *(const short8*)&Ph[wid][col][kk * 32 + quad * 8];
                    short8 pal = *(const short8*)&Pl[wid][col][kk * 32 + quad * 8];
                    int sw = kk ? sw1 : sw0;
#pragma unroll
                    for (int nd = 0; nd < 4; ++nd) {
                        int rb = (nd * 16 + col) * 64;
                        short8 vbh = *(const short8*)(&Vts[0][0] + rb + sw);
                        short8 vbl = *(const short8*)(&Vtl[0][0] + rb + sw);
                        f32x4 c = accO[nd];
                        c = MFMA16(pah, vbh, c);
                        c = MFMA16(pah, vbl, c);
                        c = MFMA16(pal, vbh, c);
                        accO[nd] = c;
                    }
                }
            }
        }
    }
#pragma unroll
    for (int r = 0; r < 4; ++r) {
        int qrow = qb * 64 + wid * 16 + quad * 4 + r;
        if (qrow < Sg) {
            float inv = 1.0f / l[r];
            size_t base = ((size_t)g * Sg + qrow) * 512 + (gh & 7) * 64;
#pragma unroll
            for (int nd = 0; nd < 4; ++nd) {
                float val = accO[nd][r] * inv;
                unsigned short h = f2bf(val);
                AOH[base + nd * 16 + col] = h;
                AOL[base + nd * 16 + col] = f2bf(val - bf2f(h));
            }
        }
    }
}

// ---- build router stream: (64 groups) x (64 tokens + 8 router tokens) -----
__global__ void router_build_kernel(const float* __restrict__ X,
        const float* __restrict__ RT, float* __restrict__ X2, int total) {
    int idx = blockIdx.x * 256 + threadIdx.x;
    if (idx >= total) return;
    int d = idx & 511;
    int p = (idx >> 9) % 72;
    int g2 = idx / (72 * 512);
    X2[idx] = (p < 64) ? X[((size_t)g2 * 64 + p) * 512 + d]
                       : RT[(p - 64) * 512 + d];
}

// ---- gather xr[:,64:72,:] into dense (512,512) bf16 hi/lo -----------------
__global__ void gather_rows_kernel(const float* __restrict__ X2,
        ushort_t* __restrict__ RRH, ushort_t* __restrict__ RRL, int total) {
    int idx = blockIdx.x * 256 + threadIdx.x;
    if (idx >= total) return;
    int d = idx & 511;
    int row = idx >> 9;
    int g2 = row >> 3, rr = row & 7;
    float v = X2[((size_t)(g2 * 72 + 64 + rr)) * 512 + d];
    unsigned short h = f2bf(v);
    RRH[idx] = h;
    RRL[idx] = f2bf(v - bf2f(h));
}

// ---- l2-normalize each 128-half of each out row (l2n commutes w/ expand) --
__global__ __launch_bounds__(64) void norm_half_kernel(const float* __restrict__ IN,
        float* __restrict__ OUT) {
    int b = blockIdx.x; int lane = threadIdx.x;
    size_t base = (size_t)(b >> 1) * 256 + (size_t)(b & 1) * 128;
    float v0 = IN[base + lane], v1 = IN[base + 64 + lane];
    float ss = wave_sum64(v0 * v0 + v1 * v1);
    float sc = 1.0f / fmaxf(sqrtf(ss), 1e-12f);
    OUT[base + lane]      = v0 * sc;
    OUT[base + 64 + lane] = v1 * sc;
}

// ---- l2-normalize key columns: keys (32,128,16) over d --------------------
__global__ __launch_bounds__(64) void norm_keys_kernel(const float* __restrict__ Kin,
        float* __restrict__ Kout) {
    int b = blockIdx.x; int lane = threadIdx.x;
    int g = b >> 4, e = b & 15;
    size_t base = (size_t)g * 2048 + e;
    float v0 = Kin[base + (size_t)lane * 16];
    float v1 = Kin[base + (size_t)(lane + 64) * 16];
    float ss = wave_sum64(v0 * v0 + v1 * v1);
    float sc = 1.0f / fmaxf(sqrtf(ss), 1e-12f);
    Kout[base + (size_t)lane * 16]        = v0 * sc;
    Kout[base + (size_t)(lane + 64) * 16] = v1 * sc;
}

// ---- logits + top2 (stable, jax tie-break) --------------------------------
__global__ __launch_bounds__(64) void logits_top2_kernel(const float* __restrict__ OUTN,
        const float* __restrict__ KRN, const float* __restrict__ KGN,
        float* __restrict__ out) {
    int blk = blockIdx.x;
    int g = blk >> 6, bcol = blk & 63;
    int b = bcol >> 5, l = bcol & 31;
    int lsrc = (l + 31) & 31;     // roll(+1): element l comes from l-1
    int r = g >> 2;               // repeat RM=4
    int row = (b * 32 + lsrc) * 8 + r;
    const float* rvec = OUTN + (size_t)row * 256;
    __shared__ float sc[32];
    int lane = threadIdx.x;
    if (lane < 32) {
        int e = lane & 15;
        const float* kb = ((lane < 16) ? KRN : KGN) + (size_t)g * 2048 + e;
        const float* xv = (lane < 16) ? rvec : (rvec + 128);
        float s = 0.f;
#pragma unroll 8
        for (int d = 0; d < 128; ++d) s = fmaf(xv[d], kb[(size_t)d * 16], s);
        sc[lane] = s;
    }
    __syncthreads();
    if (lane == 0) {
        float bv = -1e30f, sv = -1e30f; int bi = 0, si = 0;
#pragma unroll
        for (int e = 0; e < 16; ++e) {
            float v = sc[e];
            if (v > bv) { sv = bv; si = bi; bv = v; bi = e; }
            else if (v > sv) { sv = v; si = e; }
        }
        size_t base = (size_t)g * 128 + (size_t)bcol * 2;
        out[base]            = bv;
        out[base + 1]        = sv;
        out[4096 + base]     = sc[16 + bi];
        out[4096 + base + 1] = sc[16 + si];
    }
}

// ---------------------------------------------------------------------------
static void run_layer(float* X, float* BIG, float* Qb,
                      ushort_t* KHb, ushort_t* KLb, ushort_t* VTHb, ushort_t* VTLb,
                      ushort_t* XNH, ushort_t* XNL, ushort_t* AOH, ushort_t* AOL,
                      ushort_t* MIDH, ushort_t* MIDL,
                      const unsigned short* WH, const unsigned short* WL,
                      const float* n1, const float* n2,
                      const int* doc, int G, int Sg, hipStream_t stream) {
    const size_t oQKV = 0, oO = 786432, oUP = 1048576, oDN = 2097152;
    int T = G * Sg;
    rmsnorm_kernel<<<T, 256, 0, stream>>>(X, n1, XNH, XNL);
    gemm3r<128><<<dim3(12, T / 64), 256, 0, stream>>>(XNH, XNL, WH + oQKV, WL + oQKV, nullptr, BIG, T, 1536, 512);
    int rp = T * 256;
    rope_pack_kernel<<<(rp + 255) / 256, 256, 0, stream>>>(BIG, Qb, KHb, KLb, Sg, rp);
    int qblocks = (Sg + 63) >> 6;
    vtrans_kernel<<<dim3(qblocks, G * 8), 256, 0, stream>>>(BIG, VTHb, VTLb, Sg);
    if (doc)
        attn3_kernel<true><<<dim3(qblocks, G * 8), 256, 0, stream>>>(Qb, KHb, KLb, VTHb, VTLb, doc, AOH, AOL, Sg);
    else
        attn3_kernel<false><<<dim3(qblocks, G * 8), 256, 0, stream>>>(Qb, KHb, KLb, VTHb, VTLb, nullptr, AOH, AOL, Sg);
    gemm3r<64><<<dim3(8, T / 64), 256, 0, stream>>>(AOH, AOL, WH + oO, WL + oO, X, X, T, 512, 512);
    rmsnorm_kernel<<<T, 256, 0, stream>>>(X, n2, XNH, XNL);
    gemm_up_silu<<<dim3(16, T / 64), 256, 0, stream>>>(XNH, XNL, WH + oUP, WL + oUP, MIDH, MIDL, 512);
    gemm3r<64><<<dim3(8, T / 64), 256, 0, stream>>>(MIDH, MIDL, WH + oDN, WL + oDN, X, X, T, 512, 1024);
}

static void split_layer(const float* qkv, const float* o, const float* up, const float* dn,
                        unsigned short* WH, unsigned short* WL, hipStream_t stream) {
    const size_t oQKV = 0, oO = 786432, oUP = 1048576, oDN = 2097152;
    wsplit_kernel<<<dim3(48, 16), 256, 0, stream>>>(qkv, WH + oQKV, WL + oQKV, 512, 1536);
    wsplit_kernel<<<dim3(16, 16), 256, 0, stream>>>(o,   WH + oO,   WL + oO,   512, 512);
    wsplit_kernel<<<dim3(64, 16), 256, 0, stream>>>(up,  WH + oUP,  WL + oUP,  512, 2048);
    wsplit_kernel<<<dim3(16, 32), 256, 0, stream>>>(dn,  WH + oDN,  WL + oDN,  1024, 512);
}

extern "C" void kernel_launch(void* const* d_in, const int* in_sizes, int n_in,
                              void* d_out, int out_size, void* d_ws, size_t ws_size,
                              hipStream_t stream) {
    const float* x_in    = (const float*)d_in[0];
    const int*   doc     = (const int*)d_in[1];
    const float* rt      = (const float*)d_in[2];
    const float* out_w   = (const float*)d_in[3];
    const float* k_rt    = (const float*)d_in[4];
    const float* k_gt    = (const float*)d_in[5];
    const float* enc_qkv = (const float*)d_in[6];
    const float* enc_o   = (const float*)d_in[7];
    const float* enc_up  = (const float*)d_in[8];
    const float* enc_dn  = (const float*)d_in[9];
    const float* enc_n1  = (const float*)d_in[10];
    const float* enc_n2  = (const float*)d_in[11];
    const float* rtr_qkv = (const float*)d_in[12];
    const float* rtr_o   = (const float*)d_in[13];
    const float* rtr_up  = (const float*)d_in[14];
    const float* rtr_dn  = (const float*)d_in[15];
    const float* rtr_n1  = (const float*)d_in[16];
    const float* rtr_n2  = (const float*)d_in[17];

    float* ws = (float*)d_ws;
    size_t off = 0;
    auto alloc = [&](size_t n) { float* p = ws + off; off += n; return p; };
    float* X    = alloc(4608UL * 512);
    float* X2   = alloc(4608UL * 512);
    float* BIG  = alloc(4608UL * 2048);
    float* Qb   = alloc(4608UL * 512);
    ushort_t* KHb  = (ushort_t*)alloc(1179648UL);
    ushort_t* KLb  = (ushort_t*)alloc(1179648UL);
    ushort_t* VTHb = (ushort_t*)alloc(1179648UL);
    ushort_t* VTLb = (ushort_t*)alloc(1179648UL);
    unsigned short* WH = (unsigned short*)(ws + off);
    unsigned short* WL = WH + 2621440UL;
    off += 2621440UL;
    // ---- dead-range aliases (stream-ordered, non-overlapping lifetimes) ----
    ushort_t* XNH = (ushort_t*)Qb;             // XN live rms->gemm; Qb live rope->attn
    ushort_t* XNL = XNH + 4608UL * 512;
    ushort_t* AOH = (ushort_t*)BIG;            // AO in BIG (QKV dead after rope/vtrans)
    ushort_t* AOL = AOH + 4608UL * 512;
    ushort_t* MIDH = (ushort_t*)BIG;           // MID in BIG (AO dead after o-proj)
    ushort_t* MIDL = MIDH + 4608UL * 1024;
    ushort_t* RRH = (ushort_t*)X;              // X dead after router_build
    ushort_t* RRL = RRH + 262144;
    float* OUTM = X + 262144;
    float* OUTN = X + 393216;
    float* KRN  = X + 524288;
    float* KGN  = X + 589824;
    (void)ws_size; (void)in_sizes; (void)n_in; (void)out_size;

    copy_in_kernel<<<(2097152 + 255) / 256, 256, 0, stream>>>(x_in, X, 2097152);

    for (int i = 0; i < 4; ++i) {
        split_layer(enc_qkv + (size_t)i * 512 * 1536,
                    enc_o   + (size_t)i * 512 * 512,
                    enc_up  + (size_t)i * 512 * 2048,
                    enc_dn  + (size_t)i * 1024 * 512, WH, WL, stream);
        run_layer(X, BIG, Qb, KHb, KLb, VTHb, VTLb, XNH, XNL, AOH, AOL, MIDH, MIDL,
                  WH, WL, enc_n1 + (size_t)i * 512, enc_n2 + (size_t)i * 512,
                  doc, 2, 2048, stream);
    }

    int rb_total = 64 * 72 * 512;
    router_build_kernel<<<(rb_total + 255) / 256, 256, 0, stream>>>(X, rt, X2, rb_total);

    for (int i = 0; i < 2; ++i) {
        split_layer(rtr_qkv + (size_t)i * 512 * 1536,
                    rtr_o   + (size_t)i * 512 * 512,
                    rtr_up  + (size_t)i * 512 * 2048,
                    rtr_dn  + (size_t)i * 1024 * 512, WH, WL, stream);
        run_layer(X2, BIG, Qb, KHb, KLb, VTHb, VTLb, XNH, XNL, AOH, AOL, MIDH, MIDL,
                  WH, WL, rtr_n1 + (size_t)i * 512, rtr_n2 + (size_t)i * 512,
                  nullptr, 64, 72, stream);
    }

    gather_rows_kernel<<<(512 * 512) / 256, 256, 0, stream>>>(X2, RRH, RRL, 512 * 512);
    wsplit_kernel<<<dim3(8, 16), 256, 0, stream>>>(out_w, WH, WL, 512, 256);
    gemm3r<64><<<dim3(4, 8), 256, 0, stream>>>(RRH, RRL, WH, WL, nullptr, OUTM, 512, 256, 512);

    norm_half_kernel<<<1024, 64, 0, stream>>>(OUTM, OUTN);
    norm_keys_kernel<<<512, 64, 0, stream>>>(k_rt, KRN);
    norm_keys_kernel<<<512, 64, 0, stream>>>(k_gt, KGN);
    logits_top2_kernel<<<2048, 64, 0, stream>>>(OUTN, KRN, KGN, (float*)d_out);
}

// Round 8
// 1285.631 us; speedup vs baseline: 1.2269x; 1.2269x over previous
//
#include <hip/hip_runtime.h>
#include <hip/hip_bf16.h>
#include <cstdint>

// ---------------------------------------------------------------------------
// B=2 S=2048 D=512 H=8 HD=64, FFH=1024. Encoder: 4 layers, G=2, Sg=2048
// (block-causal-64 AND doc mask). Router: 2 layers, G=64, Sg=72, full attn.
// Round 17: revert r7 (reg-A refuted: scattered A gathers coupled into
// vmcnt(0) + halved per-iter MFMA density -> +277us). Back to r6 base
// (1300us), then raise waves/SIMD without shrinking tiles:
//  - gemm3w: 512-thr (8 waves, 4Mx2N), BM=128xBN=128, 2-set 64KB ->
//    2 blk/CU = 4 waves/SIMD (qkv). Same r6 schedule + swizzle.
//  - gemm_up_silu: 512-thr, M-tile 128 x 64 h-cols, both panels, 64KB.
//  - o/dn/final keep r6 gemm3<64> (N=512 grids need small tiles).
// ---------------------------------------------------------------------------

typedef __attribute__((ext_vector_type(8))) short short8;   // 8 bf16 = 4 VGPR
typedef __attribute__((ext_vector_type(4))) float f32x4;
typedef unsigned short ushort_t;

__device__ __forceinline__ float bf2f(unsigned short u) {
    return __uint_as_float(((unsigned)u) << 16);
}
__device__ __forceinline__ unsigned short f2bf(float f) {
    unsigned u = __float_as_uint(f);
    unsigned r = 0x7FFFu + ((u >> 16) & 1u);
    return (unsigned short)((u + r) >> 16);
}
__device__ __forceinline__ float wave_sum64(float v) {
#pragma unroll
    for (int o = 32; o; o >>= 1) v += __shfl_xor(v, o);
    return v;
}
__device__ __forceinline__ void load_lds16(const ushort_t* g, ushort_t* l) {
    __builtin_amdgcn_global_load_lds(
        (const __attribute__((address_space(1))) unsigned int*)g,
        (__attribute__((address_space(3))) unsigned int*)l, 16, 0, 0);
}

#define MFMA16(a, b, c) __builtin_amdgcn_mfma_f32_16x16x32_bf16(a, b, c, 0, 0, 0)
#define BARRIER_RAW() do { asm volatile("" ::: "memory"); \
    __builtin_amdgcn_s_barrier(); asm volatile("" ::: "memory"); } while (0)
#define VMCNT0() asm volatile("s_waitcnt vmcnt(0)" ::: "memory")

// ---- f32 copy (input x -> mutable X) --------------------------------------
__global__ void copy_in_kernel(const float* __restrict__ src,
                               float* __restrict__ dst, int n) {
    int i = blockIdx.x * 256 + threadIdx.x;
    if (i < n) dst[i] = src[i];
}

// ---- weight transpose + hi/lo bf16 split: W[K,N] -> WT_hi/lo[N,K] ---------
__global__ __launch_bounds__(256) void wsplit_kernel(const float* __restrict__ W,
        unsigned short* __restrict__ WH, unsigned short* __restrict__ WL,
        int K, int N) {
    __shared__ float tile[32][33];
    int bn = blockIdx.x * 32, bk = blockIdx.y * 32;
    int tx = threadIdx.x & 31, ty = threadIdx.x >> 5;
#pragma unroll
    for (int i = 0; i < 4; ++i)
        tile[ty + 8 * i][tx] = W[(size_t)(bk + ty + 8 * i) * N + bn + tx];
    __syncthreads();
#pragma unroll
    for (int i = 0; i < 4; ++i) {
        int n = bn + ty + 8 * i, k = bk + tx;
        float x = tile[tx][ty + 8 * i];
        unsigned short h = f2bf(x);
        unsigned short lo = f2bf(x - bf2f(h));
        WH[(size_t)n * K + k] = h;
        WL[(size_t)n * K + k] = lo;
    }
}

// ---- RMSNorm over D=512, emits bf16 hi/lo ---------------------------------
__global__ __launch_bounds__(256) void rmsnorm_kernel(const float* __restrict__ X,
        const float* __restrict__ W, ushort_t* __restrict__ XNH,
        ushort_t* __restrict__ XNL) {
    int t = blockIdx.x, tid = threadIdx.x;
    const float* xr = X + (size_t)t * 512;
    float v0 = xr[tid], v1 = xr[tid + 256];
    float ss = wave_sum64(v0 * v0 + v1 * v1);
    __shared__ float red[4];
    if ((tid & 63) == 0) red[tid >> 6] = ss;
    __syncthreads();
    float tot = red[0] + red[1] + red[2] + red[3];
    float scale = rsqrtf(tot * (1.0f / 512.0f) + 1e-6f);
    float a0 = v0 * scale * W[tid];
    float a1 = v1 * scale * W[tid + 256];
    unsigned short h0 = f2bf(a0), h1 = f2bf(a1);
    size_t base = (size_t)t * 512;
    XNH[base + tid]       = h0;
    XNL[base + tid]       = f2bf(a0 - bf2f(h0));
    XNH[base + tid + 256] = h1;
    XNL[base + tid + 256] = f2bf(a1 - bf2f(h1));
}

// ---- bf16x3 MFMA GEMM: 2-set LDS (48KB -> 3 blk/CU), depth-1 stage --------
// C[M,N] = A @ B^T (+Res). Tile 64x128, BK=32, 256 thr = 4 waves, wave 32x64.
// Flat set rows: [0,64)=Ah, [64,128)=Al, [128,256)=Bh, [256,384)=Bl.
// Per iter: STAGE(cur^1, kc+1); ds_read+MFMA(cur); vmcnt(0); raw barrier.
template <int BM>
__global__ __launch_bounds__(256) void gemm3(
        const ushort_t* __restrict__ AH, const ushort_t* __restrict__ AL,
        const ushort_t* __restrict__ BH, const ushort_t* __restrict__ BL,
        const float* __restrict__ Res, float* __restrict__ C,
        int M, int N, int K) {
    constexpr int MI   = BM / 32;        // M-frags per wave
    constexpr int ROWS = 2 * BM + 256;   // rows per set (Ah|Al|Bh|Bl)
    constexpr int LPW  = ROWS / 64;      // gload_lds per wave per stage
    constexpr int SS   = ROWS * 32;      // ushorts per set
    __shared__ __align__(16) ushort_t S[2][ROWS][32];
    int tid = threadIdx.x;
    int n0 = blockIdx.x * 128, m0 = blockIdx.y * BM;
    int wid = tid >> 6, lane = tid & 63;
    int wm = (wid >> 1) * (BM / 2), wn = (wid & 1) * 64;
    int col = lane & 15, quad = lane >> 4;

    const ushort_t* gsrc[LPW];
    int ldof[LPW];
#pragma unroll
    for (int j = 0; j < LPW; ++j) {
        int e = wid * LPW + j;
        int srow = e * 16 + (lane >> 2);
        const ushort_t* gp; int rin;
        if (srow < BM)                { gp = AH + (size_t)m0 * K; rin = srow; }
        else if (srow < 2 * BM)       { gp = AL + (size_t)m0 * K; rin = srow - BM; }
        else if (srow < 2 * BM + 128) { gp = BH + (size_t)n0 * K; rin = srow - 2 * BM; }
        else                          { gp = BL + (size_t)n0 * K; rin = srow - 2 * BM - 128; }
        gsrc[j] = gp + (size_t)rin * K + ((lane & 3) ^ ((lane >> 3) & 3)) * 8;
        ldof[j] = e * 512;
    }
    ushort_t* sbase = &S[0][0][0];
    auto STAGE = [&](int set, int kc) {
        ushort_t* sb = sbase + set * SS;
#pragma unroll
        for (int j = 0; j < LPW; ++j)
            load_lds16(gsrc[j] + kc * 32, sb + ldof[j]);
    };

    int chrd = (quad ^ ((col >> 1) & 3)) * 8;   // read-side swizzled chunk
    f32x4 acc[MI][4] = {};
    int nk = K >> 5;
    STAGE(0, 0);
    VMCNT0();
    BARRIER_RAW();
    int cur = 0;
#pragma unroll 1
    for (int kc = 0; kc < nk; ++kc) {
        if (kc + 1 < nk) STAGE(cur ^ 1, kc + 1);   // fly during compute(cur)
        const ushort_t* sb = sbase + cur * SS;
        short8 afh[MI], afl[MI], bfh[4], bfl[4];
#pragma unroll
        for (int i = 0; i < MI; ++i) {
            afh[i] = *(const short8*)(sb + (size_t)(wm + i * 16 + col) * 32 + chrd);
            afl[i] = *(const short8*)(sb + (size_t)(BM + wm + i * 16 + col) * 32 + chrd);
        }
#pragma unroll
        for (int i = 0; i < 4; ++i) {
            bfh[i] = *(const short8*)(sb + (size_t)(2 * BM + wn + i * 16 + col) * 32 + chrd);
            bfl[i] = *(const short8*)(sb + (size_t)(2 * BM + 128 + wn + i * 16 + col) * 32 + chrd);
        }
#pragma unroll
        for (int mi = 0; mi < MI; ++mi)
#pragma unroll
            for (int ni = 0; ni < 4; ++ni) {
                f32x4 c = acc[mi][ni];
                c = MFMA16(afh[mi], bfh[ni], c);
                c = MFMA16(afh[mi], bfl[ni], c);
                c = MFMA16(afl[mi], bfh[ni], c);
                acc[mi][ni] = c;
            }
        if (kc + 1 < nk) {
            VMCNT0();           // next set's loads landed
            BARRIER_RAW();      // all waves done reading cur
            cur ^= 1;
        }
    }
#pragma unroll
    for (int mi = 0; mi < MI; ++mi)
#pragma unroll
        for (int ni = 0; ni < 4; ++ni)
#pragma unroll
            for (int r = 0; r < 4; ++r) {
                int row = m0 + wm + mi * 16 + quad * 4 + r;
                int ccol = n0 + wn + ni * 16 + col;
                size_t o = (size_t)row * N + ccol;
                float v = acc[mi][ni][r];
                if (Res) v += Res[o];
                C[o] = v;
            }
}

// ---- bf16x3 GEMM, 512 thr (8 waves 4Mx2N), 128x128 tile, 2-set 64KB -------
// Set rows: [0,128)=Ah [128,256)=Al [256,384)=Bh [384,512)=Bl. LPW=4.
// 2 blk/CU = 16 waves/CU = 4 waves/SIMD. Same r6 schedule + swizzle.
__global__ __launch_bounds__(512, 4) void gemm3w(
        const ushort_t* __restrict__ AH, const ushort_t* __restrict__ AL,
        const ushort_t* __restrict__ BH, const ushort_t* __restrict__ BL,
        const float* __restrict__ Res, float* __restrict__ C,
        int M, int N, int K) {
    constexpr int ROWS = 512;
    constexpr int LPW  = 4;
    constexpr int SS   = ROWS * 32;
    __shared__ __align__(16) ushort_t S[2][ROWS][32];
    int tid = threadIdx.x;
    int n0 = blockIdx.x * 128, m0 = blockIdx.y * 128;
    int wid = tid >> 6, lane = tid & 63;
    int wm = (wid >> 1) * 32, wn = (wid & 1) * 64;
    int col = lane & 15, quad = lane >> 4;

    const ushort_t* gsrc[LPW];
    int ldof[LPW];
#pragma unroll
    for (int j = 0; j < LPW; ++j) {
        int e = wid * LPW + j;
        int srow = e * 16 + (lane >> 2);
        const ushort_t* gp; int rin;
        if (srow < 128)      { gp = AH; rin = m0 + srow; }
        else if (srow < 256) { gp = AL; rin = m0 + srow - 128; }
        else if (srow < 384) { gp = BH; rin = n0 + srow - 256; }
        else                 { gp = BL; rin = n0 + srow - 384; }
        gsrc[j] = gp + (size_t)rin * K + ((lane & 3) ^ ((lane >> 3) & 3)) * 8;
        ldof[j] = e * 512;
    }
    ushort_t* sbase = &S[0][0][0];
    auto STAGE = [&](int set, int kc) {
        ushort_t* sb = sbase + set * SS;
#pragma unroll
        for (int j = 0; j < LPW; ++j)
            load_lds16(gsrc[j] + kc * 32, sb + ldof[j]);
    };

    int chrd = (quad ^ ((col >> 1) & 3)) * 8;
    f32x4 acc[2][4] = {};
    int nk = K >> 5;
    STAGE(0, 0);
    VMCNT0();
    BARRIER_RAW();
    int cur = 0;
#pragma unroll 1
    for (int kc = 0; kc < nk; ++kc) {
        if (kc + 1 < nk) STAGE(cur ^ 1, kc + 1);
        const ushort_t* sb = sbase + cur * SS;
        short8 afh[2], afl[2], bfh[4], bfl[4];
#pragma unroll
        for (int i = 0; i < 2; ++i) {
            afh[i] = *(const short8*)(sb + (size_t)(wm + i * 16 + col) * 32 + chrd);
            afl[i] = *(const short8*)(sb + (size_t)(128 + wm + i * 16 + col) * 32 + chrd);
        }
#pragma unroll
        for (int i = 0; i < 4; ++i) {
            bfh[i] = *(const short8*)(sb + (size_t)(256 + wn + i * 16 + col) * 32 + chrd);
            bfl[i] = *(const short8*)(sb + (size_t)(384 + wn + i * 16 + col) * 32 + chrd);
        }
#pragma unroll
        for (int mi = 0; mi < 2; ++mi)
#pragma unroll
            for (int ni = 0; ni < 4; ++ni) {
                f32x4 c = acc[mi][ni];
                c = MFMA16(afh[mi], bfh[ni], c);
                c = MFMA16(afh[mi], bfl[ni], c);
                c = MFMA16(afl[mi], bfh[ni], c);
                acc[mi][ni] = c;
            }
        if (kc + 1 < nk) {
            VMCNT0();
            BARRIER_RAW();
            cur ^= 1;
        }
    }
#pragma unroll
    for (int mi = 0; mi < 2; ++mi)
#pragma unroll
        for (int ni = 0; ni < 4; ++ni)
#pragma unroll
            for (int r = 0; r < 4; ++r) {
                int row = m0 + wm + mi * 16 + quad * 4 + r;
                int ccol = n0 + wn + ni * 16 + col;
                size_t o = (size_t)row * N + ccol;
                float v = acc[mi][ni][r];
                if (Res) v += Res[o];
                C[o] = v;
            }
}

// ---- fused up-proj + silu, 512 thr: MID = silu(A@W1^T)*(A@W2^T) -----------
// M-tile 128, 64 h-cols. 8 waves (4Mx2H), wave 32M x 32h, both panels.
// Set rows: [0,128)Ah [128,256)Al [256,320)B1h [320,384)B1l [384,448)B2h
// [448,512)B2l. 2 sets = 64KB -> 2 blk/CU. Grid (16, T/128).
__global__ __launch_bounds__(512, 4) void gemm_up_silu(
        const ushort_t* __restrict__ AH, const ushort_t* __restrict__ AL,
        const ushort_t* __restrict__ BH, const ushort_t* __restrict__ BL,
        ushort_t* __restrict__ MIDH, ushort_t* __restrict__ MIDL, int K) {
    constexpr int ROWS = 512;
    constexpr int LPW  = 4;
    constexpr int SS   = ROWS * 32;
    __shared__ __align__(16) ushort_t S[2][ROWS][32];
    int tid = threadIdx.x;
    int n0 = blockIdx.x * 64, m0 = blockIdx.y * 128;
    int wid = tid >> 6, lane = tid & 63;
    int wm = (wid >> 1) * 32, wn = (wid & 1) * 32;
    int col = lane & 15, quad = lane >> 4;

    const ushort_t* gsrc[LPW];
    int ldof[LPW];
#pragma unroll
    for (int j = 0; j < LPW; ++j) {
        int e = wid * LPW + j;
        int srow = e * 16 + (lane >> 2);
        const ushort_t* gp; int rin;
        if (srow < 128)      { gp = AH; rin = m0 + srow; }
        else if (srow < 256) { gp = AL; rin = m0 + srow - 128; }
        else if (srow < 320) { gp = BH; rin = n0 + srow - 256; }
        else if (srow < 384) { gp = BL; rin = n0 + srow - 320; }
        else if (srow < 448) { gp = BH; rin = 1024 + n0 + srow - 384; }
        else                 { gp = BL; rin = 1024 + n0 + srow - 448; }
        gsrc[j] = gp + (size_t)rin * K + ((lane & 3) ^ ((lane >> 3) & 3)) * 8;
        ldof[j] = e * 512;
    }
    ushort_t* sbase = &S[0][0][0];
    auto STAGE = [&](int set, int kc) {
        ushort_t* sb = sbase + set * SS;
#pragma unroll
        for (int j = 0; j < LPW; ++j)
            load_lds16(gsrc[j] + kc * 32, sb + ldof[j]);
    };

    int chrd = (quad ^ ((col >> 1) & 3)) * 8;
    f32x4 a1[2][2] = {}, a2[2][2] = {};
    int nk = K >> 5;
    STAGE(0, 0);
    VMCNT0();
    BARRIER_RAW();
    int cur = 0;
#pragma unroll 1
    for (int kc = 0; kc < nk; ++kc) {
        if (kc + 1 < nk) STAGE(cur ^ 1, kc + 1);
        const ushort_t* sb = sbase + cur * SS;
        short8 afh[2], afl[2], b1h[2], b1l[2], b2h[2], b2l[2];
#pragma unroll
        for (int i = 0; i < 2; ++i) {
            afh[i] = *(const short8*)(sb + (size_t)(wm + i * 16 + col) * 32 + chrd);
            afl[i] = *(const short8*)(sb + (size_t)(128 + wm + i * 16 + col) * 32 + chrd);
            b1h[i] = *(const short8*)(sb + (size_t)(256 + wn + i * 16 + col) * 32 + chrd);
            b1l[i] = *(const short8*)(sb + (size_t)(320 + wn + i * 16 + col) * 32 + chrd);
            b2h[i] = *(const short8*)(sb + (size_t)(384 + wn + i * 16 + col) * 32 + chrd);
            b2l[i] = *(const short8*)(sb + (size_t)(448 + wn + i * 16 + col) * 32 + chrd);
        }
#pragma unroll
        for (int mi = 0; mi < 2; ++mi)
#pragma unroll
            for (int ni = 0; ni < 2; ++ni) {
                f32x4 c = a1[mi][ni];
                c = MFMA16(afh[mi], b1h[ni], c);
                c = MFMA16(afh[mi], b1l[ni], c);
                c = MFMA16(afl[mi], b1h[ni], c);
                a1[mi][ni] = c;
                f32x4 d = a2[mi][ni];
                d = MFMA16(afh[mi], b2h[ni], d);
                d = MFMA16(afh[mi], b2l[ni], d);
                d = MFMA16(afl[mi], b2h[ni], d);
                a2[mi][ni] = d;
            }
        if (kc + 1 < nk) {
            VMCNT0();
            BARRIER_RAW();
            cur ^= 1;
        }
    }
#pragma unroll
    for (int mi = 0; mi < 2; ++mi)
#pragma unroll
        for (int ni = 0; ni < 2; ++ni)
#pragma unroll
            for (int r = 0; r < 4; ++r) {
                int row = m0 + wm + mi * 16 + quad * 4 + r;
                int ccol = n0 + wn + ni * 16 + col;
                float v1 = a1[mi][ni][r], v2 = a2[mi][ni][r];
                float rr = (v1 / (1.0f + __expf(-v1))) * v2;
                unsigned short h = f2bf(rr);
                size_t o = (size_t)row * 1024 + ccol;
                MIDH[o] = h;
                MIDL[o] = f2bf(rr - bf2f(h));
            }
}

// ---- split qkv + RoPE; Q f32 (g,h,s,hd); K bf16 hi/lo [gh][Sg][64] --------
__global__ void rope_pack_kernel(const float* __restrict__ QKV,
        float* __restrict__ Q, ushort_t* __restrict__ KH,
        ushort_t* __restrict__ KL, int Sg, int total) {
    int idx = blockIdx.x * 256 + threadIdx.x;
    if (idx >= total) return;
    int i = idx & 31;
    int h = (idx >> 5) & 7;
    int t = idx >> 8;
    int g = t / Sg; int s = t - g * Sg;
    const float* row = QKV + (size_t)t * 1536;
    float inv = powf(10000.0f, -(float)(2 * i) / 64.0f);
    float sn, cs;
    sincosf((float)s * inv, &sn, &cs);
    size_t ob = ((size_t)(g * 8 + h) * Sg + s) * 64 + i;
    int c = h * 64 + i;
    float q1 = row[c], q2 = row[c + 32];
    Q[ob]      = q1 * cs + q2 * sn;
    Q[ob + 32] = q2 * cs - q1 * sn;
    float k1 = row[512 + c], k2 = row[512 + c + 32];
    float ka = k1 * cs + k2 * sn;
    float kb = k2 * cs - k1 * sn;
    unsigned short ha = f2bf(ka), hb = f2bf(kb);
    KH[ob]      = ha;  KL[ob]      = f2bf(ka - bf2f(ha));
    KH[ob + 32] = hb;  KL[ob + 32] = f2bf(kb - bf2f(hb));
}

// ---- V^T split: QKV f32 [T][1536] -> VT hi/lo [gh][64 d][Sg s] ------------
__global__ __launch_bounds__(256) void vtrans_kernel(const float* __restrict__ QKV,
        ushort_t* __restrict__ VTH, ushort_t* __restrict__ VTL, int Sg) {
    __shared__ float tile[64][65];
    int chunk = blockIdx.x, gh = blockIdx.y;
    int g = gh >> 3, h = gh & 7;
    int tid = threadIdx.x;
    int sr = tid >> 2, dc = (tid & 3) * 16;
    int s = chunk * 64 + sr;
    if (s < Sg) {
        const float* src = QKV + ((size_t)g * Sg + s) * 1536 + 1024 + h * 64 + dc;
#pragma unroll
        for (int j = 0; j < 4; ++j) {
            float4 v = *(const float4*)(src + 4 * j);
            tile[sr][dc + 4 * j]     = v.x;
            tile[sr][dc + 4 * j + 1] = v.y;
            tile[sr][dc + 4 * j + 2] = v.z;
            tile[sr][dc + 4 * j + 3] = v.w;
        }
    } else {
#pragma unroll
        for (int j = 0; j < 16; ++j) tile[sr][dc + j] = 0.f;
    }
    __syncthreads();
    int dr = tid >> 2, sc = (tid & 3) * 16;
    short8 hv[2], lv[2];
#pragma unroll
    for (int half = 0; half < 2; ++half)
#pragma unroll
        for (int j = 0; j < 8; ++j) {
            float v = tile[sc + half * 8 + j][dr];
            unsigned short hb = f2bf(v);
            hv[half][j] = (short)hb;
            lv[half][j] = (short)f2bf(v - bf2f(hb));
        }
    int scol = chunk * 64 + sc;
    size_t ob = ((size_t)gh * 64 + dr) * Sg + scol;
    if (scol + 16 <= Sg) {
        *(short8*)(VTH + ob)     = hv[0];
        *(short8*)(VTH + ob + 8) = hv[1];
        *(short8*)(VTL + ob)     = lv[0];
        *(short8*)(VTL + ob + 8) = lv[1];
    } else {
#pragma unroll
        for (int j = 0; j < 16; ++j)
            if (scol + j < Sg) {
                VTH[ob + j] = (ushort_t)((j < 8) ? hv[0][j] : hv[1][j - 8]);
                VTL[ob + j] = (ushort_t)((j < 8) ? lv[0][j] : lv[1][j - 8]);
            }
    }
}

// ---- MFMA flash attention (bf16x3), K/V pre-split, gload_lds + XOR swz ----
template <bool MASKED>
__global__ __launch_bounds__(256, 3) void attn3_kernel(const float* __restrict__ Q,
        const ushort_t* __restrict__ KHg, const ushort_t* __restrict__ KLg,
        const ushort_t* __restrict__ VTHg, const ushort_t* __restrict__ VTLg,
        const int* __restrict__ doc, ushort_t* __restrict__ AOH,
        ushort_t* __restrict__ AOL, int Sg) {
    __shared__ __align__(16) ushort_t Khs[64][64], Kls[64][64];  // swizzled
    __shared__ __align__(16) ushort_t Vts[64][64], Vtl[64][64];  // swizzled
    __shared__ __align__(16) ushort_t Ph[4][16][72], Pl[4][16][72];
    __shared__ int dock[64];
    int qb = (int)(gridDim.x - 1 - blockIdx.x);   // big qb first (load balance)
    int gh = blockIdx.y, g = gh >> 3;
    int tid = threadIdx.x, wid = tid >> 6, lane = tid & 63;
    int col = lane & 15, quad = lane >> 4;

    int rL = lane >> 3, cSw = (lane & 7) ^ rL;
    const ushort_t* kb;      // K waves: row base (chunk folded in)
    const ushort_t* vb;      // V waves: d-row base
    ushort_t* lb;
    if (wid == 0)      { kb = KHg + (size_t)gh * Sg * 64 + cSw * 8;  vb = nullptr; lb = &Khs[0][0]; }
    else if (wid == 1) { kb = KLg + (size_t)gh * Sg * 64 + cSw * 8;  vb = nullptr; lb = &Kls[0][0]; }
    else if (wid == 2) { vb = VTHg + ((size_t)gh * 64 + rL) * Sg;    kb = nullptr; lb = &Vts[0][0]; }
    else               { vb = VTLg + ((size_t)gh * 64 + rL) * Sg;    kb = nullptr; lb = &Vtl[0][0]; }
    int sw0 = ((0 + quad) ^ (col & 7)) * 8;
    int sw1 = ((4 + quad) ^ (col & 7)) * 8;

    short8 qa[2][2];  // [kk][0=hi,1=lo]
    {
        int qrow = qb * 64 + wid * 16 + col;
        if (qrow >= Sg) qrow = Sg - 1;
        const float* Qg = Q + ((size_t)gh * Sg + qrow) * 64 + quad * 8;
#pragma unroll
        for (int kk = 0; kk < 2; ++kk) {
            float4 v0 = *(const float4*)(Qg + kk * 32);
            float4 v1 = *(const float4*)(Qg + kk * 32 + 4);
            float vv[8] = {v0.x, v0.y, v0.z, v0.w, v1.x, v1.y, v1.z, v1.w};
            short8 h, l;
#pragma unroll
            for (int e = 0; e < 8; ++e) {
                float x = vv[e] * 0.125f;
                unsigned short hb = f2bf(x);
                h[e] = (short)hb;
                l[e] = (short)f2bf(x - bf2f(hb));
            }
            qa[kk][0] = h; qa[kk][1] = l;
        }
    }
    int dqr[4]; int wq0 = 0, wq1 = 0, bq0 = 0, bq1 = 0;
    if (MASKED) {
        const int* db = doc + (size_t)g * Sg + qb * 64;
#pragma unroll
        for (int r = 0; r < 4; ++r) dqr[r] = db[wid * 16 + quad * 4 + r];
        wq0 = db[wid * 16]; wq1 = db[wid * 16 + 15];
        bq0 = db[0];        bq1 = db[63];
    }
    float m[4], l[4];
    f32x4 accO[4];
#pragma unroll
    for (int r = 0; r < 4; ++r) { m[r] = -1e30f; l[r] = 0.f; }
#pragma unroll
    for (int nd = 0; nd < 4; ++nd) accO[nd] = (f32x4){0.f, 0.f, 0.f, 0.f};

    int nkt = MASKED ? (qb + 1) : ((Sg + 63) >> 6);
    for (int kt = 0; kt < nkt; ++kt) {
        int kval = Sg - kt * 64; if (kval > 64) kval = 64;
        __syncthreads();
        if (MASKED) {
            if (tid < 64) dock[tid] = doc[(size_t)g * Sg + kt * 64 + tid];
            __syncthreads();
        }
        bool bskip = false;
        if (MASKED) bskip = (dock[63] < bq0) || (dock[0] > bq1);
        if (!bskip) {
            if (wid < 2) {
#pragma unroll
                for (int p = 0; p < 8; ++p) {
                    int sr2 = kt * 64 + p * 8 + rL;
                    if (sr2 > Sg - 1) sr2 = Sg - 1;
                    load_lds16(kb + (size_t)sr2 * 64, lb + p * 512);
                }
            } else {
                int vc = kt * 64 + cSw * 8;
                if (vc > Sg - 8) vc = Sg - 8;
#pragma unroll
                for (int p = 0; p < 8; ++p)
                    load_lds16(vb + (size_t)(p * 8) * Sg + vc, lb + p * 512);
            }
            __syncthreads();
            bool wskip = false;
            if (MASKED) wskip = (dock[kval - 1] < wq0) || (dock[0] > wq1);
            if (!wskip) {
                int dk[4];
                if (MASKED) {
#pragma unroll
                    for (int ni = 0; ni < 4; ++ni) dk[ni] = dock[ni * 16 + col];
                }
                f32x4 sc[4];
#pragma unroll
                for (int ni = 0; ni < 4; ++ni) {
                    int rb = (ni * 16 + col) * 64;
                    short8 bh0 = *(const short8*)(&Khs[0][0] + rb + sw0);
                    short8 bl0 = *(const short8*)(&Kls[0][0] + rb + sw0);
                    short8 bh1 = *(const short8*)(&Khs[0][0] + rb + sw1);
                    short8 bl1 = *(const short8*)(&Kls[0][0] + rb + sw1);
                    f32x4 c = (f32x4){0.f, 0.f, 0.f, 0.f};
                    c = MFMA16(qa[0][0], bh0, c);
                    c = MFMA16(qa[0][0], bl0, c);
                    c = MFMA16(qa[0][1], bh0, c);
                    c = MFMA16(qa[1][0], bh1, c);
                    c = MFMA16(qa[1][0], bl1, c);
                    c = MFMA16(qa[1][1], bh1, c);
                    sc[ni] = c;
                }
                float mnew[4];
#pragma unroll
                for (int r = 0; r < 4; ++r) mnew[r] = -1e30f;
#pragma unroll
                for (int ni = 0; ni < 4; ++ni)
#pragma unroll
                    for (int r = 0; r < 4; ++r) {
                        bool ok = MASKED ? (dk[ni] == dqr[r]) : (ni * 16 + col < kval);
                        float s = ok ? sc[ni][r] : -1e30f;
                        sc[ni][r] = s;
                        mnew[r] = fmaxf(mnew[r], s);
                    }
#pragma unroll
                for (int r = 0; r < 4; ++r)
#pragma unroll
                    for (int o = 1; o < 16; o <<= 1)
                        mnew[r] = fmaxf(mnew[r], __shfl_xor(mnew[r], o));
                float alpha[4], lsum[4];
#pragma unroll
                for (int r = 0; r < 4; ++r) {
                    float M = fmaxf(m[r], mnew[r]);
                    alpha[r] = __expf(m[r] - M);
                    m[r] = M;
                    lsum[r] = 0.f;
                }
#pragma unroll
                for (int ni = 0; ni < 4; ++ni)
#pragma unroll
                    for (int r = 0; r < 4; ++r) {
                        bool ok = MASKED ? (dk[ni] == dqr[r]) : (ni * 16 + col < kval);
                        float p = ok ? __expf(sc[ni][r] - m[r]) : 0.f;
                        lsum[r] += p;
                        unsigned short h = f2bf(p);
                        Ph[wid][quad * 4 + r][ni * 16 + col] = h;
                        Pl[wid][quad * 4 + r][ni * 16 + col] = f2bf(p - bf2f(h));
                    }
#pragma unroll
                for (int r = 0; r < 4; ++r) {
#pragma unroll
                    for (int o = 1; o < 16; o <<= 1)
                        lsum[r] += __shfl_xor(lsum[r], o);
                    l[r] = l[r] * alpha[r] + lsum[r];
                }
#pragma unroll
                for (int nd = 0; nd < 4; ++nd)
#pragma unroll
                    for (int r = 0; r < 4; ++r) accO[nd][r] *= alpha[r];
#pragma unroll
                for (int kk = 0; kk < 2; ++kk) {
                    short8 pah = *(const short8*)&Ph[wid][col][kk * 32 + quad * 8];
                    short8 pal = *(const short8*)&Pl[wid][col][kk * 32 + quad * 8];
                    int sw = kk ? sw1 : sw0;
#pragma unroll
                    for (int nd = 0; nd < 4; ++nd) {
                        int rb = (nd * 16 + col) * 64;
                        short8 vbh = *(const short8*)(&Vts[0][0] + rb + sw);
                        short8 vbl = *(const short8*)(&Vtl[0][0] + rb + sw);
                        f32x4 c = accO[nd];
                        c = MFMA16(pah, vbh, c);
                        c = MFMA16(pah, vbl, c);
                        c = MFMA16(pal, vbh, c);
                        accO[nd] = c;
                    }
                }
            }
        }
    }
#pragma unroll
    for (int r = 0; r < 4; ++r) {
        int qrow = qb * 64 + wid * 16 + quad * 4 + r;
        if (qrow < Sg) {
            float inv = 1.0f / l[r];
            size_t base = ((size_t)g * Sg + qrow) * 512 + (gh & 7) * 64;
#pragma unroll
            for (int nd = 0; nd < 4; ++nd) {
                float val = accO[nd][r] * inv;
                unsigned short h = f2bf(val);
                AOH[base + nd * 16 + col] = h;
                AOL[base + nd * 16 + col] = f2bf(val - bf2f(h));
            }
        }
    }
}

// ---- build router stream: (64 groups) x (64 tokens + 8 router tokens) -----
__global__ void router_build_kernel(const float* __restrict__ X,
        const float* __restrict__ RT, float* __restrict__ X2, int total) {
    int idx = blockIdx.x * 256 + threadIdx.x;
    if (idx >= total) return;
    int d = idx & 511;
    int p = (idx >> 9) % 72;
    int g2 = idx / (72 * 512);
    X2[idx] = (p < 64) ? X[((size_t)g2 * 64 + p) * 512 + d]
                       : RT[(p - 64) * 512 + d];
}

// ---- gather xr[:,64:72,:] into dense (512,512) bf16 hi/lo -----------------
__global__ void gather_rows_kernel(const float* __restrict__ X2,
        ushort_t* __restrict__ RRH, ushort_t* __restrict__ RRL, int total) {
    int idx = blockIdx.x * 256 + threadIdx.x;
    if (idx >= total) return;
    int d = idx & 511;
    int row = idx >> 9;
    int g2 = row >> 3, rr = row & 7;
    float v = X2[((size_t)(g2 * 72 + 64 + rr)) * 512 + d];
    unsigned short h = f2bf(v);
    RRH[idx] = h;
    RRL[idx] = f2bf(v - bf2f(h));
}

// ---- l2-normalize each 128-half of each out row (l2n commutes w/ expand) --
__global__ __launch_bounds__(64) void norm_half_kernel(const float* __restrict__ IN,
        float* __restrict__ OUT) {
    int b = blockIdx.x; int lane = threadIdx.x;
    size_t base = (size_t)(b >> 1) * 256 + (size_t)(b & 1) * 128;
    float v0 = IN[base + lane], v1 = IN[base + 64 + lane];
    float ss = wave_sum64(v0 * v0 + v1 * v1);
    float sc = 1.0f / fmaxf(sqrtf(ss), 1e-12f);
    OUT[base + lane]      = v0 * sc;
    OUT[base + 64 + lane] = v1 * sc;
}

// ---- l2-normalize key columns: keys (32,128,16) over d --------------------
__global__ __launch_bounds__(64) void norm_keys_kernel(const float* __restrict__ Kin,
        float* __restrict__ Kout) {
    int b = blockIdx.x; int lane = threadIdx.x;
    int g = b >> 4, e = b & 15;
    size_t base = (size_t)g * 2048 + e;
    float v0 = Kin[base + (size_t)lane * 16];
    float v1 = Kin[base + (size_t)(lane + 64) * 16];
    float ss = wave_sum64(v0 * v0 + v1 * v1);
    float sc = 1.0f / fmaxf(sqrtf(ss), 1e-12f);
    Kout[base + (size_t)lane * 16]        = v0 * sc;
    Kout[base + (size_t)(lane + 64) * 16] = v1 * sc;
}

// ---- logits + top2 (stable, jax tie-break) --------------------------------
__global__ __launch_bounds__(64) void logits_top2_kernel(const float* __restrict__ OUTN,
        const float* __restrict__ KRN, const float* __restrict__ KGN,
        float* __restrict__ out) {
    int blk = blockIdx.x;
    int g = blk >> 6, bcol = blk & 63;
    int b = bcol >> 5, l = bcol & 31;
    int lsrc = (l + 31) & 31;     // roll(+1): element l comes from l-1
    int r = g >> 2;               // repeat RM=4
    int row = (b * 32 + lsrc) * 8 + r;
    const float* rvec = OUTN + (size_t)row * 256;
    __shared__ float sc[32];
    int lane = threadIdx.x;
    if (lane < 32) {
        int e = lane & 15;
        const float* kb = ((lane < 16) ? KRN : KGN) + (size_t)g * 2048 + e;
        const float* xv = (lane < 16) ? rvec : (rvec + 128);
        float s = 0.f;
#pragma unroll 8
        for (int d = 0; d < 128; ++d) s = fmaf(xv[d], kb[(size_t)d * 16], s);
        sc[lane] = s;
    }
    __syncthreads();
    if (lane == 0) {
        float bv = -1e30f, sv = -1e30f; int bi = 0, si = 0;
#pragma unroll
        for (int e = 0; e < 16; ++e) {
            float v = sc[e];
            if (v > bv) { sv = bv; si = bi; bv = v; bi = e; }
            else if (v > sv) { sv = v; si = e; }
        }
        size_t base = (size_t)g * 128 + (size_t)bcol * 2;
        out[base]            = bv;
        out[base + 1]        = sv;
        out[4096 + base]     = sc[16 + bi];
        out[4096 + base + 1] = sc[16 + si];
    }
}

// ---------------------------------------------------------------------------
static void run_layer(float* X, float* BIG, float* Qb,
                      ushort_t* KHb, ushort_t* KLb, ushort_t* VTHb, ushort_t* VTLb,
                      ushort_t* XNH, ushort_t* XNL, ushort_t* AOH, ushort_t* AOL,
                      ushort_t* MIDH, ushort_t* MIDL,
                      const unsigned short* WH, const unsigned short* WL,
                      const float* n1, const float* n2,
                      const int* doc, int G, int Sg, hipStream_t stream) {
    const size_t oQKV = 0, oO = 786432, oUP = 1048576, oDN = 2097152;
    int T = G * Sg;
    rmsnorm_kernel<<<T, 256, 0, stream>>>(X, n1, XNH, XNL);
    gemm3w<<<dim3(12, T / 128), 512, 0, stream>>>(XNH, XNL, WH + oQKV, WL + oQKV, nullptr, BIG, T, 1536, 512);
    int rp = T * 256;
    rope_pack_kernel<<<(rp + 255) / 256, 256, 0, stream>>>(BIG, Qb, KHb, KLb, Sg, rp);
    int qblocks = (Sg + 63) >> 6;
    vtrans_kernel<<<dim3(qblocks, G * 8), 256, 0, stream>>>(BIG, VTHb, VTLb, Sg);
    if (doc)
        attn3_kernel<true><<<dim3(qblocks, G * 8), 256, 0, stream>>>(Qb, KHb, KLb, VTHb, VTLb, doc, AOH, AOL, Sg);
    else
        attn3_kernel<false><<<dim3(qblocks, G * 8), 256, 0, stream>>>(Qb, KHb, KLb, VTHb, VTLb, nullptr, AOH, AOL, Sg);
    gemm3<64><<<dim3(4, T / 64), 256, 0, stream>>>(AOH, AOL, WH + oO, WL + oO, X, X, T, 512, 512);
    rmsnorm_kernel<<<T, 256, 0, stream>>>(X, n2, XNH, XNL);
    gemm_up_silu<<<dim3(16, T / 128), 512, 0, stream>>>(XNH, XNL, WH + oUP, WL + oUP, MIDH, MIDL, 512);
    gemm3<64><<<dim3(4, T / 64), 256, 0, stream>>>(MIDH, MIDL, WH + oDN, WL + oDN, X, X, T, 512, 1024);
}

static void split_layer(const float* qkv, const float* o, const float* up, const float* dn,
                        unsigned short* WH, unsigned short* WL, hipStream_t stream) {
    const size_t oQKV = 0, oO = 786432, oUP = 1048576, oDN = 2097152;
    wsplit_kernel<<<dim3(48, 16), 256, 0, stream>>>(qkv, WH + oQKV, WL + oQKV, 512, 1536);
    wsplit_kernel<<<dim3(16, 16), 256, 0, stream>>>(o,   WH + oO,   WL + oO,   512, 512);
    wsplit_kernel<<<dim3(64, 16), 256, 0, stream>>>(up,  WH + oUP,  WL + oUP,  512, 2048);
    wsplit_kernel<<<dim3(16, 32), 256, 0, stream>>>(dn,  WH + oDN,  WL + oDN,  1024, 512);
}

extern "C" void kernel_launch(void* const* d_in, const int* in_sizes, int n_in,
                              void* d_out, int out_size, void* d_ws, size_t ws_size,
                              hipStream_t stream) {
    const float* x_in    = (const float*)d_in[0];
    const int*   doc     = (const int*)d_in[1];
    const float* rt      = (const float*)d_in[2];
    const float* out_w   = (const float*)d_in[3];
    const float* k_rt    = (const float*)d_in[4];
    const float* k_gt    = (const float*)d_in[5];
    const float* enc_qkv = (const float*)d_in[6];
    const float* enc_o   = (const float*)d_in[7];
    const float* enc_up  = (const float*)d_in[8];
    const float* enc_dn  = (const float*)d_in[9];
    const float* enc_n1  = (const float*)d_in[10];
    const float* enc_n2  = (const float*)d_in[11];
    const float* rtr_qkv = (const float*)d_in[12];
    const float* rtr_o   = (const float*)d_in[13];
    const float* rtr_up  = (const float*)d_in[14];
    const float* rtr_dn  = (const float*)d_in[15];
    const float* rtr_n1  = (const float*)d_in[16];
    const float* rtr_n2  = (const float*)d_in[17];

    float* ws = (float*)d_ws;
    size_t off = 0;
    auto alloc = [&](size_t n) { float* p = ws + off; off += n; return p; };
    float* X    = alloc(4608UL * 512);
    float* X2   = alloc(4608UL * 512);
    float* BIG  = alloc(4608UL * 2048);
    float* Qb   = alloc(4608UL * 512);
    ushort_t* KHb  = (ushort_t*)alloc(1179648UL);
    ushort_t* KLb  = (ushort_t*)alloc(1179648UL);
    ushort_t* VTHb = (ushort_t*)alloc(1179648UL);
    ushort_t* VTLb = (ushort_t*)alloc(1179648UL);
    unsigned short* WH = (unsigned short*)(ws + off);
    unsigned short* WL = WH + 2621440UL;
    off += 2621440UL;
    // ---- dead-range aliases (stream-ordered, non-overlapping lifetimes) ----
    ushort_t* XNH = (ushort_t*)Qb;             // XN live rms->gemm; Qb live rope->attn
    ushort_t* XNL = XNH + 4608UL * 512;
    ushort_t* AOH = (ushort_t*)BIG;            // AO in BIG (QKV dead after rope/vtrans)
    ushort_t* AOL = AOH + 4608UL * 512;
    ushort_t* MIDH = (ushort_t*)BIG;           // MID in BIG (AO dead after o-proj)
    ushort_t* MIDL = MIDH + 4608UL * 1024;
    ushort_t* RRH = (ushort_t*)X;              // X dead after router_build
    ushort_t* RRL = RRH + 262144;
    float* OUTM = X + 262144;
    float* OUTN = X + 393216;
    float* KRN  = X + 524288;
    float* KGN  = X + 589824;
    (void)ws_size; (void)in_sizes; (void)n_in; (void)out_size;

    copy_in_kernel<<<(2097152 + 255) / 256, 256, 0, stream>>>(x_in, X, 2097152);

    for (int i = 0; i < 4; ++i) {
        split_layer(enc_qkv + (size_t)i * 512 * 1536,
                    enc_o   + (size_t)i * 512 * 512,
                    enc_up  + (size_t)i * 512 * 2048,
                    enc_dn  + (size_t)i * 1024 * 512, WH, WL, stream);
        run_layer(X, BIG, Qb, KHb, KLb, VTHb, VTLb, XNH, XNL, AOH, AOL, MIDH, MIDL,
                  WH, WL, enc_n1 + (size_t)i * 512, enc_n2 + (size_t)i * 512,
                  doc, 2, 2048, stream);
    }

    int rb_total = 64 * 72 * 512;
    router_build_kernel<<<(rb_total + 255) / 256, 256, 0, stream>>>(X, rt, X2, rb_total);

    for (int i = 0; i < 2; ++i) {
        split_layer(rtr_qkv + (size_t)i * 512 * 1536,
                    rtr_o   + (size_t)i * 512 * 512,
                    rtr_up  + (size_t)i * 512 * 2048,
                    rtr_dn  + (size_t)i * 1024 * 512, WH, WL, stream);
        run_layer(X2, BIG, Qb, KHb, KLb, VTHb, VTLb, XNH, XNL, AOH, AOL, MIDH, MIDL,
                  WH, WL, rtr_n1 + (size_t)i * 512, rtr_n2 + (size_t)i * 512,
                  nullptr, 64, 72, stream);
    }

    gather_rows_kernel<<<(512 * 512) / 256, 256, 0, stream>>>(X2, RRH, RRL, 512 * 512);
    wsplit_kernel<<<dim3(8, 16), 256, 0, stream>>>(out_w, WH, WL, 512, 256);
    gemm3<64><<<dim3(2, 8), 256, 0, stream>>>(RRH, RRL, WH, WL, nullptr, OUTM, 512, 256, 512);

    norm_half_kernel<<<1024, 64, 0, stream>>>(OUTM, OUTN);
    norm_keys_kernel<<<512, 64, 0, stream>>>(k_rt, KRN);
    norm_keys_kernel<<<512, 64, 0, stream>>>(k_gt, KGN);
    logits_top2_kernel<<<2048, 64, 0, stream>>>(OUTN, KRN, KGN, (float*)d_out);
}

// Round 9
// 1229.895 us; speedup vs baseline: 1.2825x; 1.0453x over previous
//
#include <hip/hip_runtime.h>
#include <hip/hip_bf16.h>
#include <cstdint>

// ---------------------------------------------------------------------------
// B=2 S=2048 D=512 H=8 HD=64, FFH=1024. Encoder: 4 layers, G=2, Sg=2048
// (block-causal-64 AND doc mask). Router: 2 layers, G=64, Sg=72, full attn.
// Round 18: attn3 dead-tile elimination. doc is SORTED per sequence =>
// bskip (dock[63]<bq0) is monotone in kt and dock[0]>bq1 is impossible for
// causal kt<=qb. Live range = contiguous [ktstart, qb]; ktstart found from
// per-kblock doc maxima (one 32-int LDS scan per block). Removes ~6000
// skipped tile-iters/dispatch (2 barriers + dock load each). Live tiles:
// stage+dock folded under ONE barrier pair (3 -> 2 barriers). T5 setprio
// around QK and PV MFMA clusters (+4-7% measured regime). GEMMs = r8.
// ---------------------------------------------------------------------------

typedef __attribute__((ext_vector_type(8))) short short8;   // 8 bf16 = 4 VGPR
typedef __attribute__((ext_vector_type(4))) float f32x4;
typedef unsigned short ushort_t;

__device__ __forceinline__ float bf2f(unsigned short u) {
    return __uint_as_float(((unsigned)u) << 16);
}
__device__ __forceinline__ unsigned short f2bf(float f) {
    unsigned u = __float_as_uint(f);
    unsigned r = 0x7FFFu + ((u >> 16) & 1u);
    return (unsigned short)((u + r) >> 16);
}
__device__ __forceinline__ float wave_sum64(float v) {
#pragma unroll
    for (int o = 32; o; o >>= 1) v += __shfl_xor(v, o);
    return v;
}
__device__ __forceinline__ void load_lds16(const ushort_t* g, ushort_t* l) {
    __builtin_amdgcn_global_load_lds(
        (const __attribute__((address_space(1))) unsigned int*)g,
        (__attribute__((address_space(3))) unsigned int*)l, 16, 0, 0);
}

#define MFMA16(a, b, c) __builtin_amdgcn_mfma_f32_16x16x32_bf16(a, b, c, 0, 0, 0)
#define BARRIER_RAW() do { asm volatile("" ::: "memory"); \
    __builtin_amdgcn_s_barrier(); asm volatile("" ::: "memory"); } while (0)
#define VMCNT0() asm volatile("s_waitcnt vmcnt(0)" ::: "memory")

// ---- f32 copy (input x -> mutable X) --------------------------------------
__global__ void copy_in_kernel(const float* __restrict__ src,
                               float* __restrict__ dst, int n) {
    int i = blockIdx.x * 256 + threadIdx.x;
    if (i < n) dst[i] = src[i];
}

// ---- weight transpose + hi/lo bf16 split: W[K,N] -> WT_hi/lo[N,K] ---------
__global__ __launch_bounds__(256) void wsplit_kernel(const float* __restrict__ W,
        unsigned short* __restrict__ WH, unsigned short* __restrict__ WL,
        int K, int N) {
    __shared__ float tile[32][33];
    int bn = blockIdx.x * 32, bk = blockIdx.y * 32;
    int tx = threadIdx.x & 31, ty = threadIdx.x >> 5;
#pragma unroll
    for (int i = 0; i < 4; ++i)
        tile[ty + 8 * i][tx] = W[(size_t)(bk + ty + 8 * i) * N + bn + tx];
    __syncthreads();
#pragma unroll
    for (int i = 0; i < 4; ++i) {
        int n = bn + ty + 8 * i, k = bk + tx;
        float x = tile[tx][ty + 8 * i];
        unsigned short h = f2bf(x);
        unsigned short lo = f2bf(x - bf2f(h));
        WH[(size_t)n * K + k] = h;
        WL[(size_t)n * K + k] = lo;
    }
}

// ---- RMSNorm over D=512, emits bf16 hi/lo ---------------------------------
__global__ __launch_bounds__(256) void rmsnorm_kernel(const float* __restrict__ X,
        const float* __restrict__ W, ushort_t* __restrict__ XNH,
        ushort_t* __restrict__ XNL) {
    int t = blockIdx.x, tid = threadIdx.x;
    const float* xr = X + (size_t)t * 512;
    float v0 = xr[tid], v1 = xr[tid + 256];
    float ss = wave_sum64(v0 * v0 + v1 * v1);
    __shared__ float red[4];
    if ((tid & 63) == 0) red[tid >> 6] = ss;
    __syncthreads();
    float tot = red[0] + red[1] + red[2] + red[3];
    float scale = rsqrtf(tot * (1.0f / 512.0f) + 1e-6f);
    float a0 = v0 * scale * W[tid];
    float a1 = v1 * scale * W[tid + 256];
    unsigned short h0 = f2bf(a0), h1 = f2bf(a1);
    size_t base = (size_t)t * 512;
    XNH[base + tid]       = h0;
    XNL[base + tid]       = f2bf(a0 - bf2f(h0));
    XNH[base + tid + 256] = h1;
    XNL[base + tid + 256] = f2bf(a1 - bf2f(h1));
}

// ---- bf16x3 MFMA GEMM: 2-set LDS, depth-1 stage (r6 proven) ---------------
template <int BM>
__global__ __launch_bounds__(256) void gemm3(
        const ushort_t* __restrict__ AH, const ushort_t* __restrict__ AL,
        const ushort_t* __restrict__ BH, const ushort_t* __restrict__ BL,
        const float* __restrict__ Res, float* __restrict__ C,
        int M, int N, int K) {
    constexpr int MI   = BM / 32;
    constexpr int ROWS = 2 * BM + 256;
    constexpr int LPW  = ROWS / 64;
    constexpr int SS   = ROWS * 32;
    __shared__ __align__(16) ushort_t S[2][ROWS][32];
    int tid = threadIdx.x;
    int n0 = blockIdx.x * 128, m0 = blockIdx.y * BM;
    int wid = tid >> 6, lane = tid & 63;
    int wm = (wid >> 1) * (BM / 2), wn = (wid & 1) * 64;
    int col = lane & 15, quad = lane >> 4;

    const ushort_t* gsrc[LPW];
    int ldof[LPW];
#pragma unroll
    for (int j = 0; j < LPW; ++j) {
        int e = wid * LPW + j;
        int srow = e * 16 + (lane >> 2);
        const ushort_t* gp; int rin;
        if (srow < BM)                { gp = AH + (size_t)m0 * K; rin = srow; }
        else if (srow < 2 * BM)       { gp = AL + (size_t)m0 * K; rin = srow - BM; }
        else if (srow < 2 * BM + 128) { gp = BH + (size_t)n0 * K; rin = srow - 2 * BM; }
        else                          { gp = BL + (size_t)n0 * K; rin = srow - 2 * BM - 128; }
        gsrc[j] = gp + (size_t)rin * K + ((lane & 3) ^ ((lane >> 3) & 3)) * 8;
        ldof[j] = e * 512;
    }
    ushort_t* sbase = &S[0][0][0];
    auto STAGE = [&](int set, int kc) {
        ushort_t* sb = sbase + set * SS;
#pragma unroll
        for (int j = 0; j < LPW; ++j)
            load_lds16(gsrc[j] + kc * 32, sb + ldof[j]);
    };

    int chrd = (quad ^ ((col >> 1) & 3)) * 8;
    f32x4 acc[MI][4] = {};
    int nk = K >> 5;
    STAGE(0, 0);
    VMCNT0();
    BARRIER_RAW();
    int cur = 0;
#pragma unroll 1
    for (int kc = 0; kc < nk; ++kc) {
        if (kc + 1 < nk) STAGE(cur ^ 1, kc + 1);
        const ushort_t* sb = sbase + cur * SS;
        short8 afh[MI], afl[MI], bfh[4], bfl[4];
#pragma unroll
        for (int i = 0; i < MI; ++i) {
            afh[i] = *(const short8*)(sb + (size_t)(wm + i * 16 + col) * 32 + chrd);
            afl[i] = *(const short8*)(sb + (size_t)(BM + wm + i * 16 + col) * 32 + chrd);
        }
#pragma unroll
        for (int i = 0; i < 4; ++i) {
            bfh[i] = *(const short8*)(sb + (size_t)(2 * BM + wn + i * 16 + col) * 32 + chrd);
            bfl[i] = *(const short8*)(sb + (size_t)(2 * BM + 128 + wn + i * 16 + col) * 32 + chrd);
        }
#pragma unroll
        for (int mi = 0; mi < MI; ++mi)
#pragma unroll
            for (int ni = 0; ni < 4; ++ni) {
                f32x4 c = acc[mi][ni];
                c = MFMA16(afh[mi], bfh[ni], c);
                c = MFMA16(afh[mi], bfl[ni], c);
                c = MFMA16(afl[mi], bfh[ni], c);
                acc[mi][ni] = c;
            }
        if (kc + 1 < nk) {
            VMCNT0();
            BARRIER_RAW();
            cur ^= 1;
        }
    }
#pragma unroll
    for (int mi = 0; mi < MI; ++mi)
#pragma unroll
        for (int ni = 0; ni < 4; ++ni)
#pragma unroll
            for (int r = 0; r < 4; ++r) {
                int row = m0 + wm + mi * 16 + quad * 4 + r;
                int ccol = n0 + wn + ni * 16 + col;
                size_t o = (size_t)row * N + ccol;
                float v = acc[mi][ni][r];
                if (Res) v += Res[o];
                C[o] = v;
            }
}

// ---- bf16x3 GEMM, 512 thr (8 waves 4Mx2N), 128x128 tile, 2-set 64KB -------
__global__ __launch_bounds__(512, 4) void gemm3w(
        const ushort_t* __restrict__ AH, const ushort_t* __restrict__ AL,
        const ushort_t* __restrict__ BH, const ushort_t* __restrict__ BL,
        const float* __restrict__ Res, float* __restrict__ C,
        int M, int N, int K) {
    constexpr int ROWS = 512;
    constexpr int LPW  = 4;
    constexpr int SS   = ROWS * 32;
    __shared__ __align__(16) ushort_t S[2][ROWS][32];
    int tid = threadIdx.x;
    int n0 = blockIdx.x * 128, m0 = blockIdx.y * 128;
    int wid = tid >> 6, lane = tid & 63;
    int wm = (wid >> 1) * 32, wn = (wid & 1) * 64;
    int col = lane & 15, quad = lane >> 4;

    const ushort_t* gsrc[LPW];
    int ldof[LPW];
#pragma unroll
    for (int j = 0; j < LPW; ++j) {
        int e = wid * LPW + j;
        int srow = e * 16 + (lane >> 2);
        const ushort_t* gp; int rin;
        if (srow < 128)      { gp = AH; rin = m0 + srow; }
        else if (srow < 256) { gp = AL; rin = m0 + srow - 128; }
        else if (srow < 384) { gp = BH; rin = n0 + srow - 256; }
        else                 { gp = BL; rin = n0 + srow - 384; }
        gsrc[j] = gp + (size_t)rin * K + ((lane & 3) ^ ((lane >> 3) & 3)) * 8;
        ldof[j] = e * 512;
    }
    ushort_t* sbase = &S[0][0][0];
    auto STAGE = [&](int set, int kc) {
        ushort_t* sb = sbase + set * SS;
#pragma unroll
        for (int j = 0; j < LPW; ++j)
            load_lds16(gsrc[j] + kc * 32, sb + ldof[j]);
    };

    int chrd = (quad ^ ((col >> 1) & 3)) * 8;
    f32x4 acc[2][4] = {};
    int nk = K >> 5;
    STAGE(0, 0);
    VMCNT0();
    BARRIER_RAW();
    int cur = 0;
#pragma unroll 1
    for (int kc = 0; kc < nk; ++kc) {
        if (kc + 1 < nk) STAGE(cur ^ 1, kc + 1);
        const ushort_t* sb = sbase + cur * SS;
        short8 afh[2], afl[2], bfh[4], bfl[4];
#pragma unroll
        for (int i = 0; i < 2; ++i) {
            afh[i] = *(const short8*)(sb + (size_t)(wm + i * 16 + col) * 32 + chrd);
            afl[i] = *(const short8*)(sb + (size_t)(128 + wm + i * 16 + col) * 32 + chrd);
        }
#pragma unroll
        for (int i = 0; i < 4; ++i) {
            bfh[i] = *(const short8*)(sb + (size_t)(256 + wn + i * 16 + col) * 32 + chrd);
            bfl[i] = *(const short8*)(sb + (size_t)(384 + wn + i * 16 + col) * 32 + chrd);
        }
#pragma unroll
        for (int mi = 0; mi < 2; ++mi)
#pragma unroll
            for (int ni = 0; ni < 4; ++ni) {
                f32x4 c = acc[mi][ni];
                c = MFMA16(afh[mi], bfh[ni], c);
                c = MFMA16(afh[mi], bfl[ni], c);
                c = MFMA16(afl[mi], bfh[ni], c);
                acc[mi][ni] = c;
            }
        if (kc + 1 < nk) {
            VMCNT0();
            BARRIER_RAW();
            cur ^= 1;
        }
    }
#pragma unroll
    for (int mi = 0; mi < 2; ++mi)
#pragma unroll
        for (int ni = 0; ni < 4; ++ni)
#pragma unroll
            for (int r = 0; r < 4; ++r) {
                int row = m0 + wm + mi * 16 + quad * 4 + r;
                int ccol = n0 + wn + ni * 16 + col;
                size_t o = (size_t)row * N + ccol;
                float v = acc[mi][ni][r];
                if (Res) v += Res[o];
                C[o] = v;
            }
}

// ---- fused up-proj + silu, 512 thr: MID = silu(A@W1^T)*(A@W2^T) -----------
__global__ __launch_bounds__(512, 4) void gemm_up_silu(
        const ushort_t* __restrict__ AH, const ushort_t* __restrict__ AL,
        const ushort_t* __restrict__ BH, const ushort_t* __restrict__ BL,
        ushort_t* __restrict__ MIDH, ushort_t* __restrict__ MIDL, int K) {
    constexpr int ROWS = 512;
    constexpr int LPW  = 4;
    constexpr int SS   = ROWS * 32;
    __shared__ __align__(16) ushort_t S[2][ROWS][32];
    int tid = threadIdx.x;
    int n0 = blockIdx.x * 64, m0 = blockIdx.y * 128;
    int wid = tid >> 6, lane = tid & 63;
    int wm = (wid >> 1) * 32, wn = (wid & 1) * 32;
    int col = lane & 15, quad = lane >> 4;

    const ushort_t* gsrc[LPW];
    int ldof[LPW];
#pragma unroll
    for (int j = 0; j < LPW; ++j) {
        int e = wid * LPW + j;
        int srow = e * 16 + (lane >> 2);
        const ushort_t* gp; int rin;
        if (srow < 128)      { gp = AH; rin = m0 + srow; }
        else if (srow < 256) { gp = AL; rin = m0 + srow - 128; }
        else if (srow < 320) { gp = BH; rin = n0 + srow - 256; }
        else if (srow < 384) { gp = BL; rin = n0 + srow - 320; }
        else if (srow < 448) { gp = BH; rin = 1024 + n0 + srow - 384; }
        else                 { gp = BL; rin = 1024 + n0 + srow - 448; }
        gsrc[j] = gp + (size_t)rin * K + ((lane & 3) ^ ((lane >> 3) & 3)) * 8;
        ldof[j] = e * 512;
    }
    ushort_t* sbase = &S[0][0][0];
    auto STAGE = [&](int set, int kc) {
        ushort_t* sb = sbase + set * SS;
#pragma unroll
        for (int j = 0; j < LPW; ++j)
            load_lds16(gsrc[j] + kc * 32, sb + ldof[j]);
    };

    int chrd = (quad ^ ((col >> 1) & 3)) * 8;
    f32x4 a1[2][2] = {}, a2[2][2] = {};
    int nk = K >> 5;
    STAGE(0, 0);
    VMCNT0();
    BARRIER_RAW();
    int cur = 0;
#pragma unroll 1
    for (int kc = 0; kc < nk; ++kc) {
        if (kc + 1 < nk) STAGE(cur ^ 1, kc + 1);
        const ushort_t* sb = sbase + cur * SS;
        short8 afh[2], afl[2], b1h[2], b1l[2], b2h[2], b2l[2];
#pragma unroll
        for (int i = 0; i < 2; ++i) {
            afh[i] = *(const short8*)(sb + (size_t)(wm + i * 16 + col) * 32 + chrd);
            afl[i] = *(const short8*)(sb + (size_t)(128 + wm + i * 16 + col) * 32 + chrd);
            b1h[i] = *(const short8*)(sb + (size_t)(256 + wn + i * 16 + col) * 32 + chrd);
            b1l[i] = *(const short8*)(sb + (size_t)(320 + wn + i * 16 + col) * 32 + chrd);
            b2h[i] = *(const short8*)(sb + (size_t)(384 + wn + i * 16 + col) * 32 + chrd);
            b2l[i] = *(const short8*)(sb + (size_t)(448 + wn + i * 16 + col) * 32 + chrd);
        }
#pragma unroll
        for (int mi = 0; mi < 2; ++mi)
#pragma unroll
            for (int ni = 0; ni < 2; ++ni) {
                f32x4 c = a1[mi][ni];
                c = MFMA16(afh[mi], b1h[ni], c);
                c = MFMA16(afh[mi], b1l[ni], c);
                c = MFMA16(afl[mi], b1h[ni], c);
                a1[mi][ni] = c;
                f32x4 d = a2[mi][ni];
                d = MFMA16(afh[mi], b2h[ni], d);
                d = MFMA16(afh[mi], b2l[ni], d);
                d = MFMA16(afl[mi], b2h[ni], d);
                a2[mi][ni] = d;
            }
        if (kc + 1 < nk) {
            VMCNT0();
            BARRIER_RAW();
            cur ^= 1;
        }
    }
#pragma unroll
    for (int mi = 0; mi < 2; ++mi)
#pragma unroll
        for (int ni = 0; ni < 2; ++ni)
#pragma unroll
            for (int r = 0; r < 4; ++r) {
                int row = m0 + wm + mi * 16 + quad * 4 + r;
                int ccol = n0 + wn + ni * 16 + col;
                float v1 = a1[mi][ni][r], v2 = a2[mi][ni][r];
                float rr = (v1 / (1.0f + __expf(-v1))) * v2;
                unsigned short h = f2bf(rr);
                size_t o = (size_t)row * 1024 + ccol;
                MIDH[o] = h;
                MIDL[o] = f2bf(rr - bf2f(h));
            }
}

// ---- split qkv + RoPE; Q f32 (g,h,s,hd); K bf16 hi/lo [gh][Sg][64] --------
__global__ void rope_pack_kernel(const float* __restrict__ QKV,
        float* __restrict__ Q, ushort_t* __restrict__ KH,
        ushort_t* __restrict__ KL, int Sg, int total) {
    int idx = blockIdx.x * 256 + threadIdx.x;
    if (idx >= total) return;
    int i = idx & 31;
    int h = (idx >> 5) & 7;
    int t = idx >> 8;
    int g = t / Sg; int s = t - g * Sg;
    const float* row = QKV + (size_t)t * 1536;
    float inv = powf(10000.0f, -(float)(2 * i) / 64.0f);
    float sn, cs;
    sincosf((float)s * inv, &sn, &cs);
    size_t ob = ((size_t)(g * 8 + h) * Sg + s) * 64 + i;
    int c = h * 64 + i;
    float q1 = row[c], q2 = row[c + 32];
    Q[ob]      = q1 * cs + q2 * sn;
    Q[ob + 32] = q2 * cs - q1 * sn;
    float k1 = row[512 + c], k2 = row[512 + c + 32];
    float ka = k1 * cs + k2 * sn;
    float kb = k2 * cs - k1 * sn;
    unsigned short ha = f2bf(ka), hb = f2bf(kb);
    KH[ob]      = ha;  KL[ob]      = f2bf(ka - bf2f(ha));
    KH[ob + 32] = hb;  KL[ob + 32] = f2bf(kb - bf2f(hb));
}

// ---- V^T split: QKV f32 [T][1536] -> VT hi/lo [gh][64 d][Sg s] ------------
__global__ __launch_bounds__(256) void vtrans_kernel(const float* __restrict__ QKV,
        ushort_t* __restrict__ VTH, ushort_t* __restrict__ VTL, int Sg) {
    __shared__ float tile[64][65];
    int chunk = blockIdx.x, gh = blockIdx.y;
    int g = gh >> 3, h = gh & 7;
    int tid = threadIdx.x;
    int sr = tid >> 2, dc = (tid & 3) * 16;
    int s = chunk * 64 + sr;
    if (s < Sg) {
        const float* src = QKV + ((size_t)g * Sg + s) * 1536 + 1024 + h * 64 + dc;
#pragma unroll
        for (int j = 0; j < 4; ++j) {
            float4 v = *(const float4*)(src + 4 * j);
            tile[sr][dc + 4 * j]     = v.x;
            tile[sr][dc + 4 * j + 1] = v.y;
            tile[sr][dc + 4 * j + 2] = v.z;
            tile[sr][dc + 4 * j + 3] = v.w;
        }
    } else {
#pragma unroll
        for (int j = 0; j < 16; ++j) tile[sr][dc + j] = 0.f;
    }
    __syncthreads();
    int dr = tid >> 2, sc = (tid & 3) * 16;
    short8 hv[2], lv[2];
#pragma unroll
    for (int half = 0; half < 2; ++half)
#pragma unroll
        for (int j = 0; j < 8; ++j) {
            float v = tile[sc + half * 8 + j][dr];
            unsigned short hb = f2bf(v);
            hv[half][j] = (short)hb;
            lv[half][j] = (short)f2bf(v - bf2f(hb));
        }
    int scol = chunk * 64 + sc;
    size_t ob = ((size_t)gh * 64 + dr) * Sg + scol;
    if (scol + 16 <= Sg) {
        *(short8*)(VTH + ob)     = hv[0];
        *(short8*)(VTH + ob + 8) = hv[1];
        *(short8*)(VTL + ob)     = lv[0];
        *(short8*)(VTL + ob + 8) = lv[1];
    } else {
#pragma unroll
        for (int j = 0; j < 16; ++j)
            if (scol + j < Sg) {
                VTH[ob + j] = (ushort_t)((j < 8) ? hv[0][j] : hv[1][j - 8]);
                VTL[ob + j] = (ushort_t)((j < 8) ? lv[0][j] : lv[1][j - 8]);
            }
    }
}

// ---- MFMA flash attention (bf16x3), contiguous live k-range ---------------
template <bool MASKED>
__global__ __launch_bounds__(256, 3) void attn3_kernel(const float* __restrict__ Q,
        const ushort_t* __restrict__ KHg, const ushort_t* __restrict__ KLg,
        const ushort_t* __restrict__ VTHg, const ushort_t* __restrict__ VTLg,
        const int* __restrict__ doc, ushort_t* __restrict__ AOH,
        ushort_t* __restrict__ AOL, int Sg) {
    __shared__ __align__(16) ushort_t Khs[64][64], Kls[64][64];  // swizzled
    __shared__ __align__(16) ushort_t Vts[64][64], Vtl[64][64];  // swizzled
    __shared__ __align__(16) ushort_t Ph[4][16][72], Pl[4][16][72];
    __shared__ int dock[64];
    __shared__ int dmax_s[32];
    int qb = (int)(gridDim.x - 1 - blockIdx.x);   // big qb first (load balance)
    int gh = blockIdx.y, g = gh >> 3;
    int tid = threadIdx.x, wid = tid >> 6, lane = tid & 63;
    int col = lane & 15, quad = lane >> 4;

    int rL = lane >> 3, cSw = (lane & 7) ^ rL;
    const ushort_t* kb;      // K waves: row base (chunk folded in)
    const ushort_t* vb;      // V waves: d-row base
    ushort_t* lb;
    if (wid == 0)      { kb = KHg + (size_t)gh * Sg * 64 + cSw * 8;  vb = nullptr; lb = &Khs[0][0]; }
    else if (wid == 1) { kb = KLg + (size_t)gh * Sg * 64 + cSw * 8;  vb = nullptr; lb = &Kls[0][0]; }
    else if (wid == 2) { vb = VTHg + ((size_t)gh * 64 + rL) * Sg;    kb = nullptr; lb = &Vts[0][0]; }
    else               { vb = VTLg + ((size_t)gh * 64 + rL) * Sg;    kb = nullptr; lb = &Vtl[0][0]; }
    int sw0 = ((0 + quad) ^ (col & 7)) * 8;
    int sw1 = ((4 + quad) ^ (col & 7)) * 8;

    short8 qa[2][2];  // [kk][0=hi,1=lo]
    {
        int qrow = qb * 64 + wid * 16 + col;
        if (qrow >= Sg) qrow = Sg - 1;
        const float* Qg = Q + ((size_t)gh * Sg + qrow) * 64 + quad * 8;
#pragma unroll
        for (int kk = 0; kk < 2; ++kk) {
            float4 v0 = *(const float4*)(Qg + kk * 32);
            float4 v1 = *(const float4*)(Qg + kk * 32 + 4);
            float vv[8] = {v0.x, v0.y, v0.z, v0.w, v1.x, v1.y, v1.z, v1.w};
            short8 h, l;
#pragma unroll
            for (int e = 0; e < 8; ++e) {
                float x = vv[e] * 0.125f;
                unsigned short hb = f2bf(x);
                h[e] = (short)hb;
                l[e] = (short)f2bf(x - bf2f(hb));
            }
            qa[kk][0] = h; qa[kk][1] = l;
        }
    }
    int dqr[4]; int wq0 = 0, wq1 = 0, bq0 = 0;
    int kts = 0;
    if (MASKED) {
        const int* db = doc + (size_t)g * Sg + qb * 64;
#pragma unroll
        for (int r = 0; r < 4; ++r) dqr[r] = db[wid * 16 + quad * 4 + r];
        wq0 = db[wid * 16]; wq1 = db[wid * 16 + 15];
        bq0 = db[0];
        // per-kblock doc maxima (doc sorted => block max = last element)
        int nkb = (Sg + 63) >> 6;
        if (tid < nkb) dmax_s[tid] = doc[(size_t)g * Sg + tid * 64 + 63];
        __syncthreads();
        // doc sorted => bskip (dmax<bq0) is monotone; dock[0]>bq1 impossible
        // for causal kt<=qb. Live range = [kts, qb], all tiles live.
        int kbv = 0;
        while (kbv < nkb && dmax_s[kbv] < bq0) ++kbv;
        kts = kbv;
    }
    float m[4], l[4];
    f32x4 accO[4];
#pragma unroll
    for (int r = 0; r < 4; ++r) { m[r] = -1e30f; l[r] = 0.f; }
#pragma unroll
    for (int nd = 0; nd < 4; ++nd) accO[nd] = (f32x4){0.f, 0.f, 0.f, 0.f};

    int nkt = MASKED ? (qb + 1) : ((Sg + 63) >> 6);
    for (int kt = kts; kt < nkt; ++kt) {
        int kval = Sg - kt * 64; if (kval > 64) kval = 64;
        __syncthreads();                   // prior frag reads complete
        // stage K/V (async) + dock under one barrier window
        if (wid < 2) {
#pragma unroll
            for (int p = 0; p < 8; ++p) {
                int sr2 = kt * 64 + p * 8 + rL;
                if (sr2 > Sg - 1) sr2 = Sg - 1;
                load_lds16(kb + (size_t)sr2 * 64, lb + p * 512);
            }
        } else {
            int vc = kt * 64 + cSw * 8;
            if (vc > Sg - 8) vc = Sg - 8;
#pragma unroll
            for (int p = 0; p < 8; ++p)
                load_lds16(vb + (size_t)(p * 8) * Sg + vc, lb + p * 512);
        }
        if (MASKED && tid < 64) dock[tid] = doc[(size_t)g * Sg + kt * 64 + tid];
        __syncthreads();                   // drains vmcnt + lgkm (stage+dock)
        bool wskip = false;
        if (MASKED) wskip = (dock[kval - 1] < wq0);
        if (!wskip) {
            int dk[4];
            if (MASKED) {
#pragma unroll
                for (int ni = 0; ni < 4; ++ni) dk[ni] = dock[ni * 16 + col];
            }
            f32x4 sc[4];
            __builtin_amdgcn_s_setprio(1);
#pragma unroll
            for (int ni = 0; ni < 4; ++ni) {
                int rb = (ni * 16 + col) * 64;
                short8 bh0 = *(const short8*)(&Khs[0][0] + rb + sw0);
                short8 bl0 = *(const short8*)(&Kls[0][0] + rb + sw0);
                short8 bh1 = *(const short8*)(&Khs[0][0] + rb + sw1);
                short8 bl1 = *(const short8*)(&Kls[0][0] + rb + sw1);
                f32x4 c = (f32x4){0.f, 0.f, 0.f, 0.f};
                c = MFMA16(qa[0][0], bh0, c);
                c = MFMA16(qa[0][0], bl0, c);
                c = MFMA16(qa[0][1], bh0, c);
                c = MFMA16(qa[1][0], bh1, c);
                c = MFMA16(qa[1][0], bl1, c);
                c = MFMA16(qa[1][1], bh1, c);
                sc[ni] = c;
            }
            __builtin_amdgcn_s_setprio(0);
            float mnew[4];
#pragma unroll
            for (int r = 0; r < 4; ++r) mnew[r] = -1e30f;
#pragma unroll
            for (int ni = 0; ni < 4; ++ni)
#pragma unroll
                for (int r = 0; r < 4; ++r) {
                    bool ok = MASKED ? (dk[ni] == dqr[r]) : (ni * 16 + col < kval);
                    float s = ok ? sc[ni][r] : -1e30f;
                    sc[ni][r] = s;
                    mnew[r] = fmaxf(mnew[r], s);
                }
#pragma unroll
            for (int r = 0; r < 4; ++r)
#pragma unroll
                for (int o = 1; o < 16; o <<= 1)
                    mnew[r] = fmaxf(mnew[r], __shfl_xor(mnew[r], o));
            float alpha[4], lsum[4];
#pragma unroll
            for (int r = 0; r < 4; ++r) {
                float M = fmaxf(m[r], mnew[r]);
                alpha[r] = __expf(m[r] - M);
                m[r] = M;
                lsum[r] = 0.f;
            }
#pragma unroll
            for (int ni = 0; ni < 4; ++ni)
#pragma unroll
                for (int r = 0; r < 4; ++r) {
                    bool ok = MASKED ? (dk[ni] == dqr[r]) : (ni * 16 + col < kval);
                    float p = ok ? __expf(sc[ni][r] - m[r]) : 0.f;
                    lsum[r] += p;
                    unsigned short h = f2bf(p);
                    Ph[wid][quad * 4 + r][ni * 16 + col] = h;
                    Pl[wid][quad * 4 + r][ni * 16 + col] = f2bf(p - bf2f(h));
                }
#pragma unroll
            for (int r = 0; r < 4; ++r) {
#pragma unroll
                for (int o = 1; o < 16; o <<= 1)
                    lsum[r] += __shfl_xor(lsum[r], o);
                l[r] = l[r] * alpha[r] + lsum[r];
            }
#pragma unroll
            for (int nd = 0; nd < 4; ++nd)
#pragma unroll
                for (int r = 0; r < 4; ++r) accO[nd][r] *= alpha[r];
            __builtin_amdgcn_s_setprio(1);
#pragma unroll
            for (int kk = 0; kk < 2; ++kk) {
                short8 pah = *(const short8*)&Ph[wid][col][kk * 32 + quad * 8];
                short8 pal = *(const short8*)&Pl[wid][col][kk * 32 + quad * 8];
                int sw = kk ? sw1 : sw0;
#pragma unroll
                for (int nd = 0; nd < 4; ++nd) {
                    int rb = (nd * 16 + col) * 64;
                    short8 vbh = *(const short8*)(&Vts[0][0] + rb + sw);
                    short8 vbl = *(const short8*)(&Vtl[0][0] + rb + sw);
                    f32x4 c = accO[nd];
                    c = MFMA16(pah, vbh, c);
                    c = MFMA16(pah, vbl, c);
                    c = MFMA16(pal, vbh, c);
                    accO[nd] = c;
                }
            }
            __builtin_amdgcn_s_setprio(0);
        }
    }
#pragma unroll
    for (int r = 0; r < 4; ++r) {
        int qrow = qb * 64 + wid * 16 + quad * 4 + r;
        if (qrow < Sg) {
            float inv = 1.0f / l[r];
            size_t base = ((size_t)g * Sg + qrow) * 512 + (gh & 7) * 64;
#pragma unroll
            for (int nd = 0; nd < 4; ++nd) {
                float val = accO[nd][r] * inv;
                unsigned short h = f2bf(val);
                AOH[base + nd * 16 + col] = h;
                AOL[base + nd * 16 + col] = f2bf(val - bf2f(h));
            }
        }
    }
}

// ---- build router stream: (64 groups) x (64 tokens + 8 router tokens) -----
__global__ void router_build_kernel(const float* __restrict__ X,
        const float* __restrict__ RT, float* __restrict__ X2, int total) {
    int idx = blockIdx.x * 256 + threadIdx.x;
    if (idx >= total) return;
    int d = idx & 511;
    int p = (idx >> 9) % 72;
    int g2 = idx / (72 * 512);
    X2[idx] = (p < 64) ? X[((size_t)g2 * 64 + p) * 512 + d]
                       : RT[(p - 64) * 512 + d];
}

// ---- gather xr[:,64:72,:] into dense (512,512) bf16 hi/lo -----------------
__global__ void gather_rows_kernel(const float* __restrict__ X2,
        ushort_t* __restrict__ RRH, ushort_t* __restrict__ RRL, int total) {
    int idx = blockIdx.x * 256 + threadIdx.x;
    if (idx >= total) return;
    int d = idx & 511;
    int row = idx >> 9;
    int g2 = row >> 3, rr = row & 7;
    float v = X2[((size_t)(g2 * 72 + 64 + rr)) * 512 + d];
    unsigned short h = f2bf(v);
    RRH[idx] = h;
    RRL[idx] = f2bf(v - bf2f(h));
}

// ---- l2-normalize each 128-half of each out row (l2n commutes w/ expand) --
__global__ __launch_bounds__(64) void norm_half_kernel(const float* __restrict__ IN,
        float* __restrict__ OUT) {
    int b = blockIdx.x; int lane = threadIdx.x;
    size_t base = (size_t)(b >> 1) * 256 + (size_t)(b & 1) * 128;
    float v0 = IN[base + lane], v1 = IN[base + 64 + lane];
    float ss = wave_sum64(v0 * v0 + v1 * v1);
    float sc = 1.0f / fmaxf(sqrtf(ss), 1e-12f);
    OUT[base + lane]      = v0 * sc;
    OUT[base + 64 + lane] = v1 * sc;
}

// ---- l2-normalize key columns: keys (32,128,16) over d --------------------
__global__ __launch_bounds__(64) void norm_keys_kernel(const float* __restrict__ Kin,
        float* __restrict__ Kout) {
    int b = blockIdx.x; int lane = threadIdx.x;
    int g = b >> 4, e = b & 15;
    size_t base = (size_t)g * 2048 + e;
    float v0 = Kin[base + (size_t)lane * 16];
    float v1 = Kin[base + (size_t)(lane + 64) * 16];
    float ss = wave_sum64(v0 * v0 + v1 * v1);
    float sc = 1.0f / fmaxf(sqrtf(ss), 1e-12f);
    Kout[base + (size_t)lane * 16]        = v0 * sc;
    Kout[base + (size_t)(lane + 64) * 16] = v1 * sc;
}

// ---- logits + top2 (stable, jax tie-break) --------------------------------
__global__ __launch_bounds__(64) void logits_top2_kernel(const float* __restrict__ OUTN,
        const float* __restrict__ KRN, const float* __restrict__ KGN,
        float* __restrict__ out) {
    int blk = blockIdx.x;
    int g = blk >> 6, bcol = blk & 63;
    int b = bcol >> 5, l = bcol & 31;
    int lsrc = (l + 31) & 31;     // roll(+1): element l comes from l-1
    int r = g >> 2;               // repeat RM=4
    int row = (b * 32 + lsrc) * 8 + r;
    const float* rvec = OUTN + (size_t)row * 256;
    __shared__ float sc[32];
    int lane = threadIdx.x;
    if (lane < 32) {
        int e = lane & 15;
        const float* kb = ((lane < 16) ? KRN : KGN) + (size_t)g * 2048 + e;
        const float* xv = (lane < 16) ? rvec : (rvec + 128);
        float s = 0.f;
#pragma unroll 8
        for (int d = 0; d < 128; ++d) s = fmaf(xv[d], kb[(size_t)d * 16], s);
        sc[lane] = s;
    }
    __syncthreads();
    if (lane == 0) {
        float bv = -1e30f, sv = -1e30f; int bi = 0, si = 0;
#pragma unroll
        for (int e = 0; e < 16; ++e) {
            float v = sc[e];
            if (v > bv) { sv = bv; si = bi; bv = v; bi = e; }
            else if (v > sv) { sv = v; si = e; }
        }
        size_t base = (size_t)g * 128 + (size_t)bcol * 2;
        out[base]            = bv;
        out[base + 1]        = sv;
        out[4096 + base]     = sc[16 + bi];
        out[4096 + base + 1] = sc[16 + si];
    }
}

// ---------------------------------------------------------------------------
static void run_layer(float* X, float* BIG, float* Qb,
                      ushort_t* KHb, ushort_t* KLb, ushort_t* VTHb, ushort_t* VTLb,
                      ushort_t* XNH, ushort_t* XNL, ushort_t* AOH, ushort_t* AOL,
                      ushort_t* MIDH, ushort_t* MIDL,
                      const unsigned short* WH, const unsigned short* WL,
                      const float* n1, const float* n2,
                      const int* doc, int G, int Sg, hipStream_t stream) {
    const size_t oQKV = 0, oO = 786432, oUP = 1048576, oDN = 2097152;
    int T = G * Sg;
    rmsnorm_kernel<<<T, 256, 0, stream>>>(X, n1, XNH, XNL);
    gemm3w<<<dim3(12, T / 128), 512, 0, stream>>>(XNH, XNL, WH + oQKV, WL + oQKV, nullptr, BIG, T, 1536, 512);
    int rp = T * 256;
    rope_pack_kernel<<<(rp + 255) / 256, 256, 0, stream>>>(BIG, Qb, KHb, KLb, Sg, rp);
    int qblocks = (Sg + 63) >> 6;
    vtrans_kernel<<<dim3(qblocks, G * 8), 256, 0, stream>>>(BIG, VTHb, VTLb, Sg);
    if (doc)
        attn3_kernel<true><<<dim3(qblocks, G * 8), 256, 0, stream>>>(Qb, KHb, KLb, VTHb, VTLb, doc, AOH, AOL, Sg);
    else
        attn3_kernel<false><<<dim3(qblocks, G * 8), 256, 0, stream>>>(Qb, KHb, KLb, VTHb, VTLb, nullptr, AOH, AOL, Sg);
    gemm3<64><<<dim3(4, T / 64), 256, 0, stream>>>(AOH, AOL, WH + oO, WL + oO, X, X, T, 512, 512);
    rmsnorm_kernel<<<T, 256, 0, stream>>>(X, n2, XNH, XNL);
    gemm_up_silu<<<dim3(16, T / 128), 512, 0, stream>>>(XNH, XNL, WH + oUP, WL + oUP, MIDH, MIDL, 512);
    gemm3<64><<<dim3(4, T / 64), 256, 0, stream>>>(MIDH, MIDL, WH + oDN, WL + oDN, X, X, T, 512, 1024);
}

static void split_layer(const float* qkv, const float* o, const float* up, const float* dn,
                        unsigned short* WH, unsigned short* WL, hipStream_t stream) {
    const size_t oQKV = 0, oO = 786432, oUP = 1048576, oDN = 2097152;
    wsplit_kernel<<<dim3(48, 16), 256, 0, stream>>>(qkv, WH + oQKV, WL + oQKV, 512, 1536);
    wsplit_kernel<<<dim3(16, 16), 256, 0, stream>>>(o,   WH + oO,   WL + oO,   512, 512);
    wsplit_kernel<<<dim3(64, 16), 256, 0, stream>>>(up,  WH + oUP,  WL + oUP,  512, 2048);
    wsplit_kernel<<<dim3(16, 32), 256, 0, stream>>>(dn,  WH + oDN,  WL + oDN,  1024, 512);
}

extern "C" void kernel_launch(void* const* d_in, const int* in_sizes, int n_in,
                              void* d_out, int out_size, void* d_ws, size_t ws_size,
                              hipStream_t stream) {
    const float* x_in    = (const float*)d_in[0];
    const int*   doc     = (const int*)d_in[1];
    const float* rt      = (const float*)d_in[2];
    const float* out_w   = (const float*)d_in[3];
    const float* k_rt    = (const float*)d_in[4];
    const float* k_gt    = (const float*)d_in[5];
    const float* enc_qkv = (const float*)d_in[6];
    const float* enc_o   = (const float*)d_in[7];
    const float* enc_up  = (const float*)d_in[8];
    const float* enc_dn  = (const float*)d_in[9];
    const float* enc_n1  = (const float*)d_in[10];
    const float* enc_n2  = (const float*)d_in[11];
    const float* rtr_qkv = (const float*)d_in[12];
    const float* rtr_o   = (const float*)d_in[13];
    const float* rtr_up  = (const float*)d_in[14];
    const float* rtr_dn  = (const float*)d_in[15];
    const float* rtr_n1  = (const float*)d_in[16];
    const float* rtr_n2  = (const float*)d_in[17];

    float* ws = (float*)d_ws;
    size_t off = 0;
    auto alloc = [&](size_t n) { float* p = ws + off; off += n; return p; };
    float* X    = alloc(4608UL * 512);
    float* X2   = alloc(4608UL * 512);
    float* BIG  = alloc(4608UL * 2048);
    float* Qb   = alloc(4608UL * 512);
    ushort_t* KHb  = (ushort_t*)alloc(1179648UL);
    ushort_t* KLb  = (ushort_t*)alloc(1179648UL);
    ushort_t* VTHb = (ushort_t*)alloc(1179648UL);
    ushort_t* VTLb = (ushort_t*)alloc(1179648UL);
    unsigned short* WH = (unsigned short*)(ws + off);
    unsigned short* WL = WH + 2621440UL;
    off += 2621440UL;
    // ---- dead-range aliases (stream-ordered, non-overlapping lifetimes) ----
    ushort_t* XNH = (ushort_t*)Qb;             // XN live rms->gemm; Qb live rope->attn
    ushort_t* XNL = XNH + 4608UL * 512;
    ushort_t* AOH = (ushort_t*)BIG;            // AO in BIG (QKV dead after rope/vtrans)
    ushort_t* AOL = AOH + 4608UL * 512;
    ushort_t* MIDH = (ushort_t*)BIG;           // MID in BIG (AO dead after o-proj)
    ushort_t* MIDL = MIDH + 4608UL * 1024;
    ushort_t* RRH = (ushort_t*)X;              // X dead after router_build
    ushort_t* RRL = RRH + 262144;
    float* OUTM = X + 262144;
    float* OUTN = X + 393216;
    float* KRN  = X + 524288;
    float* KGN  = X + 589824;
    (void)ws_size; (void)in_sizes; (void)n_in; (void)out_size;

    copy_in_kernel<<<(2097152 + 255) / 256, 256, 0, stream>>>(x_in, X, 2097152);

    for (int i = 0; i < 4; ++i) {
        split_layer(enc_qkv + (size_t)i * 512 * 1536,
                    enc_o   + (size_t)i * 512 * 512,
                    enc_up  + (size_t)i * 512 * 2048,
                    enc_dn  + (size_t)i * 1024 * 512, WH, WL, stream);
        run_layer(X, BIG, Qb, KHb, KLb, VTHb, VTLb, XNH, XNL, AOH, AOL, MIDH, MIDL,
                  WH, WL, enc_n1 + (size_t)i * 512, enc_n2 + (size_t)i * 512,
                  doc, 2, 2048, stream);
    }

    int rb_total = 64 * 72 * 512;
    router_build_kernel<<<(rb_total + 255) / 256, 256, 0, stream>>>(X, rt, X2, rb_total);

    for (int i = 0; i < 2; ++i) {
        split_layer(rtr_qkv + (size_t)i * 512 * 1536,
                    rtr_o   + (size_t)i * 512 * 512,
                    rtr_up  + (size_t)i * 512 * 2048,
                    rtr_dn  + (size_t)i * 1024 * 512, WH, WL, stream);
        run_layer(X2, BIG, Qb, KHb, KLb, VTHb, VTLb, XNH, XNL, AOH, AOL, MIDH, MIDL,
                  WH, WL, rtr_n1 + (size_t)i * 512, rtr_n2 + (size_t)i * 512,
                  nullptr, 64, 72, stream);
    }

    gather_rows_kernel<<<(512 * 512) / 256, 256, 0, stream>>>(X2, RRH, RRL, 512 * 512);
    wsplit_kernel<<<dim3(8, 16), 256, 0, stream>>>(out_w, WH, WL, 512, 256);
    gemm3<64><<<dim3(2, 8), 256, 0, stream>>>(RRH, RRL, WH, WL, nullptr, OUTM, 512, 256, 512);

    norm_half_kernel<<<1024, 64, 0, stream>>>(OUTM, OUTN);
    norm_keys_kernel<<<512, 64, 0, stream>>>(k_rt, KRN);
    norm_keys_kernel<<<512, 64, 0, stream>>>(k_gt, KGN);
    logits_top2_kernel<<<2048, 64, 0, stream>>>(OUTN, KRN, KGN, (float*)d_out);
}

// Round 10
// 1215.325 us; speedup vs baseline: 1.2979x; 1.0120x over previous
//
#include <hip/hip_runtime.h>
#include <hip/hip_bf16.h>
#include <cstdint>

// ---------------------------------------------------------------------------
// B=2 S=2048 D=512 H=8 HD=64, FFH=1024. Encoder: 4 layers, G=2, Sg=2048
// (block-causal-64 AND doc mask). Router: 2 layers, G=64, Sg=72, full attn.
// Round 19: LDS-bound diagnosis (32 FLOP/LDS-byte => ~21-24% MfmaUtil cap).
//  r4's 3-set counted-vmcnt schedule measured 44.4us on the up-GEMM size vs
//  50us for 2-set vmcnt(0) (r5's revert blamed the wrong variable).
//  - up_silu -> 3-set counted vmcnt(6), 256thr, ROWS=384 (72KB, 2blk/CU),
//    depth-2 prefetch; fusion kept.
//  - o/dn/final -> r4's 3-set gemm3<64> verbatim.
//  - rmsnorm -> 1 wave/token, 4 tokens/block (no LDS reduce, no barriers).
//  qkv(gemm3w) + attn(r9 dead-tile-free) unchanged.
// ---------------------------------------------------------------------------

typedef __attribute__((ext_vector_type(8))) short short8;   // 8 bf16 = 4 VGPR
typedef __attribute__((ext_vector_type(4))) float f32x4;
typedef unsigned short ushort_t;

__device__ __forceinline__ float bf2f(unsigned short u) {
    return __uint_as_float(((unsigned)u) << 16);
}
__device__ __forceinline__ unsigned short f2bf(float f) {
    unsigned u = __float_as_uint(f);
    unsigned r = 0x7FFFu + ((u >> 16) & 1u);
    return (unsigned short)((u + r) >> 16);
}
__device__ __forceinline__ float wave_sum64(float v) {
#pragma unroll
    for (int o = 32; o; o >>= 1) v += __shfl_xor(v, o);
    return v;
}
__device__ __forceinline__ void load_lds16(const ushort_t* g, ushort_t* l) {
    __builtin_amdgcn_global_load_lds(
        (const __attribute__((address_space(1))) unsigned int*)g,
        (__attribute__((address_space(3))) unsigned int*)l, 16, 0, 0);
}

#define MFMA16(a, b, c) __builtin_amdgcn_mfma_f32_16x16x32_bf16(a, b, c, 0, 0, 0)
#define BARRIER_RAW() do { asm volatile("" ::: "memory"); \
    __builtin_amdgcn_s_barrier(); asm volatile("" ::: "memory"); } while (0)
#define VMCNT0() asm volatile("s_waitcnt vmcnt(0)" ::: "memory")

// ---- f32 copy (input x -> mutable X) --------------------------------------
__global__ void copy_in_kernel(const float* __restrict__ src,
                               float* __restrict__ dst, int n) {
    int i = blockIdx.x * 256 + threadIdx.x;
    if (i < n) dst[i] = src[i];
}

// ---- weight transpose + hi/lo bf16 split: W[K,N] -> WT_hi/lo[N,K] ---------
__global__ __launch_bounds__(256) void wsplit_kernel(const float* __restrict__ W,
        unsigned short* __restrict__ WH, unsigned short* __restrict__ WL,
        int K, int N) {
    __shared__ float tile[32][33];
    int bn = blockIdx.x * 32, bk = blockIdx.y * 32;
    int tx = threadIdx.x & 31, ty = threadIdx.x >> 5;
#pragma unroll
    for (int i = 0; i < 4; ++i)
        tile[ty + 8 * i][tx] = W[(size_t)(bk + ty + 8 * i) * N + bn + tx];
    __syncthreads();
#pragma unroll
    for (int i = 0; i < 4; ++i) {
        int n = bn + ty + 8 * i, k = bk + tx;
        float x = tile[tx][ty + 8 * i];
        unsigned short h = f2bf(x);
        unsigned short lo = f2bf(x - bf2f(h));
        WH[(size_t)n * K + k] = h;
        WL[(size_t)n * K + k] = lo;
    }
}

// ---- RMSNorm over D=512: 1 wave per token, 4 tokens/block -----------------
__global__ __launch_bounds__(256) void rmsnorm_kernel(const float* __restrict__ X,
        const float* __restrict__ W, ushort_t* __restrict__ XNH,
        ushort_t* __restrict__ XNL) {
    int w = threadIdx.x >> 6, lane = threadIdx.x & 63;
    int t = blockIdx.x * 4 + w;
    const float* xr = X + (size_t)t * 512;
    float v[8];
    float ss = 0.f;
#pragma unroll
    for (int j = 0; j < 8; ++j) { v[j] = xr[lane + 64 * j]; ss += v[j] * v[j]; }
    ss = wave_sum64(ss);
    float scale = rsqrtf(ss * (1.0f / 512.0f) + 1e-6f);
    size_t base = (size_t)t * 512;
#pragma unroll
    for (int j = 0; j < 8; ++j) {
        float a = v[j] * scale * W[lane + 64 * j];
        unsigned short h = f2bf(a);
        XNH[base + lane + 64 * j] = h;
        XNL[base + lane + 64 * j] = f2bf(a - bf2f(h));
    }
}

// ---- bf16x3 MFMA GEMM: 3-set LDS, counted vmcnt, depth-2 (r4 proven) ------
// C[M,N] = A @ B^T (+Res). Tile BM x 128, BK=32, 256 thr = 4 waves.
// Flat set rows: [0,BM)=Ah, [BM,2BM)=Al, [2BM,2BM+128)=Bh, rest Bl.
template <int BM>
__global__ __launch_bounds__(256) void gemm3(
        const ushort_t* __restrict__ AH, const ushort_t* __restrict__ AL,
        const ushort_t* __restrict__ BH, const ushort_t* __restrict__ BL,
        const float* __restrict__ Res, float* __restrict__ C,
        int M, int N, int K) {
    constexpr int MI   = BM / 32;
    constexpr int ROWS = 2 * BM + 256;
    constexpr int LPW  = ROWS / 64;
    constexpr int SS   = ROWS * 32;
    __shared__ __align__(16) ushort_t S[3][ROWS][32];
    int tid = threadIdx.x;
    int n0 = blockIdx.x * 128, m0 = blockIdx.y * BM;
    int wid = tid >> 6, lane = tid & 63;
    int wm = (wid >> 1) * (BM / 2), wn = (wid & 1) * 64;
    int col = lane & 15, quad = lane >> 4;

    const ushort_t* gsrc[LPW];
    int ldof[LPW];
#pragma unroll
    for (int j = 0; j < LPW; ++j) {
        int e = wid * LPW + j;
        int srow = e * 16 + (lane >> 2);
        const ushort_t* gp; int rin;
        if (srow < BM)                { gp = AH + (size_t)m0 * K; rin = srow; }
        else if (srow < 2 * BM)       { gp = AL + (size_t)m0 * K; rin = srow - BM; }
        else if (srow < 2 * BM + 128) { gp = BH + (size_t)n0 * K; rin = srow - 2 * BM; }
        else                          { gp = BL + (size_t)n0 * K; rin = srow - 2 * BM - 128; }
        gsrc[j] = gp + (size_t)rin * K + ((lane & 3) ^ ((lane >> 3) & 3)) * 8;
        ldof[j] = e * 512;
    }
    ushort_t* sbase = &S[0][0][0];
    auto STAGE = [&](int set, int kc) {
        ushort_t* sb = sbase + set * SS;
#pragma unroll
        for (int j = 0; j < LPW; ++j)
            load_lds16(gsrc[j] + kc * 32, sb + ldof[j]);
    };
    auto WAITK = [&]() {   // keep newest stage (LPW loads) in flight
        if constexpr (BM == 64) asm volatile("s_waitcnt vmcnt(6)" ::: "memory");
        else                    asm volatile("s_waitcnt vmcnt(8)" ::: "memory");
    };

    int chrd = (quad ^ ((col >> 1) & 3)) * 8;
    f32x4 acc[MI][4] = {};
    int nk = K >> 5;
    STAGE(0, 0);
    if (nk > 1) { STAGE(1, 1); WAITK(); }
    else        { VMCNT0(); }
    BARRIER_RAW();
    int sc = 0, sn = 1, sp = 2;
#pragma unroll 1
    for (int kc = 0; kc < nk; ++kc) {
        if (kc + 2 < nk) STAGE(sp, kc + 2);
        const ushort_t* sb = sbase + sc * SS;
        short8 afh[MI], afl[MI], bfh[4], bfl[4];
#pragma unroll
        for (int i = 0; i < MI; ++i) {
            afh[i] = *(const short8*)(sb + (size_t)(wm + i * 16 + col) * 32 + chrd);
            afl[i] = *(const short8*)(sb + (size_t)(BM + wm + i * 16 + col) * 32 + chrd);
        }
#pragma unroll
        for (int i = 0; i < 4; ++i) {
            bfh[i] = *(const short8*)(sb + (size_t)(2 * BM + wn + i * 16 + col) * 32 + chrd);
            bfl[i] = *(const short8*)(sb + (size_t)(2 * BM + 128 + wn + i * 16 + col) * 32 + chrd);
        }
#pragma unroll
        for (int mi = 0; mi < MI; ++mi)
#pragma unroll
            for (int ni = 0; ni < 4; ++ni) {
                f32x4 c = acc[mi][ni];
                c = MFMA16(afh[mi], bfh[ni], c);
                c = MFMA16(afh[mi], bfl[ni], c);
                c = MFMA16(afl[mi], bfh[ni], c);
                acc[mi][ni] = c;
            }
        if (kc + 1 < nk) {
            if (kc + 2 < nk) WAITK();
            else VMCNT0();
            BARRIER_RAW();
        }
        int t = sc; sc = sn; sn = sp; sp = t;
    }
#pragma unroll
    for (int mi = 0; mi < MI; ++mi)
#pragma unroll
        for (int ni = 0; ni < 4; ++ni)
#pragma unroll
            for (int r = 0; r < 4; ++r) {
                int row = m0 + wm + mi * 16 + quad * 4 + r;
                int ccol = n0 + wn + ni * 16 + col;
                size_t o = (size_t)row * N + ccol;
                float v = acc[mi][ni][r];
                if (Res) v += Res[o];
                C[o] = v;
            }
}

// ---- bf16x3 GEMM, 512 thr (8 waves 4Mx2N), 128x128 tile, 2-set 64KB -------
__global__ __launch_bounds__(512, 4) void gemm3w(
        const ushort_t* __restrict__ AH, const ushort_t* __restrict__ AL,
        const ushort_t* __restrict__ BH, const ushort_t* __restrict__ BL,
        const float* __restrict__ Res, float* __restrict__ C,
        int M, int N, int K) {
    constexpr int ROWS = 512;
    constexpr int LPW  = 4;
    constexpr int SS   = ROWS * 32;
    __shared__ __align__(16) ushort_t S[2][ROWS][32];
    int tid = threadIdx.x;
    int n0 = blockIdx.x * 128, m0 = blockIdx.y * 128;
    int wid = tid >> 6, lane = tid & 63;
    int wm = (wid >> 1) * 32, wn = (wid & 1) * 64;
    int col = lane & 15, quad = lane >> 4;

    const ushort_t* gsrc[LPW];
    int ldof[LPW];
#pragma unroll
    for (int j = 0; j < LPW; ++j) {
        int e = wid * LPW + j;
        int srow = e * 16 + (lane >> 2);
        const ushort_t* gp; int rin;
        if (srow < 128)      { gp = AH; rin = m0 + srow; }
        else if (srow < 256) { gp = AL; rin = m0 + srow - 128; }
        else if (srow < 384) { gp = BH; rin = n0 + srow - 256; }
        else                 { gp = BL; rin = n0 + srow - 384; }
        gsrc[j] = gp + (size_t)rin * K + ((lane & 3) ^ ((lane >> 3) & 3)) * 8;
        ldof[j] = e * 512;
    }
    ushort_t* sbase = &S[0][0][0];
    auto STAGE = [&](int set, int kc) {
        ushort_t* sb = sbase + set * SS;
#pragma unroll
        for (int j = 0; j < LPW; ++j)
            load_lds16(gsrc[j] + kc * 32, sb + ldof[j]);
    };

    int chrd = (quad ^ ((col >> 1) & 3)) * 8;
    f32x4 acc[2][4] = {};
    int nk = K >> 5;
    STAGE(0, 0);
    VMCNT0();
    BARRIER_RAW();
    int cur = 0;
#pragma unroll 1
    for (int kc = 0; kc < nk; ++kc) {
        if (kc + 1 < nk) STAGE(cur ^ 1, kc + 1);
        const ushort_t* sb = sbase + cur * SS;
        short8 afh[2], afl[2], bfh[4], bfl[4];
#pragma unroll
        for (int i = 0; i < 2; ++i) {
            afh[i] = *(const short8*)(sb + (size_t)(wm + i * 16 + col) * 32 + chrd);
            afl[i] = *(const short8*)(sb + (size_t)(128 + wm + i * 16 + col) * 32 + chrd);
        }
#pragma unroll
        for (int i = 0; i < 4; ++i) {
            bfh[i] = *(const short8*)(sb + (size_t)(256 + wn + i * 16 + col) * 32 + chrd);
            bfl[i] = *(const short8*)(sb + (size_t)(384 + wn + i * 16 + col) * 32 + chrd);
        }
#pragma unroll
        for (int mi = 0; mi < 2; ++mi)
#pragma unroll
            for (int ni = 0; ni < 4; ++ni) {
                f32x4 c = acc[mi][ni];
                c = MFMA16(afh[mi], bfh[ni], c);
                c = MFMA16(afh[mi], bfl[ni], c);
                c = MFMA16(afl[mi], bfh[ni], c);
                acc[mi][ni] = c;
            }
        if (kc + 1 < nk) {
            VMCNT0();
            BARRIER_RAW();
            cur ^= 1;
        }
    }
#pragma unroll
    for (int mi = 0; mi < 2; ++mi)
#pragma unroll
        for (int ni = 0; ni < 4; ++ni)
#pragma unroll
            for (int r = 0; r < 4; ++r) {
                int row = m0 + wm + mi * 16 + quad * 4 + r;
                int ccol = n0 + wn + ni * 16 + col;
                size_t o = (size_t)row * N + ccol;
                float v = acc[mi][ni][r];
                if (Res) v += Res[o];
                C[o] = v;
            }
}

// ---- fused up-proj + silu: 3-set counted-vmcnt, 256 thr -------------------
// Tile: 64 M x 64 h-cols (both panels => 64x128 of GEMM output). 4 waves
// (2Mx2H), wave 32M x 32h x both panels = 24 MFMA/iter. Set rows: [0,64)Ah
// [64,128)Al [128,192)B1h [192,256)B1l [256,320)B2h [320,384)B2l. ROWS=384,
// LPW=6, 3 sets = 72KB -> 2 blk/CU. Grid (16, T/64).
__global__ __launch_bounds__(256) void gemm_up_silu(
        const ushort_t* __restrict__ AH, const ushort_t* __restrict__ AL,
        const ushort_t* __restrict__ BH, const ushort_t* __restrict__ BL,
        ushort_t* __restrict__ MIDH, ushort_t* __restrict__ MIDL, int K) {
    constexpr int ROWS = 384;
    constexpr int LPW  = 6;
    constexpr int SS   = ROWS * 32;
    __shared__ __align__(16) ushort_t S[3][ROWS][32];
    int tid = threadIdx.x;
    int n0 = blockIdx.x * 64, m0 = blockIdx.y * 64;
    int wid = tid >> 6, lane = tid & 63;
    int wm = (wid >> 1) * 32, wn = (wid & 1) * 32;
    int col = lane & 15, quad = lane >> 4;

    const ushort_t* gsrc[LPW];
    int ldof[LPW];
#pragma unroll
    for (int j = 0; j < LPW; ++j) {
        int e = wid * LPW + j;
        int srow = e * 16 + (lane >> 2);
        const ushort_t* gp; int rin;
        if (srow < 64)       { gp = AH; rin = m0 + srow; }
        else if (srow < 128) { gp = AL; rin = m0 + srow - 64; }
        else if (srow < 192) { gp = BH; rin = n0 + srow - 128; }
        else if (srow < 256) { gp = BL; rin = n0 + srow - 192; }
        else if (srow < 320) { gp = BH; rin = 1024 + n0 + srow - 256; }
        else                 { gp = BL; rin = 1024 + n0 + srow - 320; }
        gsrc[j] = gp + (size_t)rin * K + ((lane & 3) ^ ((lane >> 3) & 3)) * 8;
        ldof[j] = e * 512;
    }
    ushort_t* sbase = &S[0][0][0];
    auto STAGE = [&](int set, int kc) {
        ushort_t* sb = sbase + set * SS;
#pragma unroll
        for (int j = 0; j < LPW; ++j)
            load_lds16(gsrc[j] + kc * 32, sb + ldof[j]);
    };
    auto WAITK = [&]() { asm volatile("s_waitcnt vmcnt(6)" ::: "memory"); };

    int chrd = (quad ^ ((col >> 1) & 3)) * 8;
    f32x4 a1[2][2] = {}, a2[2][2] = {};
    int nk = K >> 5;
    STAGE(0, 0);
    if (nk > 1) { STAGE(1, 1); WAITK(); }
    else        { VMCNT0(); }
    BARRIER_RAW();
    int sc = 0, sn = 1, sp = 2;
#pragma unroll 1
    for (int kc = 0; kc < nk; ++kc) {
        if (kc + 2 < nk) STAGE(sp, kc + 2);
        const ushort_t* sb = sbase + sc * SS;
        short8 afh[2], afl[2], b1h[2], b1l[2], b2h[2], b2l[2];
#pragma unroll
        for (int i = 0; i < 2; ++i) {
            afh[i] = *(const short8*)(sb + (size_t)(wm + i * 16 + col) * 32 + chrd);
            afl[i] = *(const short8*)(sb + (size_t)(64 + wm + i * 16 + col) * 32 + chrd);
            b1h[i] = *(const short8*)(sb + (size_t)(128 + wn + i * 16 + col) * 32 + chrd);
            b1l[i] = *(const short8*)(sb + (size_t)(192 + wn + i * 16 + col) * 32 + chrd);
            b2h[i] = *(const short8*)(sb + (size_t)(256 + wn + i * 16 + col) * 32 + chrd);
            b2l[i] = *(const short8*)(sb + (size_t)(320 + wn + i * 16 + col) * 32 + chrd);
        }
#pragma unroll
        for (int mi = 0; mi < 2; ++mi)
#pragma unroll
            for (int ni = 0; ni < 2; ++ni) {
                f32x4 c = a1[mi][ni];
                c = MFMA16(afh[mi], b1h[ni], c);
                c = MFMA16(afh[mi], b1l[ni], c);
                c = MFMA16(afl[mi], b1h[ni], c);
                a1[mi][ni] = c;
                f32x4 d = a2[mi][ni];
                d = MFMA16(afh[mi], b2h[ni], d);
                d = MFMA16(afh[mi], b2l[ni], d);
                d = MFMA16(afl[mi], b2h[ni], d);
                a2[mi][ni] = d;
            }
        if (kc + 1 < nk) {
            if (kc + 2 < nk) WAITK();
            else VMCNT0();
            BARRIER_RAW();
        }
        int t = sc; sc = sn; sn = sp; sp = t;
    }
#pragma unroll
    for (int mi = 0; mi < 2; ++mi)
#pragma unroll
        for (int ni = 0; ni < 2; ++ni)
#pragma unroll
            for (int r = 0; r < 4; ++r) {
                int row = m0 + wm + mi * 16 + quad * 4 + r;
                int ccol = n0 + wn + ni * 16 + col;
                float v1 = a1[mi][ni][r], v2 = a2[mi][ni][r];
                float rr = (v1 / (1.0f + __expf(-v1))) * v2;
                unsigned short h = f2bf(rr);
                size_t o = (size_t)row * 1024 + ccol;
                MIDH[o] = h;
                MIDL[o] = f2bf(rr - bf2f(h));
            }
}

// ---- split qkv + RoPE; Q f32 (g,h,s,hd); K bf16 hi/lo [gh][Sg][64] --------
__global__ void rope_pack_kernel(const float* __restrict__ QKV,
        float* __restrict__ Q, ushort_t* __restrict__ KH,
        ushort_t* __restrict__ KL, int Sg, int total) {
    int idx = blockIdx.x * 256 + threadIdx.x;
    if (idx >= total) return;
    int i = idx & 31;
    int h = (idx >> 5) & 7;
    int t = idx >> 8;
    int g = t / Sg; int s = t - g * Sg;
    const float* row = QKV + (size_t)t * 1536;
    float inv = powf(10000.0f, -(float)(2 * i) / 64.0f);
    float sn, cs;
    sincosf((float)s * inv, &sn, &cs);
    size_t ob = ((size_t)(g * 8 + h) * Sg + s) * 64 + i;
    int c = h * 64 + i;
    float q1 = row[c], q2 = row[c + 32];
    Q[ob]      = q1 * cs + q2 * sn;
    Q[ob + 32] = q2 * cs - q1 * sn;
    float k1 = row[512 + c], k2 = row[512 + c + 32];
    float ka = k1 * cs + k2 * sn;
    float kb = k2 * cs - k1 * sn;
    unsigned short ha = f2bf(ka), hb = f2bf(kb);
    KH[ob]      = ha;  KL[ob]      = f2bf(ka - bf2f(ha));
    KH[ob + 32] = hb;  KL[ob + 32] = f2bf(kb - bf2f(hb));
}

// ---- V^T split: QKV f32 [T][1536] -> VT hi/lo [gh][64 d][Sg s] ------------
__global__ __launch_bounds__(256) void vtrans_kernel(const float* __restrict__ QKV,
        ushort_t* __restrict__ VTH, ushort_t* __restrict__ VTL, int Sg) {
    __shared__ float tile[64][65];
    int chunk = blockIdx.x, gh = blockIdx.y;
    int g = gh >> 3, h = gh & 7;
    int tid = threadIdx.x;
    int sr = tid >> 2, dc = (tid & 3) * 16;
    int s = chunk * 64 + sr;
    if (s < Sg) {
        const float* src = QKV + ((size_t)g * Sg + s) * 1536 + 1024 + h * 64 + dc;
#pragma unroll
        for (int j = 0; j < 4; ++j) {
            float4 v = *(const float4*)(src + 4 * j);
            tile[sr][dc + 4 * j]     = v.x;
            tile[sr][dc + 4 * j + 1] = v.y;
            tile[sr][dc + 4 * j + 2] = v.z;
            tile[sr][dc + 4 * j + 3] = v.w;
        }
    } else {
#pragma unroll
        for (int j = 0; j < 16; ++j) tile[sr][dc + j] = 0.f;
    }
    __syncthreads();
    int dr = tid >> 2, sc = (tid & 3) * 16;
    short8 hv[2], lv[2];
#pragma unroll
    for (int half = 0; half < 2; ++half)
#pragma unroll
        for (int j = 0; j < 8; ++j) {
            float v = tile[sc + half * 8 + j][dr];
            unsigned short hb = f2bf(v);
            hv[half][j] = (short)hb;
            lv[half][j] = (short)f2bf(v - bf2f(hb));
        }
    int scol = chunk * 64 + sc;
    size_t ob = ((size_t)gh * 64 + dr) * Sg + scol;
    if (scol + 16 <= Sg) {
        *(short8*)(VTH + ob)     = hv[0];
        *(short8*)(VTH + ob + 8) = hv[1];
        *(short8*)(VTL + ob)     = lv[0];
        *(short8*)(VTL + ob + 8) = lv[1];
    } else {
#pragma unroll
        for (int j = 0; j < 16; ++j)
            if (scol + j < Sg) {
                VTH[ob + j] = (ushort_t)((j < 8) ? hv[0][j] : hv[1][j - 8]);
                VTL[ob + j] = (ushort_t)((j < 8) ? lv[0][j] : lv[1][j - 8]);
            }
    }
}

// ---- MFMA flash attention (bf16x3), contiguous live k-range ---------------
template <bool MASKED>
__global__ __launch_bounds__(256, 3) void attn3_kernel(const float* __restrict__ Q,
        const ushort_t* __restrict__ KHg, const ushort_t* __restrict__ KLg,
        const ushort_t* __restrict__ VTHg, const ushort_t* __restrict__ VTLg,
        const int* __restrict__ doc, ushort_t* __restrict__ AOH,
        ushort_t* __restrict__ AOL, int Sg) {
    __shared__ __align__(16) ushort_t Khs[64][64], Kls[64][64];  // swizzled
    __shared__ __align__(16) ushort_t Vts[64][64], Vtl[64][64];  // swizzled
    __shared__ __align__(16) ushort_t Ph[4][16][72], Pl[4][16][72];
    __shared__ int dock[64];
    __shared__ int dmax_s[32];
    int qb = (int)(gridDim.x - 1 - blockIdx.x);   // big qb first (load balance)
    int gh = blockIdx.y, g = gh >> 3;
    int tid = threadIdx.x, wid = tid >> 6, lane = tid & 63;
    int col = lane & 15, quad = lane >> 4;

    int rL = lane >> 3, cSw = (lane & 7) ^ rL;
    const ushort_t* kb;      // K waves: row base (chunk folded in)
    const ushort_t* vb;      // V waves: d-row base
    ushort_t* lb;
    if (wid == 0)      { kb = KHg + (size_t)gh * Sg * 64 + cSw * 8;  vb = nullptr; lb = &Khs[0][0]; }
    else if (wid == 1) { kb = KLg + (size_t)gh * Sg * 64 + cSw * 8;  vb = nullptr; lb = &Kls[0][0]; }
    else if (wid == 2) { vb = VTHg + ((size_t)gh * 64 + rL) * Sg;    kb = nullptr; lb = &Vts[0][0]; }
    else               { vb = VTLg + ((size_t)gh * 64 + rL) * Sg;    kb = nullptr; lb = &Vtl[0][0]; }
    int sw0 = ((0 + quad) ^ (col & 7)) * 8;
    int sw1 = ((4 + quad) ^ (col & 7)) * 8;

    short8 qa[2][2];  // [kk][0=hi,1=lo]
    {
        int qrow = qb * 64 + wid * 16 + col;
        if (qrow >= Sg) qrow = Sg - 1;
        const float* Qg = Q + ((size_t)gh * Sg + qrow) * 64 + quad * 8;
#pragma unroll
        for (int kk = 0; kk < 2; ++kk) {
            float4 v0 = *(const float4*)(Qg + kk * 32);
            float4 v1 = *(const float4*)(Qg + kk * 32 + 4);
            float vv[8] = {v0.x, v0.y, v0.z, v0.w, v1.x, v1.y, v1.z, v1.w};
            short8 h, l;
#pragma unroll
            for (int e = 0; e < 8; ++e) {
                float x = vv[e] * 0.125f;
                unsigned short hb = f2bf(x);
                h[e] = (short)hb;
                l[e] = (short)f2bf(x - bf2f(hb));
            }
            qa[kk][0] = h; qa[kk][1] = l;
        }
    }
    int dqr[4]; int wq0 = 0, wq1 = 0, bq0 = 0;
    int kts = 0;
    if (MASKED) {
        const int* db = doc + (size_t)g * Sg + qb * 64;
#pragma unroll
        for (int r = 0; r < 4; ++r) dqr[r] = db[wid * 16 + quad * 4 + r];
        wq0 = db[wid * 16]; wq1 = db[wid * 16 + 15];
        bq0 = db[0];
        int nkb = (Sg + 63) >> 6;
        if (tid < nkb) dmax_s[tid] = doc[(size_t)g * Sg + tid * 64 + 63];
        __syncthreads();
        int kbv = 0;
        while (kbv < nkb && dmax_s[kbv] < bq0) ++kbv;
        kts = kbv;
    }
    float m[4], l[4];
    f32x4 accO[4];
#pragma unroll
    for (int r = 0; r < 4; ++r) { m[r] = -1e30f; l[r] = 0.f; }
#pragma unroll
    for (int nd = 0; nd < 4; ++nd) accO[nd] = (f32x4){0.f, 0.f, 0.f, 0.f};

    int nkt = MASKED ? (qb + 1) : ((Sg + 63) >> 6);
    for (int kt = kts; kt < nkt; ++kt) {
        int kval = Sg - kt * 64; if (kval > 64) kval = 64;
        __syncthreads();
        if (wid < 2) {
#pragma unroll
            for (int p = 0; p < 8; ++p) {
                int sr2 = kt * 64 + p * 8 + rL;
                if (sr2 > Sg - 1) sr2 = Sg - 1;
                load_lds16(kb + (size_t)sr2 * 64, lb + p * 512);
            }
        } else {
            int vc = kt * 64 + cSw * 8;
            if (vc > Sg - 8) vc = Sg - 8;
#pragma unroll
            for (int p = 0; p < 8; ++p)
                load_lds16(vb + (size_t)(p * 8) * Sg + vc, lb + p * 512);
        }
        if (MASKED && tid < 64) dock[tid] = doc[(size_t)g * Sg + kt * 64 + tid];
        __syncthreads();
        bool wskip = false;
        if (MASKED) wskip = (dock[kval - 1] < wq0);
        if (!wskip) {
            int dk[4];
            if (MASKED) {
#pragma unroll
                for (int ni = 0; ni < 4; ++ni) dk[ni] = dock[ni * 16 + col];
            }
            f32x4 sc[4];
            __builtin_amdgcn_s_setprio(1);
#pragma unroll
            for (int ni = 0; ni < 4; ++ni) {
                int rb = (ni * 16 + col) * 64;
                short8 bh0 = *(const short8*)(&Khs[0][0] + rb + sw0);
                short8 bl0 = *(const short8*)(&Kls[0][0] + rb + sw0);
                short8 bh1 = *(const short8*)(&Khs[0][0] + rb + sw1);
                short8 bl1 = *(const short8*)(&Kls[0][0] + rb + sw1);
                f32x4 c = (f32x4){0.f, 0.f, 0.f, 0.f};
                c = MFMA16(qa[0][0], bh0, c);
                c = MFMA16(qa[0][0], bl0, c);
                c = MFMA16(qa[0][1], bh0, c);
                c = MFMA16(qa[1][0], bh1, c);
                c = MFMA16(qa[1][0], bl1, c);
                c = MFMA16(qa[1][1], bh1, c);
                sc[ni] = c;
            }
            __builtin_amdgcn_s_setprio(0);
            float mnew[4];
#pragma unroll
            for (int r = 0; r < 4; ++r) mnew[r] = -1e30f;
#pragma unroll
            for (int ni = 0; ni < 4; ++ni)
#pragma unroll
                for (int r = 0; r < 4; ++r) {
                    bool ok = MASKED ? (dk[ni] == dqr[r]) : (ni * 16 + col < kval);
                    float s = ok ? sc[ni][r] : -1e30f;
                    sc[ni][r] = s;
                    mnew[r] = fmaxf(mnew[r], s);
                }
#pragma unroll
            for (int r = 0; r < 4; ++r)
#pragma unroll
                for (int o = 1; o < 16; o <<= 1)
                    mnew[r] = fmaxf(mnew[r], __shfl_xor(mnew[r], o));
            float alpha[4], lsum[4];
#pragma unroll
            for (int r = 0; r < 4; ++r) {
                float M = fmaxf(m[r], mnew[r]);
                alpha[r] = __expf(m[r] - M);
                m[r] = M;
                lsum[r] = 0.f;
            }
#pragma unroll
            for (int ni = 0; ni < 4; ++ni)
#pragma unroll
                for (int r = 0; r < 4; ++r) {
                    bool ok = MASKED ? (dk[ni] == dqr[r]) : (ni * 16 + col < kval);
                    float p = ok ? __expf(sc[ni][r] - m[r]) : 0.f;
                    lsum[r] += p;
                    unsigned short h = f2bf(p);
                    Ph[wid][quad * 4 + r][ni * 16 + col] = h;
                    Pl[wid][quad * 4 + r][ni * 16 + col] = f2bf(p - bf2f(h));
                }
#pragma unroll
            for (int r = 0; r < 4; ++r) {
#pragma unroll
                for (int o = 1; o < 16; o <<= 1)
                    lsum[r] += __shfl_xor(lsum[r], o);
                l[r] = l[r] * alpha[r] + lsum[r];
            }
#pragma unroll
            for (int nd = 0; nd < 4; ++nd)
#pragma unroll
                for (int r = 0; r < 4; ++r) accO[nd][r] *= alpha[r];
            __builtin_amdgcn_s_setprio(1);
#pragma unroll
            for (int kk = 0; kk < 2; ++kk) {
                short8 pah = *(const short8*)&Ph[wid][col][kk * 32 + quad * 8];
                short8 pal = *(const short8*)&Pl[wid][col][kk * 32 + quad * 8];
                int sw = kk ? sw1 : sw0;
#pragma unroll
                for (int nd = 0; nd < 4; ++nd) {
                    int rb = (nd * 16 + col) * 64;
                    short8 vbh = *(const short8*)(&Vts[0][0] + rb + sw);
                    short8 vbl = *(const short8*)(&Vtl[0][0] + rb + sw);
                    f32x4 c = accO[nd];
                    c = MFMA16(pah, vbh, c);
                    c = MFMA16(pah, vbl, c);
                    c = MFMA16(pal, vbh, c);
                    accO[nd] = c;
                }
            }
            __builtin_amdgcn_s_setprio(0);
        }
    }
#pragma unroll
    for (int r = 0; r < 4; ++r) {
        int qrow = qb * 64 + wid * 16 + quad * 4 + r;
        if (qrow < Sg) {
            float inv = 1.0f / l[r];
            size_t base = ((size_t)g * Sg + qrow) * 512 + (gh & 7) * 64;
#pragma unroll
            for (int nd = 0; nd < 4; ++nd) {
                float val = accO[nd][r] * inv;
                unsigned short h = f2bf(val);
                AOH[base + nd * 16 + col] = h;
                AOL[base + nd * 16 + col] = f2bf(val - bf2f(h));
            }
        }
    }
}

// ---- build router stream: (64 groups) x (64 tokens + 8 router tokens) -----
__global__ void router_build_kernel(const float* __restrict__ X,
        const float* __restrict__ RT, float* __restrict__ X2, int total) {
    int idx = blockIdx.x * 256 + threadIdx.x;
    if (idx >= total) return;
    int d = idx & 511;
    int p = (idx >> 9) % 72;
    int g2 = idx / (72 * 512);
    X2[idx] = (p < 64) ? X[((size_t)g2 * 64 + p) * 512 + d]
                       : RT[(p - 64) * 512 + d];
}

// ---- gather xr[:,64:72,:] into dense (512,512) bf16 hi/lo -----------------
__global__ void gather_rows_kernel(const float* __restrict__ X2,
        ushort_t* __restrict__ RRH, ushort_t* __restrict__ RRL, int total) {
    int idx = blockIdx.x * 256 + threadIdx.x;
    if (idx >= total) return;
    int d = idx & 511;
    int row = idx >> 9;
    int g2 = row >> 3, rr = row & 7;
    float v = X2[((size_t)(g2 * 72 + 64 + rr)) * 512 + d];
    unsigned short h = f2bf(v);
    RRH[idx] = h;
    RRL[idx] = f2bf(v - bf2f(h));
}

// ---- l2-normalize each 128-half of each out row (l2n commutes w/ expand) --
__global__ __launch_bounds__(64) void norm_half_kernel(const float* __restrict__ IN,
        float* __restrict__ OUT) {
    int b = blockIdx.x; int lane = threadIdx.x;
    size_t base = (size_t)(b >> 1) * 256 + (size_t)(b & 1) * 128;
    float v0 = IN[base + lane], v1 = IN[base + 64 + lane];
    float ss = wave_sum64(v0 * v0 + v1 * v1);
    float sc = 1.0f / fmaxf(sqrtf(ss), 1e-12f);
    OUT[base + lane]      = v0 * sc;
    OUT[base + 64 + lane] = v1 * sc;
}

// ---- l2-normalize key columns: keys (32,128,16) over d --------------------
__global__ __launch_bounds__(64) void norm_keys_kernel(const float* __restrict__ Kin,
        float* __restrict__ Kout) {
    int b = blockIdx.x; int lane = threadIdx.x;
    int g = b >> 4, e = b & 15;
    size_t base = (size_t)g * 2048 + e;
    float v0 = Kin[base + (size_t)lane * 16];
    float v1 = Kin[base + (size_t)(lane + 64) * 16];
    float ss = wave_sum64(v0 * v0 + v1 * v1);
    float sc = 1.0f / fmaxf(sqrtf(ss), 1e-12f);
    Kout[base + (size_t)lane * 16]        = v0 * sc;
    Kout[base + (size_t)(lane + 64) * 16] = v1 * sc;
}

// ---- logits + top2 (stable, jax tie-break) --------------------------------
__global__ __launch_bounds__(64) void logits_top2_kernel(const float* __restrict__ OUTN,
        const float* __restrict__ KRN, const float* __restrict__ KGN,
        float* __restrict__ out) {
    int blk = blockIdx.x;
    int g = blk >> 6, bcol = blk & 63;
    int b = bcol >> 5, l = bcol & 31;
    int lsrc = (l + 31) & 31;     // roll(+1): element l comes from l-1
    int r = g >> 2;               // repeat RM=4
    int row = (b * 32 + lsrc) * 8 + r;
    const float* rvec = OUTN + (size_t)row * 256;
    __shared__ float sc[32];
    int lane = threadIdx.x;
    if (lane < 32) {
        int e = lane & 15;
        const float* kb = ((lane < 16) ? KRN : KGN) + (size_t)g * 2048 + e;
        const float* xv = (lane < 16) ? rvec : (rvec + 128);
        float s = 0.f;
#pragma unroll 8
        for (int d = 0; d < 128; ++d) s = fmaf(xv[d], kb[(size_t)d * 16], s);
        sc[lane] = s;
    }
    __syncthreads();
    if (lane == 0) {
        float bv = -1e30f, sv = -1e30f; int bi = 0, si = 0;
#pragma unroll
        for (int e = 0; e < 16; ++e) {
            float v = sc[e];
            if (v > bv) { sv = bv; si = bi; bv = v; bi = e; }
            else if (v > sv) { sv = v; si = e; }
        }
        size_t base = (size_t)g * 128 + (size_t)bcol * 2;
        out[base]            = bv;
        out[base + 1]        = sv;
        out[4096 + base]     = sc[16 + bi];
        out[4096 + base + 1] = sc[16 + si];
    }
}

// ---------------------------------------------------------------------------
static void run_layer(float* X, float* BIG, float* Qb,
                      ushort_t* KHb, ushort_t* KLb, ushort_t* VTHb, ushort_t* VTLb,
                      ushort_t* XNH, ushort_t* XNL, ushort_t* AOH, ushort_t* AOL,
                      ushort_t* MIDH, ushort_t* MIDL,
                      const unsigned short* WH, const unsigned short* WL,
                      const float* n1, const float* n2,
                      const int* doc, int G, int Sg, hipStream_t stream) {
    const size_t oQKV = 0, oO = 786432, oUP = 1048576, oDN = 2097152;
    int T = G * Sg;
    rmsnorm_kernel<<<T / 4, 256, 0, stream>>>(X, n1, XNH, XNL);
    gemm3w<<<dim3(12, T / 128), 512, 0, stream>>>(XNH, XNL, WH + oQKV, WL + oQKV, nullptr, BIG, T, 1536, 512);
    int rp = T * 256;
    rope_pack_kernel<<<(rp + 255) / 256, 256, 0, stream>>>(BIG, Qb, KHb, KLb, Sg, rp);
    int qblocks = (Sg + 63) >> 6;
    vtrans_kernel<<<dim3(qblocks, G * 8), 256, 0, stream>>>(BIG, VTHb, VTLb, Sg);
    if (doc)
        attn3_kernel<true><<<dim3(qblocks, G * 8), 256, 0, stream>>>(Qb, KHb, KLb, VTHb, VTLb, doc, AOH, AOL, Sg);
    else
        attn3_kernel<false><<<dim3(qblocks, G * 8), 256, 0, stream>>>(Qb, KHb, KLb, VTHb, VTLb, nullptr, AOH, AOL, Sg);
    gemm3<64><<<dim3(4, T / 64), 256, 0, stream>>>(AOH, AOL, WH + oO, WL + oO, X, X, T, 512, 512);
    rmsnorm_kernel<<<T / 4, 256, 0, stream>>>(X, n2, XNH, XNL);
    gemm_up_silu<<<dim3(16, T / 64), 256, 0, stream>>>(XNH, XNL, WH + oUP, WL + oUP, MIDH, MIDL, 512);
    gemm3<64><<<dim3(4, T / 64), 256, 0, stream>>>(MIDH, MIDL, WH + oDN, WL + oDN, X, X, T, 512, 1024);
}

static void split_layer(const float* qkv, const float* o, const float* up, const float* dn,
                        unsigned short* WH, unsigned short* WL, hipStream_t stream) {
    const size_t oQKV = 0, oO = 786432, oUP = 1048576, oDN = 2097152;
    wsplit_kernel<<<dim3(48, 16), 256, 0, stream>>>(qkv, WH + oQKV, WL + oQKV, 512, 1536);
    wsplit_kernel<<<dim3(16, 16), 256, 0, stream>>>(o,   WH + oO,   WL + oO,   512, 512);
    wsplit_kernel<<<dim3(64, 16), 256, 0, stream>>>(up,  WH + oUP,  WL + oUP,  512, 2048);
    wsplit_kernel<<<dim3(16, 32), 256, 0, stream>>>(dn,  WH + oDN,  WL + oDN,  1024, 512);
}

extern "C" void kernel_launch(void* const* d_in, const int* in_sizes, int n_in,
                              void* d_out, int out_size, void* d_ws, size_t ws_size,
                              hipStream_t stream) {
    const float* x_in    = (const float*)d_in[0];
    const int*   doc     = (const int*)d_in[1];
    const float* rt      = (const float*)d_in[2];
    const float* out_w   = (const float*)d_in[3];
    const float* k_rt    = (const float*)d_in[4];
    const float* k_gt    = (const float*)d_in[5];
    const float* enc_qkv = (const float*)d_in[6];
    const float* enc_o   = (const float*)d_in[7];
    const float* enc_up  = (const float*)d_in[8];
    const float* enc_dn  = (const float*)d_in[9];
    const float* enc_n1  = (const float*)d_in[10];
    const float* enc_n2  = (const float*)d_in[11];
    const float* rtr_qkv = (const float*)d_in[12];
    const float* rtr_o   = (const float*)d_in[13];
    const float* rtr_up  = (const float*)d_in[14];
    const float* rtr_dn  = (const float*)d_in[15];
    const float* rtr_n1  = (const float*)d_in[16];
    const float* rtr_n2  = (const float*)d_in[17];

    float* ws = (float*)d_ws;
    size_t off = 0;
    auto alloc = [&](size_t n) { float* p = ws + off; off += n; return p; };
    float* X    = alloc(4608UL * 512);
    float* X2   = alloc(4608UL * 512);
    float* BIG  = alloc(4608UL * 2048);
    float* Qb   = alloc(4608UL * 512);
    ushort_t* KHb  = (ushort_t*)alloc(1179648UL);
    ushort_t* KLb  = (ushort_t*)alloc(1179648UL);
    ushort_t* VTHb = (ushort_t*)alloc(1179648UL);
    ushort_t* VTLb = (ushort_t*)alloc(1179648UL);
    unsigned short* WH = (unsigned short*)(ws + off);
    unsigned short* WL = WH + 2621440UL;
    off += 2621440UL;
    // ---- dead-range aliases (stream-ordered, non-overlapping lifetimes) ----
    ushort_t* XNH = (ushort_t*)Qb;             // XN live rms->gemm; Qb live rope->attn
    ushort_t* XNL = XNH + 4608UL * 512;
    ushort_t* AOH = (ushort_t*)BIG;            // AO in BIG (QKV dead after rope/vtrans)
    ushort_t* AOL = AOH + 4608UL * 512;
    ushort_t* MIDH = (ushort_t*)BIG;           // MID in BIG (AO dead after o-proj)
    ushort_t* MIDL = MIDH + 4608UL * 1024;
    ushort_t* RRH = (ushort_t*)X;              // X dead after router_build
    ushort_t* RRL = RRH + 262144;
    float* OUTM = X + 262144;
    float* OUTN = X + 393216;
    float* KRN  = X + 524288;
    float* KGN  = X + 589824;
    (void)ws_size; (void)in_sizes; (void)n_in; (void)out_size;

    copy_in_kernel<<<(2097152 + 255) / 256, 256, 0, stream>>>(x_in, X, 2097152);

    for (int i = 0; i < 4; ++i) {
        split_layer(enc_qkv + (size_t)i * 512 * 1536,
                    enc_o   + (size_t)i * 512 * 512,
                    enc_up  + (size_t)i * 512 * 2048,
                    enc_dn  + (size_t)i * 1024 * 512, WH, WL, stream);
        run_layer(X, BIG, Qb, KHb, KLb, VTHb, VTLb, XNH, XNL, AOH, AOL, MIDH, MIDL,
                  WH, WL, enc_n1 + (size_t)i * 512, enc_n2 + (size_t)i * 512,
                  doc, 2, 2048, stream);
    }

    int rb_total = 64 * 72 * 512;
    router_build_kernel<<<(rb_total + 255) / 256, 256, 0, stream>>>(X, rt, X2, rb_total);

    for (int i = 0; i < 2; ++i) {
        split_layer(rtr_qkv + (size_t)i * 512 * 1536,
                    rtr_o   + (size_t)i * 512 * 512,
                    rtr_up  + (size_t)i * 512 * 2048,
                    rtr_dn  + (size_t)i * 1024 * 512, WH, WL, stream);
        run_layer(X2, BIG, Qb, KHb, KLb, VTHb, VTLb, XNH, XNL, AOH, AOL, MIDH, MIDL,
                  WH, WL, rtr_n1 + (size_t)i * 512, rtr_n2 + (size_t)i * 512,
                  nullptr, 64, 72, stream);
    }

    gather_rows_kernel<<<(512 * 512) / 256, 256, 0, stream>>>(X2, RRH, RRL, 512 * 512);
    wsplit_kernel<<<dim3(8, 16), 256, 0, stream>>>(out_w, WH, WL, 512, 256);
    gemm3<64><<<dim3(2, 8), 256, 0, stream>>>(RRH, RRL, WH, WL, nullptr, OUTM, 512, 256, 512);

    norm_half_kernel<<<1024, 64, 0, stream>>>(OUTM, OUTN);
    norm_keys_kernel<<<512, 64, 0, stream>>>(k_rt, KRN);
    norm_keys_kernel<<<512, 64, 0, stream>>>(k_gt, KGN);
    logits_top2_kernel<<<2048, 64, 0, stream>>>(OUTN, KRN, KGN, (float*)d_out);
}

// Round 11
// 1190.640 us; speedup vs baseline: 1.3248x; 1.0207x over previous
//
#include <hip/hip_runtime.h>
#include <hip/hip_bf16.h>
#include <cstdint>

// ---------------------------------------------------------------------------
// B=2 S=2048 D=512 H=8 HD=64, FFH=1024. Encoder: 4 layers, G=2, Sg=2048
// (block-causal-64 AND doc mask). Router: 2 layers, G=64, Sg=72, full attn.
// Round 20: kill per-iter VALU address arithmetic + on-device trig.
//  r10 counters: up_silu VALUBusy 23% ~= MfmaUtil 24.7% -> loop-carried
//  set-rotation forces full LDS-address recompute each iter. K is
//  compile-time at every call site: template-K + full unroll makes set
//  indices/addresses constant.
//  - gemm3<BM,K>, gemm_up_silu<K>, gemm3w<K>: constexpr nk, full unroll.
//  - rope cos/sin table (2048x32 float2) built once into BIG tail (dead
//    region, no ws growth); rope_pack: powf+sincosf -> 1 float2 load.
//  Everything else = r10 (attn r9, schedules proven).
// ---------------------------------------------------------------------------

typedef __attribute__((ext_vector_type(8))) short short8;   // 8 bf16 = 4 VGPR
typedef __attribute__((ext_vector_type(4))) float f32x4;
typedef unsigned short ushort_t;

__device__ __forceinline__ float bf2f(unsigned short u) {
    return __uint_as_float(((unsigned)u) << 16);
}
__device__ __forceinline__ unsigned short f2bf(float f) {
    unsigned u = __float_as_uint(f);
    unsigned r = 0x7FFFu + ((u >> 16) & 1u);
    return (unsigned short)((u + r) >> 16);
}
__device__ __forceinline__ float wave_sum64(float v) {
#pragma unroll
    for (int o = 32; o; o >>= 1) v += __shfl_xor(v, o);
    return v;
}
__device__ __forceinline__ void load_lds16(const ushort_t* g, ushort_t* l) {
    __builtin_amdgcn_global_load_lds(
        (const __attribute__((address_space(1))) unsigned int*)g,
        (__attribute__((address_space(3))) unsigned int*)l, 16, 0, 0);
}

#define MFMA16(a, b, c) __builtin_amdgcn_mfma_f32_16x16x32_bf16(a, b, c, 0, 0, 0)
#define BARRIER_RAW() do { asm volatile("" ::: "memory"); \
    __builtin_amdgcn_s_barrier(); asm volatile("" ::: "memory"); } while (0)
#define VMCNT0() asm volatile("s_waitcnt vmcnt(0)" ::: "memory")

// ---- f32 copy (input x -> mutable X) --------------------------------------
__global__ void copy_in_kernel(const float* __restrict__ src,
                               float* __restrict__ dst, int n) {
    int i = blockIdx.x * 256 + threadIdx.x;
    if (i < n) dst[i] = src[i];
}

// ---- RoPE cos/sin table: [s][i] -> {cos,sin}(s * theta^-(2i/64)) ----------
__global__ void rope_table_kernel(float* __restrict__ TAB) {
    int idx = blockIdx.x * 256 + threadIdx.x;   // 2048*32
    int s = idx >> 5, i = idx & 31;
    float inv = powf(10000.0f, -(float)(2 * i) / 64.0f);
    float sn, cs;
    sincosf((float)s * inv, &sn, &cs);
    TAB[2 * idx]     = cs;
    TAB[2 * idx + 1] = sn;
}

// ---- weight transpose + hi/lo bf16 split: W[K,N] -> WT_hi/lo[N,K] ---------
__global__ __launch_bounds__(256) void wsplit_kernel(const float* __restrict__ W,
        unsigned short* __restrict__ WH, unsigned short* __restrict__ WL,
        int K, int N) {
    __shared__ float tile[32][33];
    int bn = blockIdx.x * 32, bk = blockIdx.y * 32;
    int tx = threadIdx.x & 31, ty = threadIdx.x >> 5;
#pragma unroll
    for (int i = 0; i < 4; ++i)
        tile[ty + 8 * i][tx] = W[(size_t)(bk + ty + 8 * i) * N + bn + tx];
    __syncthreads();
#pragma unroll
    for (int i = 0; i < 4; ++i) {
        int n = bn + ty + 8 * i, k = bk + tx;
        float x = tile[tx][ty + 8 * i];
        unsigned short h = f2bf(x);
        unsigned short lo = f2bf(x - bf2f(h));
        WH[(size_t)n * K + k] = h;
        WL[(size_t)n * K + k] = lo;
    }
}

// ---- RMSNorm over D=512: 1 wave per token, 4 tokens/block -----------------
__global__ __launch_bounds__(256) void rmsnorm_kernel(const float* __restrict__ X,
        const float* __restrict__ W, ushort_t* __restrict__ XNH,
        ushort_t* __restrict__ XNL) {
    int w = threadIdx.x >> 6, lane = threadIdx.x & 63;
    int t = blockIdx.x * 4 + w;
    const float* xr = X + (size_t)t * 512;
    float v[8];
    float ss = 0.f;
#pragma unroll
    for (int j = 0; j < 8; ++j) { v[j] = xr[lane + 64 * j]; ss += v[j] * v[j]; }
    ss = wave_sum64(ss);
    float scale = rsqrtf(ss * (1.0f / 512.0f) + 1e-6f);
    size_t base = (size_t)t * 512;
#pragma unroll
    for (int j = 0; j < 8; ++j) {
        float a = v[j] * scale * W[lane + 64 * j];
        unsigned short h = f2bf(a);
        XNH[base + lane + 64 * j] = h;
        XNL[base + lane + 64 * j] = f2bf(a - bf2f(h));
    }
}

// ---- bf16x3 MFMA GEMM: 3-set LDS, counted vmcnt, depth-2, K templated -----
// C[M,N] = A @ B^T (+Res). Tile BM x 128, BK=32, 256 thr = 4 waves.
// Flat set rows: [0,BM)=Ah, [BM,2BM)=Al, [2BM,2BM+128)=Bh, rest Bl.
// Full unroll (constexpr nk): set indices & LDS addresses become constants.
template <int BM, int K>
__global__ __launch_bounds__(256) void gemm3(
        const ushort_t* __restrict__ AH, const ushort_t* __restrict__ AL,
        const ushort_t* __restrict__ BH, const ushort_t* __restrict__ BL,
        const float* __restrict__ Res, float* __restrict__ C,
        int M, int N) {
    constexpr int MI   = BM / 32;
    constexpr int ROWS = 2 * BM + 256;
    constexpr int LPW  = ROWS / 64;
    constexpr int SS   = ROWS * 32;
    constexpr int nk   = K >> 5;
    __shared__ __align__(16) ushort_t S[3][ROWS][32];
    int tid = threadIdx.x;
    int n0 = blockIdx.x * 128, m0 = blockIdx.y * BM;
    int wid = tid >> 6, lane = tid & 63;
    int wm = (wid >> 1) * (BM / 2), wn = (wid & 1) * 64;
    int col = lane & 15, quad = lane >> 4;

    const ushort_t* gsrc[LPW];
    int ldof[LPW];
#pragma unroll
    for (int j = 0; j < LPW; ++j) {
        int e = wid * LPW + j;
        int srow = e * 16 + (lane >> 2);
        const ushort_t* gp; int rin;
        if (srow < BM)                { gp = AH + (size_t)m0 * K; rin = srow; }
        else if (srow < 2 * BM)       { gp = AL + (size_t)m0 * K; rin = srow - BM; }
        else if (srow < 2 * BM + 128) { gp = BH + (size_t)n0 * K; rin = srow - 2 * BM; }
        else                          { gp = BL + (size_t)n0 * K; rin = srow - 2 * BM - 128; }
        gsrc[j] = gp + (size_t)rin * K + ((lane & 3) ^ ((lane >> 3) & 3)) * 8;
        ldof[j] = e * 512;
    }
    ushort_t* sbase = &S[0][0][0];
    auto STAGE = [&](int set, int kc) {
        ushort_t* sb = sbase + set * SS;
#pragma unroll
        for (int j = 0; j < LPW; ++j)
            load_lds16(gsrc[j] + kc * 32, sb + ldof[j]);
    };
    auto WAITK = [&]() {
        if constexpr (BM == 64) asm volatile("s_waitcnt vmcnt(6)" ::: "memory");
        else                    asm volatile("s_waitcnt vmcnt(8)" ::: "memory");
    };

    int chrd = (quad ^ ((col >> 1) & 3)) * 8;
    f32x4 acc[MI][4] = {};
    STAGE(0, 0);
    if (nk > 1) { STAGE(1, 1); WAITK(); }
    else        { VMCNT0(); }
    BARRIER_RAW();
#pragma unroll
    for (int kc = 0; kc < nk; ++kc) {
        constexpr int SETS[3] = {0, 1, 2};
        const int sc = kc % 3, sp = (kc + 2) % 3;
        (void)SETS;
        if (kc + 2 < nk) STAGE(sp, kc + 2);
        const ushort_t* sb = sbase + sc * SS;
        short8 afh[MI], afl[MI], bfh[4], bfl[4];
#pragma unroll
        for (int i = 0; i < MI; ++i) {
            afh[i] = *(const short8*)(sb + (size_t)(wm + i * 16 + col) * 32 + chrd);
            afl[i] = *(const short8*)(sb + (size_t)(BM + wm + i * 16 + col) * 32 + chrd);
        }
#pragma unroll
        for (int i = 0; i < 4; ++i) {
            bfh[i] = *(const short8*)(sb + (size_t)(2 * BM + wn + i * 16 + col) * 32 + chrd);
            bfl[i] = *(const short8*)(sb + (size_t)(2 * BM + 128 + wn + i * 16 + col) * 32 + chrd);
        }
#pragma unroll
        for (int mi = 0; mi < MI; ++mi)
#pragma unroll
            for (int ni = 0; ni < 4; ++ni) {
                f32x4 c = acc[mi][ni];
                c = MFMA16(afh[mi], bfh[ni], c);
                c = MFMA16(afh[mi], bfl[ni], c);
                c = MFMA16(afl[mi], bfh[ni], c);
                acc[mi][ni] = c;
            }
        if (kc + 1 < nk) {
            if (kc + 2 < nk) WAITK();
            else VMCNT0();
            BARRIER_RAW();
        }
    }
#pragma unroll
    for (int mi = 0; mi < MI; ++mi)
#pragma unroll
        for (int ni = 0; ni < 4; ++ni)
#pragma unroll
            for (int r = 0; r < 4; ++r) {
                int row = m0 + wm + mi * 16 + quad * 4 + r;
                int ccol = n0 + wn + ni * 16 + col;
                size_t o = (size_t)row * N + ccol;
                float v = acc[mi][ni][r];
                if (Res) v += Res[o];
                C[o] = v;
            }
}

// ---- bf16x3 GEMM, 512 thr (8 waves 4Mx2N), 128x128 tile, 2-set, K templ ---
template <int K>
__global__ __launch_bounds__(512, 4) void gemm3w(
        const ushort_t* __restrict__ AH, const ushort_t* __restrict__ AL,
        const ushort_t* __restrict__ BH, const ushort_t* __restrict__ BL,
        const float* __restrict__ Res, float* __restrict__ C,
        int M, int N) {
    constexpr int ROWS = 512;
    constexpr int LPW  = 4;
    constexpr int SS   = ROWS * 32;
    constexpr int nk   = K >> 5;
    __shared__ __align__(16) ushort_t S[2][ROWS][32];
    int tid = threadIdx.x;
    int n0 = blockIdx.x * 128, m0 = blockIdx.y * 128;
    int wid = tid >> 6, lane = tid & 63;
    int wm = (wid >> 1) * 32, wn = (wid & 1) * 64;
    int col = lane & 15, quad = lane >> 4;

    const ushort_t* gsrc[LPW];
    int ldof[LPW];
#pragma unroll
    for (int j = 0; j < LPW; ++j) {
        int e = wid * LPW + j;
        int srow = e * 16 + (lane >> 2);
        const ushort_t* gp; int rin;
        if (srow < 128)      { gp = AH; rin = m0 + srow; }
        else if (srow < 256) { gp = AL; rin = m0 + srow - 128; }
        else if (srow < 384) { gp = BH; rin = n0 + srow - 256; }
        else                 { gp = BL; rin = n0 + srow - 384; }
        gsrc[j] = gp + (size_t)rin * K + ((lane & 3) ^ ((lane >> 3) & 3)) * 8;
        ldof[j] = e * 512;
    }
    ushort_t* sbase = &S[0][0][0];
    auto STAGE = [&](int set, int kc) {
        ushort_t* sb = sbase + set * SS;
#pragma unroll
        for (int j = 0; j < LPW; ++j)
            load_lds16(gsrc[j] + kc * 32, sb + ldof[j]);
    };

    int chrd = (quad ^ ((col >> 1) & 3)) * 8;
    f32x4 acc[2][4] = {};
    STAGE(0, 0);
    VMCNT0();
    BARRIER_RAW();
#pragma unroll
    for (int kc = 0; kc < nk; ++kc) {
        const int cur = kc & 1;
        if (kc + 1 < nk) STAGE(cur ^ 1, kc + 1);
        const ushort_t* sb = sbase + cur * SS;
        short8 afh[2], afl[2], bfh[4], bfl[4];
#pragma unroll
        for (int i = 0; i < 2; ++i) {
            afh[i] = *(const short8*)(sb + (size_t)(wm + i * 16 + col) * 32 + chrd);
            afl[i] = *(const short8*)(sb + (size_t)(128 + wm + i * 16 + col) * 32 + chrd);
        }
#pragma unroll
        for (int i = 0; i < 4; ++i) {
            bfh[i] = *(const short8*)(sb + (size_t)(256 + wn + i * 16 + col) * 32 + chrd);
            bfl[i] = *(const short8*)(sb + (size_t)(384 + wn + i * 16 + col) * 32 + chrd);
        }
#pragma unroll
        for (int mi = 0; mi < 2; ++mi)
#pragma unroll
            for (int ni = 0; ni < 4; ++ni) {
                f32x4 c = acc[mi][ni];
                c = MFMA16(afh[mi], bfh[ni], c);
                c = MFMA16(afh[mi], bfl[ni], c);
                c = MFMA16(afl[mi], bfh[ni], c);
                acc[mi][ni] = c;
            }
        if (kc + 1 < nk) {
            VMCNT0();
            BARRIER_RAW();
        }
    }
#pragma unroll
    for (int mi = 0; mi < 2; ++mi)
#pragma unroll
        for (int ni = 0; ni < 4; ++ni)
#pragma unroll
            for (int r = 0; r < 4; ++r) {
                int row = m0 + wm + mi * 16 + quad * 4 + r;
                int ccol = n0 + wn + ni * 16 + col;
                size_t o = (size_t)row * N + ccol;
                float v = acc[mi][ni][r];
                if (Res) v += Res[o];
                C[o] = v;
            }
}

// ---- fused up-proj + silu: 3-set counted-vmcnt, 256 thr, K templated ------
template <int K>
__global__ __launch_bounds__(256) void gemm_up_silu(
        const ushort_t* __restrict__ AH, const ushort_t* __restrict__ AL,
        const ushort_t* __restrict__ BH, const ushort_t* __restrict__ BL,
        ushort_t* __restrict__ MIDH, ushort_t* __restrict__ MIDL) {
    constexpr int ROWS = 384;
    constexpr int LPW  = 6;
    constexpr int SS   = ROWS * 32;
    constexpr int nk   = K >> 5;
    __shared__ __align__(16) ushort_t S[3][ROWS][32];
    int tid = threadIdx.x;
    int n0 = blockIdx.x * 64, m0 = blockIdx.y * 64;
    int wid = tid >> 6, lane = tid & 63;
    int wm = (wid >> 1) * 32, wn = (wid & 1) * 32;
    int col = lane & 15, quad = lane >> 4;

    const ushort_t* gsrc[LPW];
    int ldof[LPW];
#pragma unroll
    for (int j = 0; j < LPW; ++j) {
        int e = wid * LPW + j;
        int srow = e * 16 + (lane >> 2);
        const ushort_t* gp; int rin;
        if (srow < 64)       { gp = AH; rin = m0 + srow; }
        else if (srow < 128) { gp = AL; rin = m0 + srow - 64; }
        else if (srow < 192) { gp = BH; rin = n0 + srow - 128; }
        else if (srow < 256) { gp = BL; rin = n0 + srow - 192; }
        else if (srow < 320) { gp = BH; rin = 1024 + n0 + srow - 256; }
        else                 { gp = BL; rin = 1024 + n0 + srow - 320; }
        gsrc[j] = gp + (size_t)rin * K + ((lane & 3) ^ ((lane >> 3) & 3)) * 8;
        ldof[j] = e * 512;
    }
    ushort_t* sbase = &S[0][0][0];
    auto STAGE = [&](int set, int kc) {
        ushort_t* sb = sbase + set * SS;
#pragma unroll
        for (int j = 0; j < LPW; ++j)
            load_lds16(gsrc[j] + kc * 32, sb + ldof[j]);
    };
    auto WAITK = [&]() { asm volatile("s_waitcnt vmcnt(6)" ::: "memory"); };

    int chrd = (quad ^ ((col >> 1) & 3)) * 8;
    f32x4 a1[2][2] = {}, a2[2][2] = {};
    STAGE(0, 0);
    if (nk > 1) { STAGE(1, 1); WAITK(); }
    else        { VMCNT0(); }
    BARRIER_RAW();
#pragma unroll
    for (int kc = 0; kc < nk; ++kc) {
        const int sc = kc % 3, sp = (kc + 2) % 3;
        if (kc + 2 < nk) STAGE(sp, kc + 2);
        const ushort_t* sb = sbase + sc * SS;
        short8 afh[2], afl[2], b1h[2], b1l[2], b2h[2], b2l[2];
#pragma unroll
        for (int i = 0; i < 2; ++i) {
            afh[i] = *(const short8*)(sb + (size_t)(wm + i * 16 + col) * 32 + chrd);
            afl[i] = *(const short8*)(sb + (size_t)(64 + wm + i * 16 + col) * 32 + chrd);
            b1h[i] = *(const short8*)(sb + (size_t)(128 + wn + i * 16 + col) * 32 + chrd);
            b1l[i] = *(const short8*)(sb + (size_t)(192 + wn + i * 16 + col) * 32 + chrd);
            b2h[i] = *(const short8*)(sb + (size_t)(256 + wn + i * 16 + col) * 32 + chrd);
            b2l[i] = *(const short8*)(sb + (size_t)(320 + wn + i * 16 + col) * 32 + chrd);
        }
#pragma unroll
        for (int mi = 0; mi < 2; ++mi)
#pragma unroll
            for (int ni = 0; ni < 2; ++ni) {
                f32x4 c = a1[mi][ni];
                c = MFMA16(afh[mi], b1h[ni], c);
                c = MFMA16(afh[mi], b1l[ni], c);
                c = MFMA16(afl[mi], b1h[ni], c);
                a1[mi][ni] = c;
                f32x4 d = a2[mi][ni];
                d = MFMA16(afh[mi], b2h[ni], d);
                d = MFMA16(afh[mi], b2l[ni], d);
                d = MFMA16(afl[mi], b2h[ni], d);
                a2[mi][ni] = d;
            }
        if (kc + 1 < nk) {
            if (kc + 2 < nk) WAITK();
            else VMCNT0();
            BARRIER_RAW();
        }
    }
#pragma unroll
    for (int mi = 0; mi < 2; ++mi)
#pragma unroll
        for (int ni = 0; ni < 2; ++ni)
#pragma unroll
            for (int r = 0; r < 4; ++r) {
                int row = m0 + wm + mi * 16 + quad * 4 + r;
                int ccol = n0 + wn + ni * 16 + col;
                float v1 = a1[mi][ni][r], v2 = a2[mi][ni][r];
                float rr = (v1 / (1.0f + __expf(-v1))) * v2;
                unsigned short h = f2bf(rr);
                size_t o = (size_t)row * 1024 + ccol;
                MIDH[o] = h;
                MIDL[o] = f2bf(rr - bf2f(h));
            }
}

// ---- split qkv + RoPE (table-driven); Q f32; K bf16 hi/lo [gh][Sg][64] ----
__global__ void rope_pack_kernel(const float* __restrict__ QKV,
        const float* __restrict__ TAB,
        float* __restrict__ Q, ushort_t* __restrict__ KH,
        ushort_t* __restrict__ KL, int Sg, int total) {
    int idx = blockIdx.x * 256 + threadIdx.x;
    if (idx >= total) return;
    int i = idx & 31;
    int h = (idx >> 5) & 7;
    int t = idx >> 8;
    int g = t / Sg; int s = t - g * Sg;
    const float* row = QKV + (size_t)t * 1536;
    float2 cssn = *(const float2*)(TAB + 2 * (s * 32 + i));
    float cs = cssn.x, sn = cssn.y;
    size_t ob = ((size_t)(g * 8 + h) * Sg + s) * 64 + i;
    int c = h * 64 + i;
    float q1 = row[c], q2 = row[c + 32];
    Q[ob]      = q1 * cs + q2 * sn;
    Q[ob + 32] = q2 * cs - q1 * sn;
    float k1 = row[512 + c], k2 = row[512 + c + 32];
    float ka = k1 * cs + k2 * sn;
    float kb = k2 * cs - k1 * sn;
    unsigned short ha = f2bf(ka), hb = f2bf(kb);
    KH[ob]      = ha;  KL[ob]      = f2bf(ka - bf2f(ha));
    KH[ob + 32] = hb;  KL[ob + 32] = f2bf(kb - bf2f(hb));
}

// ---- V^T split: QKV f32 [T][1536] -> VT hi/lo [gh][64 d][Sg s] ------------
__global__ __launch_bounds__(256) void vtrans_kernel(const float* __restrict__ QKV,
        ushort_t* __restrict__ VTH, ushort_t* __restrict__ VTL, int Sg) {
    __shared__ float tile[64][65];
    int chunk = blockIdx.x, gh = blockIdx.y;
    int g = gh >> 3, h = gh & 7;
    int tid = threadIdx.x;
    int sr = tid >> 2, dc = (tid & 3) * 16;
    int s = chunk * 64 + sr;
    if (s < Sg) {
        const float* src = QKV + ((size_t)g * Sg + s) * 1536 + 1024 + h * 64 + dc;
#pragma unroll
        for (int j = 0; j < 4; ++j) {
            float4 v = *(const float4*)(src + 4 * j);
            tile[sr][dc + 4 * j]     = v.x;
            tile[sr][dc + 4 * j + 1] = v.y;
            tile[sr][dc + 4 * j + 2] = v.z;
            tile[sr][dc + 4 * j + 3] = v.w;
        }
    } else {
#pragma unroll
        for (int j = 0; j < 16; ++j) tile[sr][dc + j] = 0.f;
    }
    __syncthreads();
    int dr = tid >> 2, sc = (tid & 3) * 16;
    short8 hv[2], lv[2];
#pragma unroll
    for (int half = 0; half < 2; ++half)
#pragma unroll
        for (int j = 0; j < 8; ++j) {
            float v = tile[sc + half * 8 + j][dr];
            unsigned short hb = f2bf(v);
            hv[half][j] = (short)hb;
            lv[half][j] = (short)f2bf(v - bf2f(hb));
        }
    int scol = chunk * 64 + sc;
    size_t ob = ((size_t)gh * 64 + dr) * Sg + scol;
    if (scol + 16 <= Sg) {
        *(short8*)(VTH + ob)     = hv[0];
        *(short8*)(VTH + ob + 8) = hv[1];
        *(short8*)(VTL + ob)     = lv[0];
        *(short8*)(VTL + ob + 8) = lv[1];
    } else {
#pragma unroll
        for (int j = 0; j < 16; ++j)
            if (scol + j < Sg) {
                VTH[ob + j] = (ushort_t)((j < 8) ? hv[0][j] : hv[1][j - 8]);
                VTL[ob + j] = (ushort_t)((j < 8) ? lv[0][j] : lv[1][j - 8]);
            }
    }
}

// ---- MFMA flash attention (bf16x3), contiguous live k-range ---------------
template <bool MASKED>
__global__ __launch_bounds__(256, 3) void attn3_kernel(const float* __restrict__ Q,
        const ushort_t* __restrict__ KHg, const ushort_t* __restrict__ KLg,
        const ushort_t* __restrict__ VTHg, const ushort_t* __restrict__ VTLg,
        const int* __restrict__ doc, ushort_t* __restrict__ AOH,
        ushort_t* __restrict__ AOL, int Sg) {
    __shared__ __align__(16) ushort_t Khs[64][64], Kls[64][64];  // swizzled
    __shared__ __align__(16) ushort_t Vts[64][64], Vtl[64][64];  // swizzled
    __shared__ __align__(16) ushort_t Ph[4][16][72], Pl[4][16][72];
    __shared__ int dock[64];
    __shared__ int dmax_s[32];
    int qb = (int)(gridDim.x - 1 - blockIdx.x);   // big qb first (load balance)
    int gh = blockIdx.y, g = gh >> 3;
    int tid = threadIdx.x, wid = tid >> 6, lane = tid & 63;
    int col = lane & 15, quad = lane >> 4;

    int rL = lane >> 3, cSw = (lane & 7) ^ rL;
    const ushort_t* kb;      // K waves: row base (chunk folded in)
    const ushort_t* vb;      // V waves: d-row base
    ushort_t* lb;
    if (wid == 0)      { kb = KHg + (size_t)gh * Sg * 64 + cSw * 8;  vb = nullptr; lb = &Khs[0][0]; }
    else if (wid == 1) { kb = KLg + (size_t)gh * Sg * 64 + cSw * 8;  vb = nullptr; lb = &Kls[0][0]; }
    else if (wid == 2) { vb = VTHg + ((size_t)gh * 64 + rL) * Sg;    kb = nullptr; lb = &Vts[0][0]; }
    else               { vb = VTLg + ((size_t)gh * 64 + rL) * Sg;    kb = nullptr; lb = &Vtl[0][0]; }
    int sw0 = ((0 + quad) ^ (col & 7)) * 8;
    int sw1 = ((4 + quad) ^ (col & 7)) * 8;

    short8 qa[2][2];  // [kk][0=hi,1=lo]
    {
        int qrow = qb * 64 + wid * 16 + col;
        if (qrow >= Sg) qrow = Sg - 1;
        const float* Qg = Q + ((size_t)gh * Sg + qrow) * 64 + quad * 8;
#pragma unroll
        for (int kk = 0; kk < 2; ++kk) {
            float4 v0 = *(const float4*)(Qg + kk * 32);
            float4 v1 = *(const float4*)(Qg + kk * 32 + 4);
            float vv[8] = {v0.x, v0.y, v0.z, v0.w, v1.x, v1.y, v1.z, v1.w};
            short8 h, l;
#pragma unroll
            for (int e = 0; e < 8; ++e) {
                float x = vv[e] * 0.125f;
                unsigned short hb = f2bf(x);
                h[e] = (short)hb;
                l[e] = (short)f2bf(x - bf2f(hb));
            }
            qa[kk][0] = h; qa[kk][1] = l;
        }
    }
    int dqr[4]; int wq0 = 0, wq1 = 0, bq0 = 0;
    int kts = 0;
    if (MASKED) {
        const int* db = doc + (size_t)g * Sg + qb * 64;
#pragma unroll
        for (int r = 0; r < 4; ++r) dqr[r] = db[wid * 16 + quad * 4 + r];
        wq0 = db[wid * 16]; wq1 = db[wid * 16 + 15];
        bq0 = db[0];
        int nkb = (Sg + 63) >> 6;
        if (tid < nkb) dmax_s[tid] = doc[(size_t)g * Sg + tid * 64 + 63];
        __syncthreads();
        int kbv = 0;
        while (kbv < nkb && dmax_s[kbv] < bq0) ++kbv;
        kts = kbv;
    }
    float m[4], l[4];
    f32x4 accO[4];
#pragma unroll
    for (int r = 0; r < 4; ++r) { m[r] = -1e30f; l[r] = 0.f; }
#pragma unroll
    for (int nd = 0; nd < 4; ++nd) accO[nd] = (f32x4){0.f, 0.f, 0.f, 0.f};

    int nkt = MASKED ? (qb + 1) : ((Sg + 63) >> 6);
    for (int kt = kts; kt < nkt; ++kt) {
        int kval = Sg - kt * 64; if (kval > 64) kval = 64;
        __syncthreads();
        if (wid < 2) {
#pragma unroll
            for (int p = 0; p < 8; ++p) {
                int sr2 = kt * 64 + p * 8 + rL;
                if (sr2 > Sg - 1) sr2 = Sg - 1;
                load_lds16(kb + (size_t)sr2 * 64, lb + p * 512);
            }
        } else {
            int vc = kt * 64 + cSw * 8;
            if (vc > Sg - 8) vc = Sg - 8;
#pragma unroll
            for (int p = 0; p < 8; ++p)
                load_lds16(vb + (size_t)(p * 8) * Sg + vc, lb + p * 512);
        }
        if (MASKED && tid < 64) dock[tid] = doc[(size_t)g * Sg + kt * 64 + tid];
        __syncthreads();
        bool wskip = false;
        if (MASKED) wskip = (dock[kval - 1] < wq0);
        if (!wskip) {
            int dk[4];
            if (MASKED) {
#pragma unroll
                for (int ni = 0; ni < 4; ++ni) dk[ni] = dock[ni * 16 + col];
            }
            f32x4 sc[4];
            __builtin_amdgcn_s_setprio(1);
#pragma unroll
            for (int ni = 0; ni < 4; ++ni) {
                int rb = (ni * 16 + col) * 64;
                short8 bh0 = *(const short8*)(&Khs[0][0] + rb + sw0);
                short8 bl0 = *(const short8*)(&Kls[0][0] + rb + sw0);
                short8 bh1 = *(const short8*)(&Khs[0][0] + rb + sw1);
                short8 bl1 = *(const short8*)(&Kls[0][0] + rb + sw1);
                f32x4 c = (f32x4){0.f, 0.f, 0.f, 0.f};
                c = MFMA16(qa[0][0], bh0, c);
                c = MFMA16(qa[0][0], bl0, c);
                c = MFMA16(qa[0][1], bh0, c);
                c = MFMA16(qa[1][0], bh1, c);
                c = MFMA16(qa[1][0], bl1, c);
                c = MFMA16(qa[1][1], bh1, c);
                sc[ni] = c;
            }
            __builtin_amdgcn_s_setprio(0);
            float mnew[4];
#pragma unroll
            for (int r = 0; r < 4; ++r) mnew[r] = -1e30f;
#pragma unroll
            for (int ni = 0; ni < 4; ++ni)
#pragma unroll
                for (int r = 0; r < 4; ++r) {
                    bool ok = MASKED ? (dk[ni] == dqr[r]) : (ni * 16 + col < kval);
                    float s = ok ? sc[ni][r] : -1e30f;
                    sc[ni][r] = s;
                    mnew[r] = fmaxf(mnew[r], s);
                }
#pragma unroll
            for (int r = 0; r < 4; ++r)
#pragma unroll
                for (int o = 1; o < 16; o <<= 1)
                    mnew[r] = fmaxf(mnew[r], __shfl_xor(mnew[r], o));
            float alpha[4], lsum[4];
#pragma unroll
            for (int r = 0; r < 4; ++r) {
                float M = fmaxf(m[r], mnew[r]);
                alpha[r] = __expf(m[r] - M);
                m[r] = M;
                lsum[r] = 0.f;
            }
#pragma unroll
            for (int ni = 0; ni < 4; ++ni)
#pragma unroll
                for (int r = 0; r < 4; ++r) {
                    bool ok = MASKED ? (dk[ni] == dqr[r]) : (ni * 16 + col < kval);
                    float p = ok ? __expf(sc[ni][r] - m[r]) : 0.f;
                    lsum[r] += p;
                    unsigned short h = f2bf(p);
                    Ph[wid][quad * 4 + r][ni * 16 + col] = h;
                    Pl[wid][quad * 4 + r][ni * 16 + col] = f2bf(p - bf2f(h));
                }
#pragma unroll
            for (int r = 0; r < 4; ++r) {
#pragma unroll
                for (int o = 1; o < 16; o <<= 1)
                    lsum[r] += __shfl_xor(lsum[r], o);
                l[r] = l[r] * alpha[r] + lsum[r];
            }
#pragma unroll
            for (int nd = 0; nd < 4; ++nd)
#pragma unroll
                for (int r = 0; r < 4; ++r) accO[nd][r] *= alpha[r];
            __builtin_amdgcn_s_setprio(1);
#pragma unroll
            for (int kk = 0; kk < 2; ++kk) {
                short8 pah = *(const short8*)&Ph[wid][col][kk * 32 + quad * 8];
                short8 pal = *(const short8*)&Pl[wid][col][kk * 32 + quad * 8];
                int sw = kk ? sw1 : sw0;
#pragma unroll
                for (int nd = 0; nd < 4; ++nd) {
                    int rb = (nd * 16 + col) * 64;
                    short8 vbh = *(const short8*)(&Vts[0][0] + rb + sw);
                    short8 vbl = *(const short8*)(&Vtl[0][0] + rb + sw);
                    f32x4 c = accO[nd];
                    c = MFMA16(pah, vbh, c);
                    c = MFMA16(pah, vbl, c);
                    c = MFMA16(pal, vbh, c);
                    accO[nd] = c;
                }
            }
            __builtin_amdgcn_s_setprio(0);
        }
    }
#pragma unroll
    for (int r = 0; r < 4; ++r) {
        int qrow = qb * 64 + wid * 16 + quad * 4 + r;
        if (qrow < Sg) {
            float inv = 1.0f / l[r];
            size_t base = ((size_t)g * Sg + qrow) * 512 + (gh & 7) * 64;
#pragma unroll
            for (int nd = 0; nd < 4; ++nd) {
                float val = accO[nd][r] * inv;
                unsigned short h = f2bf(val);
                AOH[base + nd * 16 + col] = h;
                AOL[base + nd * 16 + col] = f2bf(val - bf2f(h));
            }
        }
    }
}

// ---- build router stream: (64 groups) x (64 tokens + 8 router tokens) -----
__global__ void router_build_kernel(const float* __restrict__ X,
        const float* __restrict__ RT, float* __restrict__ X2, int total) {
    int idx = blockIdx.x * 256 + threadIdx.x;
    if (idx >= total) return;
    int d = idx & 511;
    int p = (idx >> 9) % 72;
    int g2 = idx / (72 * 512);
    X2[idx] = (p < 64) ? X[((size_t)g2 * 64 + p) * 512 + d]
                       : RT[(p - 64) * 512 + d];
}

// ---- gather xr[:,64:72,:] into dense (512,512) bf16 hi/lo -----------------
__global__ void gather_rows_kernel(const float* __restrict__ X2,
        ushort_t* __restrict__ RRH, ushort_t* __restrict__ RRL, int total) {
    int idx = blockIdx.x * 256 + threadIdx.x;
    if (idx >= total) return;
    int d = idx & 511;
    int row = idx >> 9;
    int g2 = row >> 3, rr = row & 7;
    float v = X2[((size_t)(g2 * 72 + 64 + rr)) * 512 + d];
    unsigned short h = f2bf(v);
    RRH[idx] = h;
    RRL[idx] = f2bf(v - bf2f(h));
}

// ---- l2-normalize each 128-half of each out row (l2n commutes w/ expand) --
__global__ __launch_bounds__(64) void norm_half_kernel(const float* __restrict__ IN,
        float* __restrict__ OUT) {
    int b = blockIdx.x; int lane = threadIdx.x;
    size_t base = (size_t)(b >> 1) * 256 + (size_t)(b & 1) * 128;
    float v0 = IN[base + lane], v1 = IN[base + 64 + lane];
    float ss = wave_sum64(v0 * v0 + v1 * v1);
    float sc = 1.0f / fmaxf(sqrtf(ss), 1e-12f);
    OUT[base + lane]      = v0 * sc;
    OUT[base + 64 + lane] = v1 * sc;
}

// ---- l2-normalize key columns: keys (32,128,16) over d --------------------
__global__ __launch_bounds__(64) void norm_keys_kernel(const float* __restrict__ Kin,
        float* __restrict__ Kout) {
    int b = blockIdx.x; int lane = threadIdx.x;
    int g = b >> 4, e = b & 15;
    size_t base = (size_t)g * 2048 + e;
    float v0 = Kin[base + (size_t)lane * 16];
    float v1 = Kin[base + (size_t)(lane + 64) * 16];
    float ss = wave_sum64(v0 * v0 + v1 * v1);
    float sc = 1.0f / fmaxf(sqrtf(ss), 1e-12f);
    Kout[base + (size_t)lane * 16]        = v0 * sc;
    Kout[base + (size_t)(lane + 64) * 16] = v1 * sc;
}

// ---- logits + top2 (stable, jax tie-break) --------------------------------
__global__ __launch_bounds__(64) void logits_top2_kernel(const float* __restrict__ OUTN,
        const float* __restrict__ KRN, const float* __restrict__ KGN,
        float* __restrict__ out) {
    int blk = blockIdx.x;
    int g = blk >> 6, bcol = blk & 63;
    int b = bcol >> 5, l = bcol & 31;
    int lsrc = (l + 31) & 31;     // roll(+1): element l comes from l-1
    int r = g >> 2;               // repeat RM=4
    int row = (b * 32 + lsrc) * 8 + r;
    const float* rvec = OUTN + (size_t)row * 256;
    __shared__ float sc[32];
    int lane = threadIdx.x;
    if (lane < 32) {
        int e = lane & 15;
        const float* kb = ((lane < 16) ? KRN : KGN) + (size_t)g * 2048 + e;
        const float* xv = (lane < 16) ? rvec : (rvec + 128);
        float s = 0.f;
#pragma unroll 8
        for (int d = 0; d < 128; ++d) s = fmaf(xv[d], kb[(size_t)d * 16], s);
        sc[lane] = s;
    }
    __syncthreads();
    if (lane == 0) {
        float bv = -1e30f, sv = -1e30f; int bi = 0, si = 0;
#pragma unroll
        for (int e = 0; e < 16; ++e) {
            float v = sc[e];
            if (v > bv) { sv = bv; si = bi; bv = v; bi = e; }
            else if (v > sv) { sv = v; si = e; }
        }
        size_t base = (size_t)g * 128 + (size_t)bcol * 2;
        out[base]            = bv;
        out[base + 1]        = sv;
        out[4096 + base]     = sc[16 + bi];
        out[4096 + base + 1] = sc[16 + si];
    }
}

// ---------------------------------------------------------------------------
static void run_layer(float* X, float* BIG, float* Qb, const float* TAB,
                      ushort_t* KHb, ushort_t* KLb, ushort_t* VTHb, ushort_t* VTLb,
                      ushort_t* XNH, ushort_t* XNL, ushort_t* AOH, ushort_t* AOL,
                      ushort_t* MIDH, ushort_t* MIDL,
                      const unsigned short* WH, const unsigned short* WL,
                      const float* n1, const float* n2,
                      const int* doc, int G, int Sg, hipStream_t stream) {
    const size_t oQKV = 0, oO = 786432, oUP = 1048576, oDN = 2097152;
    int T = G * Sg;
    rmsnorm_kernel<<<T / 4, 256, 0, stream>>>(X, n1, XNH, XNL);
    gemm3w<512><<<dim3(12, T / 128), 512, 0, stream>>>(XNH, XNL, WH + oQKV, WL + oQKV, nullptr, BIG, T, 1536);
    int rp = T * 256;
    rope_pack_kernel<<<(rp + 255) / 256, 256, 0, stream>>>(BIG, TAB, Qb, KHb, KLb, Sg, rp);
    int qblocks = (Sg + 63) >> 6;
    vtrans_kernel<<<dim3(qblocks, G * 8), 256, 0, stream>>>(BIG, VTHb, VTLb, Sg);
    if (doc)
        attn3_kernel<true><<<dim3(qblocks, G * 8), 256, 0, stream>>>(Qb, KHb, KLb, VTHb, VTLb, doc, AOH, AOL, Sg);
    else
        attn3_kernel<false><<<dim3(qblocks, G * 8), 256, 0, stream>>>(Qb, KHb, KLb, VTHb, VTLb, nullptr, AOH, AOL, Sg);
    gemm3<64, 512><<<dim3(4, T / 64), 256, 0, stream>>>(AOH, AOL, WH + oO, WL + oO, X, X, T, 512);
    rmsnorm_kernel<<<T / 4, 256, 0, stream>>>(X, n2, XNH, XNL);
    gemm_up_silu<512><<<dim3(16, T / 64), 256, 0, stream>>>(XNH, XNL, WH + oUP, WL + oUP, MIDH, MIDL);
    gemm3<64, 1024><<<dim3(4, T / 64), 256, 0, stream>>>(MIDH, MIDL, WH + oDN, WL + oDN, X, X, T, 512);
}

static void split_layer(const float* qkv, const float* o, const float* up, const float* dn,
                        unsigned short* WH, unsigned short* WL, hipStream_t stream) {
    const size_t oQKV = 0, oO = 786432, oUP = 1048576, oDN = 2097152;
    wsplit_kernel<<<dim3(48, 16), 256, 0, stream>>>(qkv, WH + oQKV, WL + oQKV, 512, 1536);
    wsplit_kernel<<<dim3(16, 16), 256, 0, stream>>>(o,   WH + oO,   WL + oO,   512, 512);
    wsplit_kernel<<<dim3(64, 16), 256, 0, stream>>>(up,  WH + oUP,  WL + oUP,  512, 2048);
    wsplit_kernel<<<dim3(16, 32), 256, 0, stream>>>(dn,  WH + oDN,  WL + oDN,  1024, 512);
}

extern "C" void kernel_launch(void* const* d_in, const int* in_sizes, int n_in,
                              void* d_out, int out_size, void* d_ws, size_t ws_size,
                              hipStream_t stream) {
    const float* x_in    = (const float*)d_in[0];
    const int*   doc     = (const int*)d_in[1];
    const float* rt      = (const float*)d_in[2];
    const float* out_w   = (const float*)d_in[3];
    const float* k_rt    = (const float*)d_in[4];
    const float* k_gt    = (const float*)d_in[5];
    const float* enc_qkv = (const float*)d_in[6];
    const float* enc_o   = (const float*)d_in[7];
    const float* enc_up  = (const float*)d_in[8];
    const float* enc_dn  = (const float*)d_in[9];
    const float* enc_n1  = (const float*)d_in[10];
    const float* enc_n2  = (const float*)d_in[11];
    const float* rtr_qkv = (const float*)d_in[12];
    const float* rtr_o   = (const float*)d_in[13];
    const float* rtr_up  = (const float*)d_in[14];
    const float* rtr_dn  = (const float*)d_in[15];
    const float* rtr_n1  = (const float*)d_in[16];
    const float* rtr_n2  = (const float*)d_in[17];

    float* ws = (float*)d_ws;
    size_t off = 0;
    auto alloc = [&](size_t n) { float* p = ws + off; off += n; return p; };
    float* X    = alloc(4608UL * 512);
    float* X2   = alloc(4608UL * 512);
    float* BIG  = alloc(4608UL * 2048);
    float* Qb   = alloc(4608UL * 512);
    ushort_t* KHb  = (ushort_t*)alloc(1179648UL);
    ushort_t* KLb  = (ushort_t*)alloc(1179648UL);
    ushort_t* VTHb = (ushort_t*)alloc(1179648UL);
    ushort_t* VTLb = (ushort_t*)alloc(1179648UL);
    unsigned short* WH = (unsigned short*)(ws + off);
    unsigned short* WL = WH + 2621440UL;
    off += 2621440UL;
    // ---- dead-range aliases (stream-ordered, non-overlapping lifetimes) ----
    ushort_t* XNH = (ushort_t*)Qb;             // XN live rms->gemm; Qb live rope->attn
    ushort_t* XNL = XNH + 4608UL * 512;
    ushort_t* AOH = (ushort_t*)BIG;            // AO in BIG (QKV dead after rope/vtrans)
    ushort_t* AOL = AOH + 4608UL * 512;
    ushort_t* MIDH = (ushort_t*)BIG;           // MID in BIG (AO dead after o-proj)
    ushort_t* MIDL = MIDH + 4608UL * 1024;
    float* TAB = BIG + 7864320;                // BIG tail: live max 7.08M floats
    ushort_t* RRH = (ushort_t*)X;              // X dead after router_build
    ushort_t* RRL = RRH + 262144;
    float* OUTM = X + 262144;
    float* OUTN = X + 393216;
    float* KRN  = X + 524288;
    float* KGN  = X + 589824;
    (void)ws_size; (void)in_sizes; (void)n_in; (void)out_size;

    copy_in_kernel<<<(2097152 + 255) / 256, 256, 0, stream>>>(x_in, X, 2097152);
    rope_table_kernel<<<256, 256, 0, stream>>>(TAB);

    for (int i = 0; i < 4; ++i) {
        split_layer(enc_qkv + (size_t)i * 512 * 1536,
                    enc_o   + (size_t)i * 512 * 512,
                    enc_up  + (size_t)i * 512 * 2048,
                    enc_dn  + (size_t)i * 1024 * 512, WH, WL, stream);
        run_layer(X, BIG, Qb, TAB, KHb, KLb, VTHb, VTLb, XNH, XNL, AOH, AOL, MIDH, MIDL,
                  WH, WL, enc_n1 + (size_t)i * 512, enc_n2 + (size_t)i * 512,
                  doc, 2, 2048, stream);
    }

    int rb_total = 64 * 72 * 512;
    router_build_kernel<<<(rb_total + 255) / 256, 256, 0, stream>>>(X, rt, X2, rb_total);

    for (int i = 0; i < 2; ++i) {
        split_layer(rtr_qkv + (size_t)i * 512 * 1536,
                    rtr_o   + (size_t)i * 512 * 512,
                    rtr_up  + (size_t)i * 512 * 2048,
                    rtr_dn  + (size_t)i * 1024 * 512, WH, WL, stream);
        run_layer(X2, BIG, Qb, TAB, KHb, KLb, VTHb, VTLb, XNH, XNL, AOH, AOL, MIDH, MIDL,
                  WH, WL, rtr_n1 + (size_t)i * 512, rtr_n2 + (size_t)i * 512,
                  nullptr, 64, 72, stream);
    }

    gather_rows_kernel<<<(512 * 512) / 256, 256, 0, stream>>>(X2, RRH, RRL, 512 * 512);
    wsplit_kernel<<<dim3(8, 16), 256, 0, stream>>>(out_w, WH, WL, 512, 256);
    gemm3<64, 512><<<dim3(2, 8), 256, 0, stream>>>(RRH, RRL, WH, WL, nullptr, OUTM, 512, 256);

    norm_half_kernel<<<1024, 64, 0, stream>>>(OUTM, OUTN);
    norm_keys_kernel<<<512, 64, 0, stream>>>(k_rt, KRN);
    norm_keys_kernel<<<512, 64, 0, stream>>>(k_gt, KGN);
    logits_top2_kernel<<<2048, 64, 0, stream>>>(OUTN, KRN, KGN, (float*)d_out);
}